// Round 1
// baseline (360.744 us; speedup 1.0000x reference)
//
#include <hip/hip_runtime.h>
#include <cstdint>
#include <cmath>

#define T_SEQ 2048
#define NBATCH 8
#define DM 1024
#define DH 512
#define MROWS (NBATCH * T_SEQ)   // 16384
#define NC 16                    // chunks per batch
#define CL 128                   // chunk length

typedef short s8v __attribute__((ext_vector_type(8)));
typedef float f32x4 __attribute__((ext_vector_type(4)));

typedef unsigned int __attribute__((address_space(1))) uint_g;
typedef unsigned int __attribute__((address_space(3))) uint_l;

#define QKSCALE 0.044194173824159216f   // 1/sqrt(512)

__device__ __forceinline__ float b2f(unsigned short s) {
    union { unsigned u; float f; } c; c.u = ((unsigned)s) << 16; return c.f;
}
__device__ __forceinline__ unsigned short f2b(float f) {
    union { float f; unsigned u; } c; c.f = f;
    unsigned r = c.u + 0x7fffu + ((c.u >> 16) & 1u);
    return (unsigned short)(r >> 16);
}
__device__ __forceinline__ void gld_lds16(const void* g, void* l) {
    __builtin_amdgcn_global_load_lds((const uint_g*)g, (uint_l*)l, 16, 0, 0);
}

#define WAITV(N) asm volatile("s_waitcnt vmcnt(" #N ")" ::: "memory")
#define BARSYNC() do { asm volatile("" ::: "memory"); __builtin_amdgcn_s_barrier(); asm volatile("" ::: "memory"); } while (0)

// ---------------- weight conversion (merged) ----------------
__global__ __launch_bounds__(256) void convAll_kernel(
    const float* __restrict__ Wq, const float* __restrict__ Wk,
    const float* __restrict__ Wo, const float* __restrict__ Wv,
    const float* __restrict__ Wout,
    unsigned short* __restrict__ Wcat1, unsigned short* __restrict__ WvB,
    unsigned short* __restrict__ Woutb)
{
    int idx = blockIdx.x * 256 + threadIdx.x;
    if (idx < 1572864) {
        int nrow = idx >> 10;
        float v;
        if      (nrow < 512)  v = Wq[idx];
        else if (nrow < 1024) v = Wk[idx - 512 * 1024];
        else                  v = Wo[idx - 1024 * 1024];
        Wcat1[idx] = f2b(v);
    } else if (idx < 2097152) {
        int j = idx - 1572864;
        WvB[j] = f2b(Wv[j]);
    } else {
        int j = idx - 2097152;
        Woutb[j] = f2b(Wout[j]);
    }
}

// ---------------- RMSNorm + zi/zf ----------------
__global__ __launch_bounds__(256) void norm_kernel(
    const float* __restrict__ x, const float* __restrict__ nw,
    const float* __restrict__ wi, const float* __restrict__ wf,
    const float* __restrict__ wib, const float* __restrict__ wfb,
    unsigned short* __restrict__ normed, float* __restrict__ zi, float* __restrict__ zf)
{
    int t = blockIdx.x, tid = threadIdx.x;
    float4 xv = ((const float4*)(x + (size_t)t * DM))[tid];
    float ss = xv.x * xv.x + xv.y * xv.y + xv.z * xv.z + xv.w * xv.w;
#pragma unroll
    for (int m = 1; m < 64; m <<= 1) ss += __shfl_xor(ss, m, 64);
    __shared__ float sred[4];
    __shared__ float sred2[8];
    if ((tid & 63) == 0) sred[tid >> 6] = ss;
    __syncthreads();
    ss = sred[0] + sred[1] + sred[2] + sred[3];
    float rstd = rsqrtf(ss * (1.0f / DM) + 1e-6f);
    float4 nwv = ((const float4*)nw)[tid];
    float n0 = xv.x * rstd * nwv.x, n1 = xv.y * rstd * nwv.y;
    float n2 = xv.z * rstd * nwv.z, n3 = xv.w * rstd * nwv.w;
    ushort4 pk;
    pk.x = f2b(n0); pk.y = f2b(n1); pk.z = f2b(n2); pk.w = f2b(n3);
    ((ushort4*)(normed + (size_t)t * DM))[tid] = pk;
    float4 wiv = ((const float4*)wi)[tid];
    float4 wfv = ((const float4*)wf)[tid];
    float pzi = n0 * wiv.x + n1 * wiv.y + n2 * wiv.z + n3 * wiv.w;
    float pzf = n0 * wfv.x + n1 * wfv.y + n2 * wfv.z + n3 * wfv.w;
#pragma unroll
    for (int m = 1; m < 64; m <<= 1) {
        pzi += __shfl_xor(pzi, m, 64);
        pzf += __shfl_xor(pzf, m, 64);
    }
    if ((tid & 63) == 0) { sred2[tid >> 6] = pzi; sred2[4 + (tid >> 6)] = pzf; }
    __syncthreads();
    if (tid == 0) {
        zi[t] = sred2[0] + sred2[1] + sred2[2] + sred2[3] + wib[0];
        zf[t] = sred2[4] + sred2[5] + sred2[6] + sred2[7] + wfb[0];
    }
}

// ---------------- parallel scans: u = zi - cumsum(zf), a = runmax(u) ------
__global__ __launch_bounds__(256) void mscan2_kernel(
    const float* __restrict__ zi, const float* __restrict__ zf,
    float* __restrict__ u, float* __restrict__ a)
{
    int b = blockIdx.x, tid = threadIdx.x, lane = tid & 63, wid = tid >> 6;
    size_t base = (size_t)b * T_SEQ + tid * 8;
    float z_f[8], z_i[8];
    *(float4*)&z_f[0] = *(const float4*)&zf[base];
    *(float4*)&z_f[4] = *(const float4*)&zf[base + 4];
    *(float4*)&z_i[0] = *(const float4*)&zi[base];
    *(float4*)&z_i[4] = *(const float4*)&zi[base + 4];
    __shared__ float wt[4];
    float c8[8]; float run = 0.0f;
#pragma unroll
    for (int i = 0; i < 8; ++i) { run += z_f[i]; c8[i] = run; }
    float v = run;
#pragma unroll
    for (int d = 1; d < 64; d <<= 1) {
        float o = __shfl_up(v, d, 64);
        if (lane >= d) v += o;
    }
    if (lane == 63) wt[wid] = v;
    __syncthreads();
    float woff = 0.0f;
    for (int j = 0; j < wid; ++j) woff += wt[j];
    float excl = __shfl_up(v, 1, 64);
    if (lane == 0) excl = 0.0f;
    float pre = woff + excl;
    float uu[8];
#pragma unroll
    for (int i = 0; i < 8; ++i) uu[i] = z_i[i] - (pre + c8[i]);
    *(float4*)&u[base] = *(float4*)&uu[0];
    *(float4*)&u[base + 4] = *(float4*)&uu[4];
    __syncthreads();
    float m8[8]; float rm = -INFINITY;
#pragma unroll
    for (int i = 0; i < 8; ++i) { rm = fmaxf(rm, uu[i]); m8[i] = rm; }
    float mv = rm;
#pragma unroll
    for (int d = 1; d < 64; d <<= 1) {
        float o = __shfl_up(mv, d, 64);
        if (lane >= d) mv = fmaxf(mv, o);
    }
    if (lane == 63) wt[wid] = mv;
    __syncthreads();
    float moff = -INFINITY;
    for (int j = 0; j < wid; ++j) moff = fmaxf(moff, wt[j]);
    float mexcl = __shfl_up(mv, 1, 64);
    if (lane == 0) mexcl = -INFINITY;
    float mpre = fmaxf(moff, mexcl);
    float aa[8];
#pragma unroll
    for (int i = 0; i < 8; ++i) aa[i] = fmaxf(mpre, m8[i]);
    *(float4*)&a[base] = *(float4*)&aa[0];
    *(float4*)&a[base + 4] = *(float4*)&aa[4];
}

// ---------------- 128x128 bf16 MFMA GEMM (2-phase structure) -------------
// kept only for the 512x16384 V-projection (M=512 needs 128-tile for grid)
template <int EPI, int ORD>
__global__ __launch_bounds__(256, 4) void gemm_bt(
    const unsigned short* __restrict__ A, const unsigned short* __restrict__ Bw,
    int M, int N, int K, int ldo,
    unsigned short* __restrict__ outb, const float* __restrict__ bo,
    float* __restrict__ outf, const float* __restrict__ xres)
{
    __shared__ unsigned short As[128 * 64];
    __shared__ unsigned short Bs[128 * 64];
    int tid = threadIdx.x;
    int l = tid & 63, w = tid >> 6;
    int cpx = gridDim.x >> 3;
    int wg = (blockIdx.x & 7) * cpx + (blockIdx.x >> 3);
    int mb = M >> 7;
    int nb = N >> 7;
    int bm, bn;
    if (ORD == 0) { bm = wg % mb; bn = wg / mb; }
    else          { bn = wg % nb; bm = wg / nb; }
    int wr = w >> 1, wc = w & 1;
    f32x4 acc[4][4] = {};
    const size_t abase = (size_t)(bm * 128) * K;
    const size_t bbase = (size_t)(bn * 128) * K;

    for (int ks = 0; ks < K; ks += 64) {
        __syncthreads();
#pragma unroll
        for (int i = 0; i < 4; ++i) {
            int off = (i * 256 + tid) * 8;
            int row = off >> 6, kc = off & 63;
            int kcs = kc ^ ((row & 7) << 3);
            gld_lds16(A + abase + (size_t)row * K + ks + kcs, &As[off]);
            gld_lds16(Bw + bbase + (size_t)row * K + ks + kcs, &Bs[off]);
        }
        __syncthreads();
#pragma unroll
        for (int kk = 0; kk < 2; ++kk) {
            int cbo = kk * 32 + (l >> 4) * 8;
            s8v af[4], bfv[4];
#pragma unroll
            for (int m = 0; m < 4; ++m) {
                int row = wr * 64 + m * 16 + (l & 15);
                af[m] = *(const s8v*)&As[row * 64 + (cbo ^ ((row & 7) << 3))];
            }
#pragma unroll
            for (int n = 0; n < 4; ++n) {
                int row = wc * 64 + n * 16 + (l & 15);
                bfv[n] = *(const s8v*)&Bs[row * 64 + (cbo ^ ((row & 7) << 3))];
            }
#pragma unroll
            for (int m = 0; m < 4; ++m)
#pragma unroll
                for (int n = 0; n < 4; ++n)
                    acc[m][n] = __builtin_amdgcn_mfma_f32_16x16x32_bf16(af[m], bfv[n], acc[m][n], 0, 0, 0);
        }
    }

#pragma unroll
    for (int m = 0; m < 4; ++m) {
#pragma unroll
        for (int n = 0; n < 4; ++n) {
            int col = bn * 128 + wc * 64 + n * 16 + (l & 15);
#pragma unroll
            for (int r = 0; r < 4; ++r) {
                int row = bm * 128 + wr * 64 + m * 16 + (l >> 4) * 4 + r;
                float v = acc[m][n][r];
                if (EPI == 0) {
                    if (col < 1024) v *= QKSCALE;
                    else {
                        float s = v + bo[col - 1024];
                        v = 1.0f / (1.0f + expf(-s));
                    }
                    outb[(size_t)row * ldo + col] = f2b(v);
                } else if (EPI == 3) {
                    outb[(size_t)row * ldo + col] = f2b(v);
                } else {
                    size_t idx = (size_t)row * ldo + col;
                    outf[idx] = xres[idx] + v;
                }
            }
        }
    }
}

// ---------------- 256x256 bf16 MFMA GEMM, 8-phase counted-vmcnt ----------
// BM=BN=256, BK=64, 512 threads (8 waves, 2Mx4N). LDS: 2 bufs x {A,B} x
// 2 K-half slots [256][32] bf16 = 128 KiB -> 1 block/CU, 2 waves/SIMD.
// Per K-tile: 4 phases {kh0/qm0, kh0/qm1, kh1/qm0, kh1/qm1}, 16 MFMA each.
// Stage 1 half-slot/phase: P0/P1 -> tile t+1 k1 (buf^1), P2/P3 -> tile t+2
// k0 (own buf; slots dead after P1). Waits: vmcnt(8) at end of P1 and P3
// (4 half-slots in flight across barriers; FIFO-derived tail counts).
// Swizzle: c ^= ((row>>1)&3)<<3 within 32-col rows (2 lanes/16B-slot: free),
// applied on pre-swizzled global source + swizzled ds_read (rule 21).
template <int B0>
__device__ __forceinline__ void mfma16(f32x4 (&acc)[8][4], const s8v (&af)[4], const s8v (&bf)[4]) {
#pragma unroll
    for (int m = 0; m < 4; ++m)
#pragma unroll
        for (int n = 0; n < 4; ++n)
            acc[B0 + m][n] = __builtin_amdgcn_mfma_f32_16x16x32_bf16(af[m], bf[n], acc[B0 + m][n], 0, 0, 0);
}

template <int EPI>
__global__ __launch_bounds__(512, 2) void gemm256(
    const unsigned short* __restrict__ A, const unsigned short* __restrict__ Bw,
    int M, int N, int K, int ldo,
    unsigned short* __restrict__ outb, const float* __restrict__ bo,
    float* __restrict__ outf, const float* __restrict__ xres)
{
    __shared__ unsigned short As[2 * 2 * 8192];   // [buf][kh][256][32]
    __shared__ unsigned short Bs[2 * 2 * 8192];
    int tid = threadIdx.x;
    int l = tid & 63, w = tid >> 6;
    int wr = w >> 2, wc = w & 3;
    int cpx = gridDim.x >> 3;
    int wg = (blockIdx.x & 7) * cpx + (blockIdx.x >> 3);
    int nb = N >> 8;
    int bn = wg % nb, bm = wg / nb;               // bn-minor (A >> B reuse)
    const unsigned short* Ab = A + (size_t)(bm * 256) * K;
    const unsigned short* Bb = Bw + (size_t)(bn * 256) * K;
    const int NKT = K >> 6;

    // per-thread staging geometry: granule gi = i*512+tid -> (row=gi>>2, j=gi&3)
    int srow = tid >> 2;
    int scol = ((tid & 3) << 3) ^ (((srow >> 1) & 3) << 3);
    size_t r0K = (size_t)srow * K + scol;
    size_t r1K = r0K + (size_t)128 * K;           // row+128: same swizzle bits
    int d0 = tid * 8, d1 = d0 + 4096;

    // fragment LDS element indices (within one [256][32] slot)
    int c8 = (l >> 4) << 3;
    int iA[8], iB[4];
#pragma unroll
    for (int mf = 0; mf < 8; ++mf) {
        int ra = wr * 128 + mf * 16 + (l & 15);
        iA[mf] = ra * 32 + (c8 ^ (((ra >> 1) & 3) << 3));
    }
#pragma unroll
    for (int n = 0; n < 4; ++n) {
        int rb = wc * 64 + n * 16 + (l & 15);
        iB[n] = rb * 32 + (c8 ^ (((rb >> 1) & 3) << 3));
    }

    f32x4 acc[8][4] = {};
    s8v af[4], bf[4];

#define STAGE(srcb, kscol, ldsb) do { \
        gld_lds16((srcb) + r0K + (kscol), (ldsb) + d0); \
        gld_lds16((srcb) + r1K + (kscol), (ldsb) + d1); } while (0)

    // prologue: tile0 {k0,k1} + tile1 k0  (12 loads; allow tile1 k0 in flight)
    STAGE(Ab, 0, As);
    STAGE(Bb, 0, Bs);
    STAGE(Ab, 32, As + 8192);
    STAGE(Bb, 32, Bs + 8192);
    STAGE(Ab, 64, As + 16384);
    STAGE(Bb, 64, Bs + 16384);
    WAITV(8);
    BARSYNC();

    for (int kt = 0; kt < NKT; ++kt) {
        int q = kt & 1, ks = kt << 6;
        const unsigned short* Aq = As + q * 16384;
        const unsigned short* Bq = Bs + q * 16384;
        unsigned short* An1 = As + (q ^ 1) * 16384 + 8192;   // (t+1).k1
        unsigned short* Bn1 = Bs + (q ^ 1) * 16384 + 8192;
        unsigned short* An2 = As + q * 16384;                // (t+2).k0
        unsigned short* Bn2 = Bs + q * 16384;

        // ---- P0: kh0, qm0 ----
#pragma unroll
        for (int n = 0; n < 4; ++n) bf[n] = *(const s8v*)&Bq[iB[n]];
#pragma unroll
        for (int m = 0; m < 4; ++m) af[m] = *(const s8v*)&Aq[iA[m]];
        if (kt + 1 < NKT) STAGE(Ab, ks + 96, An1);
        BARSYNC();
        __builtin_amdgcn_s_setprio(1);
        mfma16<0>(acc, af, bf);
        __builtin_amdgcn_s_setprio(0);
        BARSYNC();
        // ---- P1: kh0, qm1 ----
#pragma unroll
        for (int m = 0; m < 4; ++m) af[m] = *(const s8v*)&Aq[iA[4 + m]];
        if (kt + 1 < NKT) STAGE(Bb, ks + 96, Bn1);
        BARSYNC();
        __builtin_amdgcn_s_setprio(1);
        mfma16<4>(acc, af, bf);
        __builtin_amdgcn_s_setprio(0);
        if (kt < NKT - 1) { WAITV(8); } else { WAITV(0); }   // (t).k1 ready
        BARSYNC();
        // ---- P2: kh1, qm0 ----
#pragma unroll
        for (int n = 0; n < 4; ++n) bf[n] = *(const s8v*)&Bq[8192 + iB[n]];
#pragma unroll
        for (int m = 0; m < 4; ++m) af[m] = *(const s8v*)&Aq[8192 + iA[m]];
        if (kt + 2 < NKT) STAGE(Ab, ks + 128, An2);
        BARSYNC();
        __builtin_amdgcn_s_setprio(1);
        mfma16<0>(acc, af, bf);
        __builtin_amdgcn_s_setprio(0);
        BARSYNC();
        // ---- P3: kh1, qm1 ----
#pragma unroll
        for (int m = 0; m < 4; ++m) af[m] = *(const s8v*)&Aq[8192 + iA[4 + m]];
        if (kt + 2 < NKT) STAGE(Bb, ks + 128, Bn2);
        BARSYNC();
        __builtin_amdgcn_s_setprio(1);
        mfma16<4>(acc, af, bf);
        __builtin_amdgcn_s_setprio(0);
        if (kt < NKT - 2) { WAITV(8); }                      // (t+1).k0 ready
        else if (kt == NKT - 2) { WAITV(4); }
        else { WAITV(0); }
        BARSYNC();
    }
#undef STAGE

    // epilogue
#pragma unroll
    for (int mf = 0; mf < 8; ++mf) {
#pragma unroll
        for (int n = 0; n < 4; ++n) {
            int col = bn * 256 + wc * 64 + n * 16 + (l & 15);
#pragma unroll
            for (int r = 0; r < 4; ++r) {
                int row = bm * 256 + wr * 128 + mf * 16 + (l >> 4) * 4 + r;
                float v = acc[mf][n][r];
                if (EPI == 0) {
                    if (col < 1024) v *= QKSCALE;
                    else {
                        float s = v + bo[col - 1024];
                        v = 1.0f / (1.0f + expf(-s));
                    }
                    outb[(size_t)row * ldo + col] = f2b(v);
                } else {
                    size_t idx = (size_t)row * ldo + col;
                    outf[idx] = xres[idx] + v;
                }
            }
        }
    }
}

// ---------------- ktrans: kvT[s][t] = qko[t][512+s] (k, already scaled) ----
__global__ __launch_bounds__(256) void ktrans_kernel(
    const unsigned short* __restrict__ qko, unsigned short* __restrict__ kvT)
{
    __shared__ unsigned short T[64][72];
    int st = blockIdx.x & 7, tt = blockIdx.x >> 3;
    int t0 = tt * 64, s0 = st * 64;
    int tid = threadIdx.x;
    int ir = tid >> 3, jc = (tid & 7) * 8;
#pragma unroll
    for (int rr = 0; rr < 2; ++rr) {
        int row = rr * 32 + ir;
        s8v v = *(const s8v*)&qko[(size_t)(t0 + row) * 1536 + 512 + s0 + jc];
#pragma unroll
        for (int e = 0; e < 8; ++e) T[jc + e][row] = (unsigned short)v[e];
    }
    __syncthreads();
#pragma unroll
    for (int rr = 0; rr < 2; ++rr) {
        int srow = rr * 32 + ir;
        s8v o = *(const s8v*)&T[srow][jc];
        *(s8v*)&kvT[(size_t)(s0 + srow) * MROWS + t0 + jc] = o;
    }
}

// ---------------- phase A: St[t][j] = exp(u_j - a_t)*(q_t.k_j), j<=t ------
__global__ __launch_bounds__(256) void phaseA_kernel(
    const unsigned short* __restrict__ qko,
    const float* __restrict__ u, const float* __restrict__ a,
    unsigned short* __restrict__ st, float* __restrict__ rowsum)
{
    __shared__ unsigned short Qs[64 * 32], Ks[128 * 32];
    int bid = blockIdx.x;
    int b = bid & 7, c = (bid >> 3) & 15, th = bid >> 7;
    int tid = threadIdx.x, l = tid & 63, wv = tid >> 6;
    size_t cb = (size_t)b * T_SEQ + c * CL;
    f32x4 acc[8] = {};
    for (int ks = 0; ks < 512; ks += 32) {
        __syncthreads();
        {
            int p = tid;
            int row = p >> 2, kc = (p & 3) * 8;
            gld_lds16(qko + (cb + th * 64 + row) * 1536 + ks + kc, &Qs[p * 8]);
#pragma unroll
            for (int rI = 0; rI < 2; ++rI) {
                int pp = rI * 256 + tid;
                int rw = pp >> 2, kk = (pp & 3) * 8;
                gld_lds16(qko + (cb + rw) * 1536 + 512 + ks + kk, &Ks[pp * 8]);
            }
        }
        __syncthreads();
        s8v af = *(const s8v*)&Qs[(wv * 16 + (l & 15)) * 32 + (l >> 4) * 8];
#pragma unroll
        for (int n = 0; n < 8; ++n) {
            s8v bf = *(const s8v*)&Ks[(n * 16 + (l & 15)) * 32 + (l >> 4) * 8];
            acc[n] = __builtin_amdgcn_mfma_f32_16x16x32_bf16(af, bf, acc[n], 0, 0, 0);
        }
    }
    float rs[4] = {0.f, 0.f, 0.f, 0.f};
    size_t stb = (size_t)(b * NC + c) * (CL * CL);
#pragma unroll
    for (int e = 0; e < 4; ++e) {
        int tl = th * 64 + wv * 16 + (l >> 4) * 4 + e;
        float a_t = a[cb + tl];
#pragma unroll
        for (int n = 0; n < 8; ++n) {
            int j = n * 16 + (l & 15);
            float val = (j <= tl) ? acc[n][e] * expf(u[cb + j] - a_t) : 0.0f;
            rs[e] += val;
            st[stb + (size_t)tl * CL + j] = f2b(val);
        }
    }
#pragma unroll
    for (int e = 0; e < 4; ++e) {
#pragma unroll
        for (int m = 1; m < 16; m <<= 1) rs[e] += __shfl_xor(rs[e], m, 64);
    }
    if ((l & 15) == 0) {
#pragma unroll
        for (int e = 0; e < 4; ++e)
            rowsum[cb + th * 64 + wv * 16 + (l >> 4) * 4 + e] = rs[e];
    }
}

// ---------------- kwprep: kw[s][t] = w_t * k_t[s]; P = chunk row-sums ----
__global__ __launch_bounds__(256) void kwprep_kernel(
    const unsigned short* __restrict__ kvT,
    const float* __restrict__ u, const float* __restrict__ a,
    unsigned short* __restrict__ kw, float* __restrict__ P, float* __restrict__ aE)
{
    int bid = blockIdx.x;
    int b = bid & 7, c = (bid >> 3) & 15, sb = bid >> 7;
    int tid = threadIdx.x;
    int s = sb * 16 + (tid >> 4), jg = tid & 15;
    size_t cb = (size_t)b * T_SEQ + c * CL;
    __shared__ float w_l[CL];
    float a_e = a[cb + CL - 1];
    if (tid < CL) w_l[tid] = expf(u[cb + tid] - a_e);
    if (tid == 0 && sb == 0) aE[b * NC + c] = a_e;
    __syncthreads();
    s8v kv = *(const s8v*)&kvT[(size_t)s * MROWS + cb + jg * 8];
    s8v kwv;
    float psum = 0.0f;
#pragma unroll
    for (int e = 0; e < 8; ++e) {
        float f = b2f((unsigned short)kv[e]) * w_l[jg * 8 + e];
        kwv[e] = (short)f2b(f);
        psum += f;
    }
    *(s8v*)&kw[(size_t)s * MROWS + cb + jg * 8] = kwv;
#pragma unroll
    for (int m = 1; m < 16; m <<= 1) psum += __shfl_xor(psum, m, 64);
    if (jg == 0) P[(size_t)(b * NC + c) * 512 + s] = psum;
}

// nhprev[b][c][s] = n-state before chunk c (ref aE[c-1]); scan over c.
__global__ __launch_bounds__(256) void nhscan_kernel(
    const float* __restrict__ P, const float* __restrict__ aE,
    float* __restrict__ nhprev)
{
    int gid = blockIdx.x * 256 + threadIdx.x;   // 0..4095
    int b = gid >> 9, s = gid & 511;
    float nh = 0.0f, aprev = 0.0f;
    for (int c = 0; c < NC; ++c) {
        nhprev[(size_t)(b * NC + c) * 512 + s] = nh;
        float ae = aE[b * NC + c];
        float gam = (c == 0) ? 0.0f : expf(aprev - ae);
        nh = gam * nh + P[(size_t)(b * NC + c) * 512 + s];
        aprev = ae;
    }
}

// rdnm[t] = 1 / max(|beta_t*(q_t.nhprev) + rowsum[t]|, 1)
__global__ __launch_bounds__(256) void denom_kernel(
    const unsigned short* __restrict__ qko, const float* __restrict__ nhprev,
    const float* __restrict__ aE, const float* __restrict__ a,
    const float* __restrict__ rowsum, float* __restrict__ rdnm)
{
    int wv = threadIdx.x >> 6, l = threadIdx.x & 63;
    int t = blockIdx.x * 4 + wv;      // 0..16383
    int b = t >> 11, c = (t & 2047) >> 7;
    const unsigned short* qrow = qko + (size_t)t * 1536 + l * 8;
    const float* nh = nhprev + (size_t)(b * NC + c) * 512 + l * 8;
    s8v qv = *(const s8v*)qrow;
    float4 n0 = *(const float4*)nh;
    float4 n1 = *(const float4*)(nh + 4);
    float nq = b2f((unsigned short)qv[0]) * n0.x + b2f((unsigned short)qv[1]) * n0.y
             + b2f((unsigned short)qv[2]) * n0.z + b2f((unsigned short)qv[3]) * n0.w
             + b2f((unsigned short)qv[4]) * n1.x + b2f((unsigned short)qv[5]) * n1.y
             + b2f((unsigned short)qv[6]) * n1.z + b2f((unsigned short)qv[7]) * n1.w;
#pragma unroll
    for (int m = 1; m < 64; m <<= 1) nq += __shfl_xor(nq, m, 64);
    if (l == 0) {
        float beta = (c == 0) ? 0.0f : expf(aE[b * NC + c - 1] - a[t]);
        rdnm[t] = 1.0f / fmaxf(fabsf(beta * nq + rowsum[t]), 1.0f);
    }
}

// ---------------- cscan: C checkpoints, 1 wave per (b, r-tile32, s-tile32) ----
__global__ __launch_bounds__(64) void cscan_kernel(
    const unsigned short* __restrict__ kvT, const unsigned short* __restrict__ kw,
    const float* __restrict__ aE, unsigned short* __restrict__ chk)
{
    int bid = blockIdx.x;
    int b = bid & 7, rt = (bid >> 3) & 15, stt = bid >> 7;
    int r0 = rt * 32, s0 = stt * 32;
    int l = threadIdx.x;
    size_t tb = (size_t)b * T_SEQ;
    f32x4 acc[2][2] = {};
    float a_prev = 0.0f;

    for (int c = 0; c < NC; ++c) {
        size_t cb = tb + c * CL;
        float a_e = aE[b * NC + c];
        if (c > 0) {
            unsigned short* slot = chk + (size_t)(b * (NC - 1) + (c - 1)) * (512 * 512);
#pragma unroll
            for (int m = 0; m < 2; ++m)
#pragma unroll
                for (int n = 0; n < 2; ++n)
#pragma unroll
                    for (int e = 0; e < 4; ++e) {
                        int r = r0 + m * 16 + (l >> 4) * 4 + e;
                        int s = s0 + n * 16 + (l & 15);
                        slot[r * 512 + s] = f2b(acc[m][n][e]);
                    }
            float gam = expf(a_prev - a_e);
#pragma unroll
            for (int m = 0; m < 2; ++m)
#pragma unroll
                for (int n = 0; n < 2; ++n)
#pragma unroll
                    for (int e = 0; e < 4; ++e) acc[m][n][e] *= gam;
        }
#pragma unroll
        for (int ks = 0; ks < 4; ++ks) {
            int jb = ks * 32 + (l >> 4) * 8;
            s8v vf[2], kf[2];
#pragma unroll
            for (int m = 0; m < 2; ++m)
                vf[m] = *(const s8v*)&kvT[(size_t)(512 + r0 + m * 16 + (l & 15)) * MROWS + cb + jb];
#pragma unroll
            for (int n = 0; n < 2; ++n)
                kf[n] = *(const s8v*)&kw[(size_t)(s0 + n * 16 + (l & 15)) * MROWS + cb + jb];
#pragma unroll
            for (int m = 0; m < 2; ++m)
#pragma unroll
                for (int n = 0; n < 2; ++n)
                    acc[m][n] = __builtin_amdgcn_mfma_f32_16x16x32_bf16(vf[m], kf[n], acc[m][n], 0, 0, 0);
        }
        a_prev = a_e;
    }
}

// ---------------- hout: G = beta*(Q.Cchk^T) + St.V ; h = o*G*rdnm ----------
__global__ __launch_bounds__(512) void hout_kernel(
    const unsigned short* __restrict__ qko, const unsigned short* __restrict__ kvT,
    const unsigned short* __restrict__ st, const unsigned short* __restrict__ chk,
    const float* __restrict__ a, const float* __restrict__ aE,
    const float* __restrict__ rdnm, unsigned short* __restrict__ g)
{
    int bid = blockIdx.x;
    int b = bid & 7, cc = bid >> 3;
    int c = cc >> 1, rh = cc & 1;
    int tid = threadIdx.x, l = tid & 63, wv = tid >> 6;
    int mq = wv & 3;
    int rr = (wv >> 2) * 128 + rh * 256;
    size_t cb = (size_t)b * T_SEQ + c * CL;
    f32x4 acc[2][8] = {};

    if (c > 0) {
        const unsigned short* slot = chk + (size_t)(b * (NC - 1) + (c - 1)) * (512 * 512);
#pragma unroll
        for (int ks = 0; ks < 16; ++ks) {
            s8v aq[2];
#pragma unroll
            for (int mf = 0; mf < 2; ++mf)
                aq[mf] = *(const s8v*)&qko[(cb + mq * 32 + mf * 16 + (l & 15)) * 1536 + ks * 32 + (l >> 4) * 8];
#pragma unroll
            for (int n = 0; n < 8; ++n) {
                s8v bc = *(const s8v*)&slot[(size_t)(rr + n * 16 + (l & 15)) * 512 + ks * 32 + (l >> 4) * 8];
                acc[0][n] = __builtin_amdgcn_mfma_f32_16x16x32_bf16(aq[0], bc, acc[0][n], 0, 0, 0);
                acc[1][n] = __builtin_amdgcn_mfma_f32_16x16x32_bf16(aq[1], bc, acc[1][n], 0, 0, 0);
            }
        }
        float aprev = aE[b * NC + c - 1];
#pragma unroll
        for (int mf = 0; mf < 2; ++mf)
#pragma unroll
            for (int e = 0; e < 4; ++e) {
                int t = mq * 32 + mf * 16 + (l >> 4) * 4 + e;
                float bta = expf(aprev - a[cb + t]);
#pragma unroll
                for (int n = 0; n < 8; ++n) acc[mf][n][e] *= bta;
            }
    }
    const unsigned short* stp = st + (size_t)(b * NC + c) * (CL * CL);
#pragma unroll
    for (int ks = 0; ks < 4; ++ks) {
        s8v aq[2];
#pragma unroll
        for (int mf = 0; mf < 2; ++mf)
            aq[mf] = *(const s8v*)&stp[(size_t)(mq * 32 + mf * 16 + (l & 15)) * CL + ks * 32 + (l >> 4) * 8];
#pragma unroll
        for (int n = 0; n < 8; ++n) {
            s8v bv = *(const s8v*)&kvT[(size_t)(512 + rr + n * 16 + (l & 15)) * MROWS + cb + ks * 32 + (l >> 4) * 8];
            acc[0][n] = __builtin_amdgcn_mfma_f32_16x16x32_bf16(aq[0], bv, acc[0][n], 0, 0, 0);
            acc[1][n] = __builtin_amdgcn_mfma_f32_16x16x32_bf16(aq[1], bv, acc[1][n], 0, 0, 0);
        }
    }
#pragma unroll
    for (int mf = 0; mf < 2; ++mf)
#pragma unroll
        for (int e = 0; e < 4; ++e) {
            int t = mq * 32 + mf * 16 + (l >> 4) * 4 + e;
            float rd = rdnm[cb + t];
#pragma unroll
            for (int n = 0; n < 8; ++n) {
                int r = rr + n * 16 + (l & 15);
                float ov = b2f(qko[(cb + t) * 1536 + 1024 + r]);
                g[(cb + t) * DH + r] = f2b(ov * acc[mf][n][e] * rd);
            }
        }
}

extern "C" void kernel_launch(void* const* d_in, const int* in_sizes, int n_in,
                              void* d_out, int out_size, void* d_ws, size_t ws_size,
                              hipStream_t stream)
{
    (void)in_sizes; (void)n_in; (void)out_size; (void)ws_size;
    const float* x    = (const float*)d_in[0];
    const float* nw   = (const float*)d_in[1];
    const float* Wq   = (const float*)d_in[2];
    const float* Wk   = (const float*)d_in[3];
    const float* Wv   = (const float*)d_in[4];
    const float* wi   = (const float*)d_in[5];
    const float* wib  = (const float*)d_in[6];
    const float* wf   = (const float*)d_in[7];
    const float* wfb  = (const float*)d_in[8];
    const float* Wo   = (const float*)d_in[9];
    const float* bo   = (const float*)d_in[10];
    const float* Wout = (const float*)d_in[11];
    float* out = (float*)d_out;

    char* ws = (char*)d_ws;
    unsigned short* qko    = (unsigned short*)ws;                        // 0 .. 50,331,648
    unsigned short* kvT    = (unsigned short*)(ws + 50331648);           // .. 83,886,080
    unsigned short* normed = (unsigned short*)(ws + 83886080);           // .. 117,440,512
    unsigned short* g      = normed;                                     // first 16 MB (normed dead)
    unsigned short* kw     = (unsigned short*)(ws + 100663296);          // 16 MB (normed dead)
    float* Pbuf   = (float*)(ws + 117440512);                            // 262,144 (Wcat1 dead)
    float* nhprev = (float*)(ws + 117702656);                            // 262,144
    float* aE     = (float*)(ws + 117964800);                            // 512
    unsigned short* Wcat1  = (unsigned short*)(ws + 117440512);          // 3 MB (dead after gemm256<0>)
    unsigned short* WvB    = (unsigned short*)(ws + 120586240);          // 1 MB
    unsigned short* Woutb  = (unsigned short*)(ws + 122683392);          // 1 MB
    float* zi     = (float*)(ws + 123731968);
    float* zf     = zi + MROWS;
    float* uarr   = zf + MROWS;
    float* aarr   = uarr + MROWS;
    float* rowsum = aarr + MROWS;
    float* rdnm   = rowsum + MROWS;                                      // ends ~124.1 MB

    // d_out as scratch until final gemm: Cchk (60 MiB) + stbuf (4 MiB)
    unsigned short* chk   = (unsigned short*)d_out;                      // 8*15*512*512*2
    unsigned short* stbuf = (unsigned short*)((char*)d_out + 62914560);  // 8*16*128*128*2

    convAll_kernel <<<10240, 256, 0, stream>>>(Wq, Wk, Wo, Wv, Wout, Wcat1, WvB, Woutb);
    norm_kernel    <<<MROWS, 256, 0, stream>>>(x, nw, wi, wf, wib, wfb, normed, zi, zf);
    mscan2_kernel  <<<NBATCH, 256, 0, stream>>>(zi, zf, uarr, aarr);
    // A=normed (32MB) >> B=Wcat1 (3MB): 256^2 8-phase, grid 64x6=384
    gemm256<0>     <<<384, 512, 0, stream>>>(normed, Wcat1, MROWS, 1536, DM, 1536, qko, bo, nullptr, nullptr);
    // k: transpose from qko (already scaled)
    ktrans_kernel  <<<2048, 256, 0, stream>>>(qko, kvT);
    // v only: A=WvB (1MB) << B=normed (32MB): M=512 -> keep 128-tile, ORD=0
    gemm_bt<3, 0>  <<<4 * 128, 256, 0, stream>>>(WvB, normed, 512, MROWS, DM, MROWS, kvT + (size_t)512 * MROWS, nullptr, nullptr, nullptr);
    phaseA_kernel  <<<256, 256, 0, stream>>>(qko, uarr, aarr, stbuf, rowsum);
    kwprep_kernel  <<<4096, 256, 0, stream>>>(kvT, uarr, aarr, kw, Pbuf, aE);
    nhscan_kernel  <<<16, 256, 0, stream>>>(Pbuf, aE, nhprev);
    denom_kernel   <<<4096, 256, 0, stream>>>(qko, nhprev, aE, aarr, rowsum, rdnm);
    cscan_kernel   <<<2048, 64, 0, stream>>>(kvT, kw, aE, chk);
    hout_kernel    <<<256, 512, 0, stream>>>(qko, kvT, stbuf, chk, aarr, aE, rdnm, g);
    // A=g (16MB) >> B=Woutb (1MB): 256^2 8-phase, grid 64x4=256 (1 block/CU)
    gemm256<1>     <<<256, 512, 0, stream>>>(g, Woutb, MROWS, DM, DH, DM, nullptr, nullptr, out, x);
}

// Round 2
// 331.835 us; speedup vs baseline: 1.0871x; 1.0871x over previous
//
#include <hip/hip_runtime.h>
#include <cstdint>
#include <cmath>

#define T_SEQ 2048
#define NBATCH 8
#define DM 1024
#define DH 512
#define MROWS (NBATCH * T_SEQ)   // 16384
#define NC 16                    // chunks per batch
#define CL 128                   // chunk length

typedef short s8v __attribute__((ext_vector_type(8)));
typedef float f32x4 __attribute__((ext_vector_type(4)));

typedef unsigned int __attribute__((address_space(1))) uint_g;
typedef unsigned int __attribute__((address_space(3))) uint_l;

#define QKSCALE 0.044194173824159216f   // 1/sqrt(512)

__device__ __forceinline__ float b2f(unsigned short s) {
    union { unsigned u; float f; } c; c.u = ((unsigned)s) << 16; return c.f;
}
__device__ __forceinline__ unsigned short f2b(float f) {
    union { float f; unsigned u; } c; c.f = f;
    unsigned r = c.u + 0x7fffu + ((c.u >> 16) & 1u);
    return (unsigned short)(r >> 16);
}
__device__ __forceinline__ void gld_lds16(const void* g, void* l) {
    __builtin_amdgcn_global_load_lds((const uint_g*)g, (uint_l*)l, 16, 0, 0);
}

#define WAITV(N) asm volatile("s_waitcnt vmcnt(" #N ")" ::: "memory")
#define BARSYNC() do { asm volatile("" ::: "memory"); __builtin_amdgcn_s_barrier(); asm volatile("" ::: "memory"); } while (0)

// ---------------- weight conversion (merged) ----------------
__global__ __launch_bounds__(256) void convAll_kernel(
    const float* __restrict__ Wq, const float* __restrict__ Wk,
    const float* __restrict__ Wo, const float* __restrict__ Wv,
    const float* __restrict__ Wout,
    unsigned short* __restrict__ Wcat1, unsigned short* __restrict__ WvB,
    unsigned short* __restrict__ Woutb)
{
    int idx = blockIdx.x * 256 + threadIdx.x;
    if (idx < 1572864) {
        int nrow = idx >> 10;
        float v;
        if      (nrow < 512)  v = Wq[idx];
        else if (nrow < 1024) v = Wk[idx - 512 * 1024];
        else                  v = Wo[idx - 1024 * 1024];
        Wcat1[idx] = f2b(v);
    } else if (idx < 2097152) {
        int j = idx - 1572864;
        WvB[j] = f2b(Wv[j]);
    } else {
        int j = idx - 2097152;
        Woutb[j] = f2b(Wout[j]);
    }
}

// ---------------- RMSNorm + zi/zf ----------------
__global__ __launch_bounds__(256) void norm_kernel(
    const float* __restrict__ x, const float* __restrict__ nw,
    const float* __restrict__ wi, const float* __restrict__ wf,
    const float* __restrict__ wib, const float* __restrict__ wfb,
    unsigned short* __restrict__ normed, float* __restrict__ zi, float* __restrict__ zf)
{
    int t = blockIdx.x, tid = threadIdx.x;
    float4 xv = ((const float4*)(x + (size_t)t * DM))[tid];
    float ss = xv.x * xv.x + xv.y * xv.y + xv.z * xv.z + xv.w * xv.w;
#pragma unroll
    for (int m = 1; m < 64; m <<= 1) ss += __shfl_xor(ss, m, 64);
    __shared__ float sred[4];
    __shared__ float sred2[8];
    if ((tid & 63) == 0) sred[tid >> 6] = ss;
    __syncthreads();
    ss = sred[0] + sred[1] + sred[2] + sred[3];
    float rstd = rsqrtf(ss * (1.0f / DM) + 1e-6f);
    float4 nwv = ((const float4*)nw)[tid];
    float n0 = xv.x * rstd * nwv.x, n1 = xv.y * rstd * nwv.y;
    float n2 = xv.z * rstd * nwv.z, n3 = xv.w * rstd * nwv.w;
    ushort4 pk;
    pk.x = f2b(n0); pk.y = f2b(n1); pk.z = f2b(n2); pk.w = f2b(n3);
    ((ushort4*)(normed + (size_t)t * DM))[tid] = pk;
    float4 wiv = ((const float4*)wi)[tid];
    float4 wfv = ((const float4*)wf)[tid];
    float pzi = n0 * wiv.x + n1 * wiv.y + n2 * wiv.z + n3 * wiv.w;
    float pzf = n0 * wfv.x + n1 * wfv.y + n2 * wfv.z + n3 * wfv.w;
#pragma unroll
    for (int m = 1; m < 64; m <<= 1) {
        pzi += __shfl_xor(pzi, m, 64);
        pzf += __shfl_xor(pzf, m, 64);
    }
    if ((tid & 63) == 0) { sred2[tid >> 6] = pzi; sred2[4 + (tid >> 6)] = pzf; }
    __syncthreads();
    if (tid == 0) {
        zi[t] = sred2[0] + sred2[1] + sred2[2] + sred2[3] + wib[0];
        zf[t] = sred2[4] + sred2[5] + sred2[6] + sred2[7] + wfb[0];
    }
}

// ---------------- parallel scans: u = zi - cumsum(zf), a = runmax(u) ------
__global__ __launch_bounds__(256) void mscan2_kernel(
    const float* __restrict__ zi, const float* __restrict__ zf,
    float* __restrict__ u, float* __restrict__ a)
{
    int b = blockIdx.x, tid = threadIdx.x, lane = tid & 63, wid = tid >> 6;
    size_t base = (size_t)b * T_SEQ + tid * 8;
    float z_f[8], z_i[8];
    *(float4*)&z_f[0] = *(const float4*)&zf[base];
    *(float4*)&z_f[4] = *(const float4*)&zf[base + 4];
    *(float4*)&z_i[0] = *(const float4*)&zi[base];
    *(float4*)&z_i[4] = *(const float4*)&zi[base + 4];
    __shared__ float wt[4];
    float c8[8]; float run = 0.0f;
#pragma unroll
    for (int i = 0; i < 8; ++i) { run += z_f[i]; c8[i] = run; }
    float v = run;
#pragma unroll
    for (int d = 1; d < 64; d <<= 1) {
        float o = __shfl_up(v, d, 64);
        if (lane >= d) v += o;
    }
    if (lane == 63) wt[wid] = v;
    __syncthreads();
    float woff = 0.0f;
    for (int j = 0; j < wid; ++j) woff += wt[j];
    float excl = __shfl_up(v, 1, 64);
    if (lane == 0) excl = 0.0f;
    float pre = woff + excl;
    float uu[8];
#pragma unroll
    for (int i = 0; i < 8; ++i) uu[i] = z_i[i] - (pre + c8[i]);
    *(float4*)&u[base] = *(float4*)&uu[0];
    *(float4*)&u[base + 4] = *(float4*)&uu[4];
    __syncthreads();
    float m8[8]; float rm = -INFINITY;
#pragma unroll
    for (int i = 0; i < 8; ++i) { rm = fmaxf(rm, uu[i]); m8[i] = rm; }
    float mv = rm;
#pragma unroll
    for (int d = 1; d < 64; d <<= 1) {
        float o = __shfl_up(mv, d, 64);
        if (lane >= d) mv = fmaxf(mv, o);
    }
    if (lane == 63) wt[wid] = mv;
    __syncthreads();
    float moff = -INFINITY;
    for (int j = 0; j < wid; ++j) moff = fmaxf(moff, wt[j]);
    float mexcl = __shfl_up(mv, 1, 64);
    if (lane == 0) mexcl = -INFINITY;
    float mpre = fmaxf(moff, mexcl);
    float aa[8];
#pragma unroll
    for (int i = 0; i < 8; ++i) aa[i] = fmaxf(mpre, m8[i]);
    *(float4*)&a[base] = *(float4*)&aa[0];
    *(float4*)&a[base + 4] = *(float4*)&aa[4];
}

// ---------------- merged QKO + V projection, 128x128 bf16 MFMA ----------
// 2048 blocks = exactly 2 full rounds at 4 blocks/CU (no tail).
// wg < 1536: qko tile (M=16384, N=1536, bn-minor);  wg >= 1536: v-proj
// tile (M=512 of WvB, N=16384 of normed, bm-minor). Same K=1024 and
// identical inner loop -> rounds stay balanced. XCD swizzle partitions
// XCD0-5 = qko, XCD6-7 = v-proj (clean per-XCD L2 streams).
__global__ __launch_bounds__(256, 4) void gemm_qkv(
    const unsigned short* __restrict__ normed, const unsigned short* __restrict__ Wcat1,
    const unsigned short* __restrict__ WvB, int K,
    unsigned short* __restrict__ qko, const float* __restrict__ bo,
    unsigned short* __restrict__ vout)
{
    __shared__ unsigned short As[128 * 64];
    __shared__ unsigned short Bs[128 * 64];
    int tid = threadIdx.x;
    int l = tid & 63, w = tid >> 6;
    int wg = (blockIdx.x & 7) * 256 + (blockIdx.x >> 3);   // bijective, 2048 blocks
    int job = (wg >= 1536) ? 1 : 0;
    const unsigned short* A;
    const unsigned short* Bw;
    int bm, bn;
    if (job == 0) { A = normed; Bw = Wcat1; bn = wg % 12; bm = wg / 12; }
    else          { int w2 = wg - 1536; A = WvB; Bw = normed; bm = w2 & 3; bn = w2 >> 2; }
    int wr = w >> 1, wc = w & 1;
    f32x4 acc[4][4] = {};
    const size_t abase = (size_t)(bm * 128) * K;
    const size_t bbase = (size_t)(bn * 128) * K;

    for (int ks = 0; ks < K; ks += 64) {
        __syncthreads();
#pragma unroll
        for (int i = 0; i < 4; ++i) {
            int off = (i * 256 + tid) * 8;
            int row = off >> 6, kc = off & 63;
            int kcs = kc ^ ((row & 7) << 3);
            gld_lds16(A + abase + (size_t)row * K + ks + kcs, &As[off]);
            gld_lds16(Bw + bbase + (size_t)row * K + ks + kcs, &Bs[off]);
        }
        __syncthreads();
#pragma unroll
        for (int kk = 0; kk < 2; ++kk) {
            int cbo = kk * 32 + (l >> 4) * 8;
            s8v af[4], bfv[4];
#pragma unroll
            for (int m = 0; m < 4; ++m) {
                int row = wr * 64 + m * 16 + (l & 15);
                af[m] = *(const s8v*)&As[row * 64 + (cbo ^ ((row & 7) << 3))];
            }
#pragma unroll
            for (int n = 0; n < 4; ++n) {
                int row = wc * 64 + n * 16 + (l & 15);
                bfv[n] = *(const s8v*)&Bs[row * 64 + (cbo ^ ((row & 7) << 3))];
            }
#pragma unroll
            for (int m = 0; m < 4; ++m)
#pragma unroll
                for (int n = 0; n < 4; ++n)
                    acc[m][n] = __builtin_amdgcn_mfma_f32_16x16x32_bf16(af[m], bfv[n], acc[m][n], 0, 0, 0);
        }
    }

    if (job == 0) {
#pragma unroll
        for (int m = 0; m < 4; ++m) {
#pragma unroll
            for (int n = 0; n < 4; ++n) {
                int col = bn * 128 + wc * 64 + n * 16 + (l & 15);
#pragma unroll
                for (int r = 0; r < 4; ++r) {
                    int row = bm * 128 + wr * 64 + m * 16 + (l >> 4) * 4 + r;
                    float v = acc[m][n][r];
                    if (col < 1024) v *= QKSCALE;
                    else {
                        float s = v + bo[col - 1024];
                        v = 1.0f / (1.0f + expf(-s));
                    }
                    qko[(size_t)row * 1536 + col] = f2b(v);
                }
            }
        }
    } else {
#pragma unroll
        for (int m = 0; m < 4; ++m) {
#pragma unroll
            for (int n = 0; n < 4; ++n) {
                int col = bn * 128 + wc * 64 + n * 16 + (l & 15);
#pragma unroll
                for (int r = 0; r < 4; ++r) {
                    int row = bm * 128 + wr * 64 + m * 16 + (l >> 4) * 4 + r;
                    vout[(size_t)row * MROWS + col] = f2b(acc[m][n][r]);
                }
            }
        }
    }
}

// ---------------- 256x256 bf16 MFMA GEMM, 8-phase counted-vmcnt ----------
// Used ONLY for the output GEMM (grid 256 = exact 1 round; measured faster
// than the 128^2 structure there). NOT used where grid would exceed 256.
template <int B0>
__device__ __forceinline__ void mfma16(f32x4 (&acc)[8][4], const s8v (&af)[4], const s8v (&bf)[4]) {
#pragma unroll
    for (int m = 0; m < 4; ++m)
#pragma unroll
        for (int n = 0; n < 4; ++n)
            acc[B0 + m][n] = __builtin_amdgcn_mfma_f32_16x16x32_bf16(af[m], bf[n], acc[B0 + m][n], 0, 0, 0);
}

template <int EPI>
__global__ __launch_bounds__(512, 2) void gemm256(
    const unsigned short* __restrict__ A, const unsigned short* __restrict__ Bw,
    int M, int N, int K, int ldo,
    unsigned short* __restrict__ outb, const float* __restrict__ bo,
    float* __restrict__ outf, const float* __restrict__ xres)
{
    __shared__ unsigned short As[2 * 2 * 8192];   // [buf][kh][256][32]
    __shared__ unsigned short Bs[2 * 2 * 8192];
    int tid = threadIdx.x;
    int l = tid & 63, w = tid >> 6;
    int wr = w >> 2, wc = w & 3;
    int cpx = gridDim.x >> 3;
    int wg = (blockIdx.x & 7) * cpx + (blockIdx.x >> 3);
    int nb = N >> 8;
    int bn = wg % nb, bm = wg / nb;               // bn-minor (A >> B reuse)
    const unsigned short* Ab = A + (size_t)(bm * 256) * K;
    const unsigned short* Bb = Bw + (size_t)(bn * 256) * K;
    const int NKT = K >> 6;

    int srow = tid >> 2;
    int scol = ((tid & 3) << 3) ^ (((srow >> 1) & 3) << 3);
    size_t r0K = (size_t)srow * K + scol;
    size_t r1K = r0K + (size_t)128 * K;
    int d0 = tid * 8, d1 = d0 + 4096;

    int c8 = (l >> 4) << 3;
    int iA[8], iB[4];
#pragma unroll
    for (int mf = 0; mf < 8; ++mf) {
        int ra = wr * 128 + mf * 16 + (l & 15);
        iA[mf] = ra * 32 + (c8 ^ (((ra >> 1) & 3) << 3));
    }
#pragma unroll
    for (int n = 0; n < 4; ++n) {
        int rb = wc * 64 + n * 16 + (l & 15);
        iB[n] = rb * 32 + (c8 ^ (((rb >> 1) & 3) << 3));
    }

    f32x4 acc[8][4] = {};
    s8v af[4], bf[4];

#define STAGE(srcb, kscol, ldsb) do { \
        gld_lds16((srcb) + r0K + (kscol), (ldsb) + d0); \
        gld_lds16((srcb) + r1K + (kscol), (ldsb) + d1); } while (0)

    STAGE(Ab, 0, As);
    STAGE(Bb, 0, Bs);
    STAGE(Ab, 32, As + 8192);
    STAGE(Bb, 32, Bs + 8192);
    STAGE(Ab, 64, As + 16384);
    STAGE(Bb, 64, Bs + 16384);
    WAITV(8);
    BARSYNC();

    for (int kt = 0; kt < NKT; ++kt) {
        int q = kt & 1, ks = kt << 6;
        const unsigned short* Aq = As + q * 16384;
        const unsigned short* Bq = Bs + q * 16384;
        unsigned short* An1 = As + (q ^ 1) * 16384 + 8192;
        unsigned short* Bn1 = Bs + (q ^ 1) * 16384 + 8192;
        unsigned short* An2 = As + q * 16384;
        unsigned short* Bn2 = Bs + q * 16384;

        // ---- P0 ----
#pragma unroll
        for (int n = 0; n < 4; ++n) bf[n] = *(const s8v*)&Bq[iB[n]];
#pragma unroll
        for (int m = 0; m < 4; ++m) af[m] = *(const s8v*)&Aq[iA[m]];
        if (kt + 1 < NKT) STAGE(Ab, ks + 96, An1);
        BARSYNC();
        __builtin_amdgcn_s_setprio(1);
        mfma16<0>(acc, af, bf);
        __builtin_amdgcn_s_setprio(0);
        BARSYNC();
        // ---- P1 ----
#pragma unroll
        for (int m = 0; m < 4; ++m) af[m] = *(const s8v*)&Aq[iA[4 + m]];
        if (kt + 1 < NKT) STAGE(Bb, ks + 96, Bn1);
        BARSYNC();
        __builtin_amdgcn_s_setprio(1);
        mfma16<4>(acc, af, bf);
        __builtin_amdgcn_s_setprio(0);
        if (kt < NKT - 1) { WAITV(8); } else { WAITV(0); }
        BARSYNC();
        // ---- P2 ----
#pragma unroll
        for (int n = 0; n < 4; ++n) bf[n] = *(const s8v*)&Bq[8192 + iB[n]];
#pragma unroll
        for (int m = 0; m < 4; ++m) af[m] = *(const s8v*)&Aq[8192 + iA[m]];
        if (kt + 2 < NKT) STAGE(Ab, ks + 128, An2);
        BARSYNC();
        __builtin_amdgcn_s_setprio(1);
        mfma16<0>(acc, af, bf);
        __builtin_amdgcn_s_setprio(0);
        BARSYNC();
        // ---- P3 ----
#pragma unroll
        for (int m = 0; m < 4; ++m) af[m] = *(const s8v*)&Aq[8192 + iA[4 + m]];
        if (kt + 2 < NKT) STAGE(Bb, ks + 128, Bn2);
        BARSYNC();
        __builtin_amdgcn_s_setprio(1);
        mfma16<4>(acc, af, bf);
        __builtin_amdgcn_s_setprio(0);
        if (kt < NKT - 2) { WAITV(8); }
        else if (kt == NKT - 2) { WAITV(4); }
        else { WAITV(0); }
        BARSYNC();
    }
#undef STAGE

#pragma unroll
    for (int mf = 0; mf < 8; ++mf) {
#pragma unroll
        for (int n = 0; n < 4; ++n) {
            int col = bn * 256 + wc * 64 + n * 16 + (l & 15);
#pragma unroll
            for (int r = 0; r < 4; ++r) {
                int row = bm * 256 + wr * 128 + mf * 16 + (l >> 4) * 4 + r;
                float v = acc[mf][n][r];
                if (EPI == 0) {
                    if (col < 1024) v *= QKSCALE;
                    else {
                        float s = v + bo[col - 1024];
                        v = 1.0f / (1.0f + expf(-s));
                    }
                    outb[(size_t)row * ldo + col] = f2b(v);
                } else {
                    size_t idx = (size_t)row * ldo + col;
                    outf[idx] = xres[idx] + v;
                }
            }
        }
    }
}

// ---------------- ktrans: kvT[s][t] = qko[t][512+s] (k, already scaled) ----
__global__ __launch_bounds__(256) void ktrans_kernel(
    const unsigned short* __restrict__ qko, unsigned short* __restrict__ kvT)
{
    __shared__ unsigned short T[64][72];
    int st = blockIdx.x & 7, tt = blockIdx.x >> 3;
    int t0 = tt * 64, s0 = st * 64;
    int tid = threadIdx.x;
    int ir = tid >> 3, jc = (tid & 7) * 8;
#pragma unroll
    for (int rr = 0; rr < 2; ++rr) {
        int row = rr * 32 + ir;
        s8v v = *(const s8v*)&qko[(size_t)(t0 + row) * 1536 + 512 + s0 + jc];
#pragma unroll
        for (int e = 0; e < 8; ++e) T[jc + e][row] = (unsigned short)v[e];
    }
    __syncthreads();
#pragma unroll
    for (int rr = 0; rr < 2; ++rr) {
        int srow = rr * 32 + ir;
        s8v o = *(const s8v*)&T[srow][jc];
        *(s8v*)&kvT[(size_t)(s0 + srow) * MROWS + t0 + jc] = o;
    }
}

// ---------------- phase A: St[t][j] = exp(u_j - a_t)*(q_t.k_j), j<=t ------
__global__ __launch_bounds__(256) void phaseA_kernel(
    const unsigned short* __restrict__ qko,
    const float* __restrict__ u, const float* __restrict__ a,
    unsigned short* __restrict__ st, float* __restrict__ rowsum)
{
    __shared__ unsigned short Qs[64 * 32], Ks[128 * 32];
    int bid = blockIdx.x;
    int b = bid & 7, c = (bid >> 3) & 15, th = bid >> 7;
    int tid = threadIdx.x, l = tid & 63, wv = tid >> 6;
    size_t cb = (size_t)b * T_SEQ + c * CL;
    f32x4 acc[8] = {};
    for (int ks = 0; ks < 512; ks += 32) {
        __syncthreads();
        {
            int p = tid;
            int row = p >> 2, kc = (p & 3) * 8;
            gld_lds16(qko + (cb + th * 64 + row) * 1536 + ks + kc, &Qs[p * 8]);
#pragma unroll
            for (int rI = 0; rI < 2; ++rI) {
                int pp = rI * 256 + tid;
                int rw = pp >> 2, kk = (pp & 3) * 8;
                gld_lds16(qko + (cb + rw) * 1536 + 512 + ks + kk, &Ks[pp * 8]);
            }
        }
        __syncthreads();
        s8v af = *(const s8v*)&Qs[(wv * 16 + (l & 15)) * 32 + (l >> 4) * 8];
#pragma unroll
        for (int n = 0; n < 8; ++n) {
            s8v bf = *(const s8v*)&Ks[(n * 16 + (l & 15)) * 32 + (l >> 4) * 8];
            acc[n] = __builtin_amdgcn_mfma_f32_16x16x32_bf16(af, bf, acc[n], 0, 0, 0);
        }
    }
    float rs[4] = {0.f, 0.f, 0.f, 0.f};
    size_t stb = (size_t)(b * NC + c) * (CL * CL);
#pragma unroll
    for (int e = 0; e < 4; ++e) {
        int tl = th * 64 + wv * 16 + (l >> 4) * 4 + e;
        float a_t = a[cb + tl];
#pragma unroll
        for (int n = 0; n < 8; ++n) {
            int j = n * 16 + (l & 15);
            float val = (j <= tl) ? acc[n][e] * expf(u[cb + j] - a_t) : 0.0f;
            rs[e] += val;
            st[stb + (size_t)tl * CL + j] = f2b(val);
        }
    }
#pragma unroll
    for (int e = 0; e < 4; ++e) {
#pragma unroll
        for (int m = 1; m < 16; m <<= 1) rs[e] += __shfl_xor(rs[e], m, 64);
    }
    if ((l & 15) == 0) {
#pragma unroll
        for (int e = 0; e < 4; ++e)
            rowsum[cb + th * 64 + wv * 16 + (l >> 4) * 4 + e] = rs[e];
    }
}

// ---------------- kwprep: kw[s][t] = w_t * k_t[s]; P = chunk row-sums ----
__global__ __launch_bounds__(256) void kwprep_kernel(
    const unsigned short* __restrict__ kvT,
    const float* __restrict__ u, const float* __restrict__ a,
    unsigned short* __restrict__ kw, float* __restrict__ P, float* __restrict__ aE)
{
    int bid = blockIdx.x;
    int b = bid & 7, c = (bid >> 3) & 15, sb = bid >> 7;
    int tid = threadIdx.x;
    int s = sb * 16 + (tid >> 4), jg = tid & 15;
    size_t cb = (size_t)b * T_SEQ + c * CL;
    __shared__ float w_l[CL];
    float a_e = a[cb + CL - 1];
    if (tid < CL) w_l[tid] = expf(u[cb + tid] - a_e);
    if (tid == 0 && sb == 0) aE[b * NC + c] = a_e;
    __syncthreads();
    s8v kv = *(const s8v*)&kvT[(size_t)s * MROWS + cb + jg * 8];
    s8v kwv;
    float psum = 0.0f;
#pragma unroll
    for (int e = 0; e < 8; ++e) {
        float f = b2f((unsigned short)kv[e]) * w_l[jg * 8 + e];
        kwv[e] = (short)f2b(f);
        psum += f;
    }
    *(s8v*)&kw[(size_t)s * MROWS + cb + jg * 8] = kwv;
#pragma unroll
    for (int m = 1; m < 16; m <<= 1) psum += __shfl_xor(psum, m, 64);
    if (jg == 0) P[(size_t)(b * NC + c) * 512 + s] = psum;
}

// nhprev[b][c][s] = n-state before chunk c (ref aE[c-1]); scan over c.
__global__ __launch_bounds__(256) void nhscan_kernel(
    const float* __restrict__ P, const float* __restrict__ aE,
    float* __restrict__ nhprev)
{
    int gid = blockIdx.x * 256 + threadIdx.x;   // 0..4095
    int b = gid >> 9, s = gid & 511;
    float nh = 0.0f, aprev = 0.0f;
    for (int c = 0; c < NC; ++c) {
        nhprev[(size_t)(b * NC + c) * 512 + s] = nh;
        float ae = aE[b * NC + c];
        float gam = (c == 0) ? 0.0f : expf(aprev - ae);
        nh = gam * nh + P[(size_t)(b * NC + c) * 512 + s];
        aprev = ae;
    }
}

// rdnm[t] = 1 / max(|beta_t*(q_t.nhprev) + rowsum[t]|, 1)
__global__ __launch_bounds__(256) void denom_kernel(
    const unsigned short* __restrict__ qko, const float* __restrict__ nhprev,
    const float* __restrict__ aE, const float* __restrict__ a,
    const float* __restrict__ rowsum, float* __restrict__ rdnm)
{
    int wv = threadIdx.x >> 6, l = threadIdx.x & 63;
    int t = blockIdx.x * 4 + wv;      // 0..16383
    int b = t >> 11, c = (t & 2047) >> 7;
    const unsigned short* qrow = qko + (size_t)t * 1536 + l * 8;
    const float* nh = nhprev + (size_t)(b * NC + c) * 512 + l * 8;
    s8v qv = *(const s8v*)qrow;
    float4 n0 = *(const float4*)nh;
    float4 n1 = *(const float4*)(nh + 4);
    float nq = b2f((unsigned short)qv[0]) * n0.x + b2f((unsigned short)qv[1]) * n0.y
             + b2f((unsigned short)qv[2]) * n0.z + b2f((unsigned short)qv[3]) * n0.w
             + b2f((unsigned short)qv[4]) * n1.x + b2f((unsigned short)qv[5]) * n1.y
             + b2f((unsigned short)qv[6]) * n1.z + b2f((unsigned short)qv[7]) * n1.w;
#pragma unroll
    for (int m = 1; m < 64; m <<= 1) nq += __shfl_xor(nq, m, 64);
    if (l == 0) {
        float beta = (c == 0) ? 0.0f : expf(aE[b * NC + c - 1] - a[t]);
        rdnm[t] = 1.0f / fmaxf(fabsf(beta * nq + rowsum[t]), 1.0f);
    }
}

// ---------------- cscan: C checkpoints, 1 wave per (b, r-tile32, s-tile32) ----
__global__ __launch_bounds__(64) void cscan_kernel(
    const unsigned short* __restrict__ kvT, const unsigned short* __restrict__ kw,
    const float* __restrict__ aE, unsigned short* __restrict__ chk)
{
    int bid = blockIdx.x;
    int b = bid & 7, rt = (bid >> 3) & 15, stt = bid >> 7;
    int r0 = rt * 32, s0 = stt * 32;
    int l = threadIdx.x;
    size_t tb = (size_t)b * T_SEQ;
    f32x4 acc[2][2] = {};
    float a_prev = 0.0f;

    for (int c = 0; c < NC; ++c) {
        size_t cb = tb + c * CL;
        float a_e = aE[b * NC + c];
        if (c > 0) {
            unsigned short* slot = chk + (size_t)(b * (NC - 1) + (c - 1)) * (512 * 512);
#pragma unroll
            for (int m = 0; m < 2; ++m)
#pragma unroll
                for (int n = 0; n < 2; ++n)
#pragma unroll
                    for (int e = 0; e < 4; ++e) {
                        int r = r0 + m * 16 + (l >> 4) * 4 + e;
                        int s = s0 + n * 16 + (l & 15);
                        slot[r * 512 + s] = f2b(acc[m][n][e]);
                    }
            float gam = expf(a_prev - a_e);
#pragma unroll
            for (int m = 0; m < 2; ++m)
#pragma unroll
                for (int n = 0; n < 2; ++n)
#pragma unroll
                    for (int e = 0; e < 4; ++e) acc[m][n][e] *= gam;
        }
#pragma unroll
        for (int ks = 0; ks < 4; ++ks) {
            int jb = ks * 32 + (l >> 4) * 8;
            s8v vf[2], kf[2];
#pragma unroll
            for (int m = 0; m < 2; ++m)
                vf[m] = *(const s8v*)&kvT[(size_t)(512 + r0 + m * 16 + (l & 15)) * MROWS + cb + jb];
#pragma unroll
            for (int n = 0; n < 2; ++n)
                kf[n] = *(const s8v*)&kw[(size_t)(s0 + n * 16 + (l & 15)) * MROWS + cb + jb];
#pragma unroll
            for (int m = 0; m < 2; ++m)
#pragma unroll
                for (int n = 0; n < 2; ++n)
                    acc[m][n] = __builtin_amdgcn_mfma_f32_16x16x32_bf16(vf[m], kf[n], acc[m][n], 0, 0, 0);
        }
        a_prev = a_e;
    }
}

// ---------------- hout: G = beta*(Q.Cchk^T) + St.V ; h = o*G*rdnm ----------
__global__ __launch_bounds__(512) void hout_kernel(
    const unsigned short* __restrict__ qko, const unsigned short* __restrict__ kvT,
    const unsigned short* __restrict__ st, const unsigned short* __restrict__ chk,
    const float* __restrict__ a, const float* __restrict__ aE,
    const float* __restrict__ rdnm, unsigned short* __restrict__ g)
{
    int bid = blockIdx.x;
    int b = bid & 7, cc = bid >> 3;
    int c = cc >> 1, rh = cc & 1;
    int tid = threadIdx.x, l = tid & 63, wv = tid >> 6;
    int mq = wv & 3;
    int rr = (wv >> 2) * 128 + rh * 256;
    size_t cb = (size_t)b * T_SEQ + c * CL;
    f32x4 acc[2][8] = {};

    if (c > 0) {
        const unsigned short* slot = chk + (size_t)(b * (NC - 1) + (c - 1)) * (512 * 512);
#pragma unroll
        for (int ks = 0; ks < 16; ++ks) {
            s8v aq[2];
#pragma unroll
            for (int mf = 0; mf < 2; ++mf)
                aq[mf] = *(const s8v*)&qko[(cb + mq * 32 + mf * 16 + (l & 15)) * 1536 + ks * 32 + (l >> 4) * 8];
#pragma unroll
            for (int n = 0; n < 8; ++n) {
                s8v bc = *(const s8v*)&slot[(size_t)(rr + n * 16 + (l & 15)) * 512 + ks * 32 + (l >> 4) * 8];
                acc[0][n] = __builtin_amdgcn_mfma_f32_16x16x32_bf16(aq[0], bc, acc[0][n], 0, 0, 0);
                acc[1][n] = __builtin_amdgcn_mfma_f32_16x16x32_bf16(aq[1], bc, acc[1][n], 0, 0, 0);
            }
        }
        float aprev = aE[b * NC + c - 1];
#pragma unroll
        for (int mf = 0; mf < 2; ++mf)
#pragma unroll
            for (int e = 0; e < 4; ++e) {
                int t = mq * 32 + mf * 16 + (l >> 4) * 4 + e;
                float bta = expf(aprev - a[cb + t]);
#pragma unroll
                for (int n = 0; n < 8; ++n) acc[mf][n][e] *= bta;
            }
    }
    const unsigned short* stp = st + (size_t)(b * NC + c) * (CL * CL);
#pragma unroll
    for (int ks = 0; ks < 4; ++ks) {
        s8v aq[2];
#pragma unroll
        for (int mf = 0; mf < 2; ++mf)
            aq[mf] = *(const s8v*)&stp[(size_t)(mq * 32 + mf * 16 + (l & 15)) * CL + ks * 32 + (l >> 4) * 8];
#pragma unroll
        for (int n = 0; n < 8; ++n) {
            s8v bv = *(const s8v*)&kvT[(size_t)(512 + rr + n * 16 + (l & 15)) * MROWS + cb + ks * 32 + (l >> 4) * 8];
            acc[0][n] = __builtin_amdgcn_mfma_f32_16x16x32_bf16(aq[0], bv, acc[0][n], 0, 0, 0);
            acc[1][n] = __builtin_amdgcn_mfma_f32_16x16x32_bf16(aq[1], bv, acc[1][n], 0, 0, 0);
        }
    }
#pragma unroll
    for (int mf = 0; mf < 2; ++mf)
#pragma unroll
        for (int e = 0; e < 4; ++e) {
            int t = mq * 32 + mf * 16 + (l >> 4) * 4 + e;
            float rd = rdnm[cb + t];
#pragma unroll
            for (int n = 0; n < 8; ++n) {
                int r = rr + n * 16 + (l & 15);
                float ov = b2f(qko[(cb + t) * 1536 + 1024 + r]);
                g[(cb + t) * DH + r] = f2b(ov * acc[mf][n][e] * rd);
            }
        }
}

extern "C" void kernel_launch(void* const* d_in, const int* in_sizes, int n_in,
                              void* d_out, int out_size, void* d_ws, size_t ws_size,
                              hipStream_t stream)
{
    (void)in_sizes; (void)n_in; (void)out_size; (void)ws_size;
    const float* x    = (const float*)d_in[0];
    const float* nw   = (const float*)d_in[1];
    const float* Wq   = (const float*)d_in[2];
    const float* Wk   = (const float*)d_in[3];
    const float* Wv   = (const float*)d_in[4];
    const float* wi   = (const float*)d_in[5];
    const float* wib  = (const float*)d_in[6];
    const float* wf   = (const float*)d_in[7];
    const float* wfb  = (const float*)d_in[8];
    const float* Wo   = (const float*)d_in[9];
    const float* bo   = (const float*)d_in[10];
    const float* Wout = (const float*)d_in[11];
    float* out = (float*)d_out;

    char* ws = (char*)d_ws;
    unsigned short* qko    = (unsigned short*)ws;                        // 0 .. 50,331,648
    unsigned short* kvT    = (unsigned short*)(ws + 50331648);           // .. 83,886,080
    unsigned short* normed = (unsigned short*)(ws + 83886080);           // .. 117,440,512
    unsigned short* g      = normed;                                     // first 16 MB (normed dead)
    unsigned short* kw     = (unsigned short*)(ws + 100663296);          // 16 MB (normed dead)
    float* Pbuf   = (float*)(ws + 117440512);                            // 262,144 (Wcat1 dead)
    float* nhprev = (float*)(ws + 117702656);                            // 262,144
    float* aE     = (float*)(ws + 117964800);                            // 512
    unsigned short* Wcat1  = (unsigned short*)(ws + 117440512);          // 3 MB (dead after gemm_qkv)
    unsigned short* WvB    = (unsigned short*)(ws + 120586240);          // 1 MB
    unsigned short* Woutb  = (unsigned short*)(ws + 122683392);          // 1 MB
    float* zi     = (float*)(ws + 123731968);
    float* zf     = zi + MROWS;
    float* uarr   = zf + MROWS;
    float* aarr   = uarr + MROWS;
    float* rowsum = aarr + MROWS;
    float* rdnm   = rowsum + MROWS;                                      // ends ~124.1 MB

    // d_out as scratch until final gemm: Cchk (60 MiB) + stbuf (4 MiB)
    unsigned short* chk   = (unsigned short*)d_out;                      // 8*15*512*512*2
    unsigned short* stbuf = (unsigned short*)((char*)d_out + 62914560);  // 8*16*128*128*2

    convAll_kernel <<<10240, 256, 0, stream>>>(Wq, Wk, Wo, Wv, Wout, Wcat1, WvB, Woutb);
    norm_kernel    <<<MROWS, 256, 0, stream>>>(x, nw, wi, wf, wib, wfb, normed, zi, zf);
    mscan2_kernel  <<<NBATCH, 256, 0, stream>>>(zi, zf, uarr, aarr);
    // merged QKO (1536 tiles) + V-proj (512 tiles): 2048 blocks = 2 exact rounds
    gemm_qkv       <<<2048, 256, 0, stream>>>(normed, Wcat1, WvB, DM, qko, bo, kvT + (size_t)512 * MROWS);
    // k: transpose from qko (already scaled)
    ktrans_kernel  <<<2048, 256, 0, stream>>>(qko, kvT);
    phaseA_kernel  <<<256, 256, 0, stream>>>(qko, uarr, aarr, stbuf, rowsum);
    kwprep_kernel  <<<4096, 256, 0, stream>>>(kvT, uarr, aarr, kw, Pbuf, aE);
    nhscan_kernel  <<<16, 256, 0, stream>>>(Pbuf, aE, nhprev);
    denom_kernel   <<<4096, 256, 0, stream>>>(qko, nhprev, aE, aarr, rowsum, rdnm);
    cscan_kernel   <<<2048, 64, 0, stream>>>(kvT, kw, aE, chk);
    hout_kernel    <<<256, 512, 0, stream>>>(qko, kvT, stbuf, chk, aarr, aE, rdnm, g);
    // A=g (16MB) >> B=Woutb (1MB): 256^2 8-phase, grid 64x4=256 (1 block/CU)
    gemm256<1>     <<<256, 512, 0, stream>>>(g, Woutb, MROWS, DM, DH, DM, nullptr, nullptr, out, x);
}

// Round 3
// 316.086 us; speedup vs baseline: 1.1413x; 1.0498x over previous
//
#include <hip/hip_runtime.h>
#include <cstdint>
#include <cmath>

#define T_SEQ 2048
#define NBATCH 8
#define DM 1024
#define DH 512
#define MROWS (NBATCH * T_SEQ)   // 16384
#define NC 16                    // chunks per batch
#define CL 128                   // chunk length

typedef short s8v __attribute__((ext_vector_type(8)));
typedef float f32x4 __attribute__((ext_vector_type(4)));

typedef unsigned int __attribute__((address_space(1))) uint_g;
typedef unsigned int __attribute__((address_space(3))) uint_l;

#define QKSCALE 0.044194173824159216f   // 1/sqrt(512)

__device__ __forceinline__ float b2f(unsigned short s) {
    union { unsigned u; float f; } c; c.u = ((unsigned)s) << 16; return c.f;
}
__device__ __forceinline__ unsigned short f2b(float f) {
    union { float f; unsigned u; } c; c.f = f;
    unsigned r = c.u + 0x7fffu + ((c.u >> 16) & 1u);
    return (unsigned short)(r >> 16);
}
__device__ __forceinline__ void gld_lds16(const void* g, void* l) {
    __builtin_amdgcn_global_load_lds((const uint_g*)g, (uint_l*)l, 16, 0, 0);
}

// ---------------- RMSNorm + zi/zf + fused weight conversion ----------------
// conv: 16384 blocks x 160 elems = 2,621,440 exact cover of Wcat1|WvB|Woutb.
__global__ __launch_bounds__(256) void norm_kernel(
    const float* __restrict__ x, const float* __restrict__ nw,
    const float* __restrict__ wi, const float* __restrict__ wf,
    const float* __restrict__ wib, const float* __restrict__ wfb,
    unsigned short* __restrict__ normed, float* __restrict__ zi, float* __restrict__ zf,
    const float* __restrict__ Wq, const float* __restrict__ Wk,
    const float* __restrict__ Wo, const float* __restrict__ Wv,
    const float* __restrict__ Wout,
    unsigned short* __restrict__ Wcat1, unsigned short* __restrict__ WvB,
    unsigned short* __restrict__ Woutb)
{
    int t = blockIdx.x, tid = threadIdx.x;
    float4 xv = ((const float4*)(x + (size_t)t * DM))[tid];
    float ss = xv.x * xv.x + xv.y * xv.y + xv.z * xv.z + xv.w * xv.w;
#pragma unroll
    for (int m = 1; m < 64; m <<= 1) ss += __shfl_xor(ss, m, 64);
    __shared__ float sred[4];
    __shared__ float sred2[8];
    if ((tid & 63) == 0) sred[tid >> 6] = ss;
    __syncthreads();
    ss = sred[0] + sred[1] + sred[2] + sred[3];
    float rstd = rsqrtf(ss * (1.0f / DM) + 1e-6f);
    float4 nwv = ((const float4*)nw)[tid];
    float n0 = xv.x * rstd * nwv.x, n1 = xv.y * rstd * nwv.y;
    float n2 = xv.z * rstd * nwv.z, n3 = xv.w * rstd * nwv.w;
    ushort4 pk;
    pk.x = f2b(n0); pk.y = f2b(n1); pk.z = f2b(n2); pk.w = f2b(n3);
    ((ushort4*)(normed + (size_t)t * DM))[tid] = pk;
    float4 wiv = ((const float4*)wi)[tid];
    float4 wfv = ((const float4*)wf)[tid];
    float pzi = n0 * wiv.x + n1 * wiv.y + n2 * wiv.z + n3 * wiv.w;
    float pzf = n0 * wfv.x + n1 * wfv.y + n2 * wfv.z + n3 * wfv.w;
#pragma unroll
    for (int m = 1; m < 64; m <<= 1) {
        pzi += __shfl_xor(pzi, m, 64);
        pzf += __shfl_xor(pzf, m, 64);
    }
    if ((tid & 63) == 0) { sred2[tid >> 6] = pzi; sred2[4 + (tid >> 6)] = pzf; }
    __syncthreads();
    if (tid == 0) {
        zi[t] = sred2[0] + sred2[1] + sred2[2] + sred2[3] + wib[0];
        zf[t] = sred2[4] + sred2[5] + sred2[6] + sred2[7] + wfb[0];
    }
    // ---- fused weight conversion ----
    if (tid < 160) {
        int idx = blockIdx.x * 160 + tid;
        if (idx < 1572864) {
            int nrow = idx >> 10;
            float v;
            if      (nrow < 512)  v = Wq[idx];
            else if (nrow < 1024) v = Wk[idx - 512 * 1024];
            else                  v = Wo[idx - 1024 * 1024];
            Wcat1[idx] = f2b(v);
        } else if (idx < 2097152) {
            int j = idx - 1572864;
            WvB[j] = f2b(Wv[j]);
        } else {
            int j = idx - 2097152;
            Woutb[j] = f2b(Wout[j]);
        }
    }
}

// ---------------- parallel scans: u = zi - cumsum(zf), a = runmax(u) ------
__global__ __launch_bounds__(256) void mscan2_kernel(
    const float* __restrict__ zi, const float* __restrict__ zf,
    float* __restrict__ u, float* __restrict__ a)
{
    int b = blockIdx.x, tid = threadIdx.x, lane = tid & 63, wid = tid >> 6;
    size_t base = (size_t)b * T_SEQ + tid * 8;
    float z_f[8], z_i[8];
    *(float4*)&z_f[0] = *(const float4*)&zf[base];
    *(float4*)&z_f[4] = *(const float4*)&zf[base + 4];
    *(float4*)&z_i[0] = *(const float4*)&zi[base];
    *(float4*)&z_i[4] = *(const float4*)&zi[base + 4];
    __shared__ float wt[4];
    float c8[8]; float run = 0.0f;
#pragma unroll
    for (int i = 0; i < 8; ++i) { run += z_f[i]; c8[i] = run; }
    float v = run;
#pragma unroll
    for (int d = 1; d < 64; d <<= 1) {
        float o = __shfl_up(v, d, 64);
        if (lane >= d) v += o;
    }
    if (lane == 63) wt[wid] = v;
    __syncthreads();
    float woff = 0.0f;
    for (int j = 0; j < wid; ++j) woff += wt[j];
    float excl = __shfl_up(v, 1, 64);
    if (lane == 0) excl = 0.0f;
    float pre = woff + excl;
    float uu[8];
#pragma unroll
    for (int i = 0; i < 8; ++i) uu[i] = z_i[i] - (pre + c8[i]);
    *(float4*)&u[base] = *(float4*)&uu[0];
    *(float4*)&u[base + 4] = *(float4*)&uu[4];
    __syncthreads();
    float m8[8]; float rm = -INFINITY;
#pragma unroll
    for (int i = 0; i < 8; ++i) { rm = fmaxf(rm, uu[i]); m8[i] = rm; }
    float mv = rm;
#pragma unroll
    for (int d = 1; d < 64; d <<= 1) {
        float o = __shfl_up(mv, d, 64);
        if (lane >= d) mv = fmaxf(mv, o);
    }
    if (lane == 63) wt[wid] = mv;
    __syncthreads();
    float moff = -INFINITY;
    for (int j = 0; j < wid; ++j) moff = fmaxf(moff, wt[j]);
    float mexcl = __shfl_up(mv, 1, 64);
    if (lane == 0) mexcl = -INFINITY;
    float mpre = fmaxf(moff, mexcl);
    float aa[8];
#pragma unroll
    for (int i = 0; i < 8; ++i) aa[i] = fmaxf(mpre, m8[i]);
    *(float4*)&a[base] = *(float4*)&aa[0];
    *(float4*)&a[base + 4] = *(float4*)&aa[4];
}

// ---------------- merged QKO + V projection, 128x128 bf16 MFMA ----------
// 2048 blocks = exactly 2 full rounds at 4 blocks/CU (no tail).
__global__ __launch_bounds__(256, 4) void gemm_qkv(
    const unsigned short* __restrict__ normed, const unsigned short* __restrict__ Wcat1,
    const unsigned short* __restrict__ WvB, int K,
    unsigned short* __restrict__ qko, const float* __restrict__ bo,
    unsigned short* __restrict__ vout)
{
    __shared__ unsigned short As[128 * 64];
    __shared__ unsigned short Bs[128 * 64];
    int tid = threadIdx.x;
    int l = tid & 63, w = tid >> 6;
    int wg = (blockIdx.x & 7) * 256 + (blockIdx.x >> 3);   // bijective, 2048 blocks
    int job = (wg >= 1536) ? 1 : 0;
    const unsigned short* A;
    const unsigned short* Bw;
    int bm, bn;
    if (job == 0) { A = normed; Bw = Wcat1; bn = wg % 12; bm = wg / 12; }
    else          { int w2 = wg - 1536; A = WvB; Bw = normed; bm = w2 & 3; bn = w2 >> 2; }
    int wr = w >> 1, wc = w & 1;
    f32x4 acc[4][4] = {};
    const size_t abase = (size_t)(bm * 128) * K;
    const size_t bbase = (size_t)(bn * 128) * K;

    for (int ks = 0; ks < K; ks += 64) {
        __syncthreads();
#pragma unroll
        for (int i = 0; i < 4; ++i) {
            int off = (i * 256 + tid) * 8;
            int row = off >> 6, kc = off & 63;
            int kcs = kc ^ ((row & 7) << 3);
            gld_lds16(A + abase + (size_t)row * K + ks + kcs, &As[off]);
            gld_lds16(Bw + bbase + (size_t)row * K + ks + kcs, &Bs[off]);
        }
        __syncthreads();
#pragma unroll
        for (int kk = 0; kk < 2; ++kk) {
            int cbo = kk * 32 + (l >> 4) * 8;
            s8v af[4], bfv[4];
#pragma unroll
            for (int m = 0; m < 4; ++m) {
                int row = wr * 64 + m * 16 + (l & 15);
                af[m] = *(const s8v*)&As[row * 64 + (cbo ^ ((row & 7) << 3))];
            }
#pragma unroll
            for (int n = 0; n < 4; ++n) {
                int row = wc * 64 + n * 16 + (l & 15);
                bfv[n] = *(const s8v*)&Bs[row * 64 + (cbo ^ ((row & 7) << 3))];
            }
#pragma unroll
            for (int m = 0; m < 4; ++m)
#pragma unroll
                for (int n = 0; n < 4; ++n)
                    acc[m][n] = __builtin_amdgcn_mfma_f32_16x16x32_bf16(af[m], bfv[n], acc[m][n], 0, 0, 0);
        }
    }

    if (job == 0) {
#pragma unroll
        for (int m = 0; m < 4; ++m) {
#pragma unroll
            for (int n = 0; n < 4; ++n) {
                int col = bn * 128 + wc * 64 + n * 16 + (l & 15);
#pragma unroll
                for (int r = 0; r < 4; ++r) {
                    int row = bm * 128 + wr * 64 + m * 16 + (l >> 4) * 4 + r;
                    float v = acc[m][n][r];
                    if (col < 1024) v *= QKSCALE;
                    else {
                        float s = v + bo[col - 1024];
                        v = 1.0f / (1.0f + expf(-s));
                    }
                    qko[(size_t)row * 1536 + col] = f2b(v);
                }
            }
        }
    } else {
#pragma unroll
        for (int m = 0; m < 4; ++m) {
#pragma unroll
            for (int n = 0; n < 4; ++n) {
                int col = bn * 128 + wc * 64 + n * 16 + (l & 15);
#pragma unroll
                for (int r = 0; r < 4; ++r) {
                    int row = bm * 128 + wr * 64 + m * 16 + (l >> 4) * 4 + r;
                    vout[(size_t)row * MROWS + col] = f2b(acc[m][n][r]);
                }
            }
        }
    }
}

// ---------------- 128x128 bf16 MFMA GEMM (output projection) -------------
template <int EPI, int ORD>
__global__ __launch_bounds__(256, 4) void gemm_bt(
    const unsigned short* __restrict__ A, const unsigned short* __restrict__ Bw,
    int M, int N, int K, int ldo,
    unsigned short* __restrict__ outb, const float* __restrict__ bo,
    float* __restrict__ outf, const float* __restrict__ xres)
{
    __shared__ unsigned short As[128 * 64];
    __shared__ unsigned short Bs[128 * 64];
    int tid = threadIdx.x;
    int l = tid & 63, w = tid >> 6;
    int cpx = gridDim.x >> 3;
    int wg = (blockIdx.x & 7) * cpx + (blockIdx.x >> 3);
    int mb = M >> 7;
    int nb = N >> 7;
    int bm, bn;
    if (ORD == 0) { bm = wg % mb; bn = wg / mb; }
    else          { bn = wg % nb; bm = wg / nb; }
    int wr = w >> 1, wc = w & 1;
    f32x4 acc[4][4] = {};
    const size_t abase = (size_t)(bm * 128) * K;
    const size_t bbase = (size_t)(bn * 128) * K;

    for (int ks = 0; ks < K; ks += 64) {
        __syncthreads();
#pragma unroll
        for (int i = 0; i < 4; ++i) {
            int off = (i * 256 + tid) * 8;
            int row = off >> 6, kc = off & 63;
            int kcs = kc ^ ((row & 7) << 3);
            gld_lds16(A + abase + (size_t)row * K + ks + kcs, &As[off]);
            gld_lds16(Bw + bbase + (size_t)row * K + ks + kcs, &Bs[off]);
        }
        __syncthreads();
#pragma unroll
        for (int kk = 0; kk < 2; ++kk) {
            int cbo = kk * 32 + (l >> 4) * 8;
            s8v af[4], bfv[4];
#pragma unroll
            for (int m = 0; m < 4; ++m) {
                int row = wr * 64 + m * 16 + (l & 15);
                af[m] = *(const s8v*)&As[row * 64 + (cbo ^ ((row & 7) << 3))];
            }
#pragma unroll
            for (int n = 0; n < 4; ++n) {
                int row = wc * 64 + n * 16 + (l & 15);
                bfv[n] = *(const s8v*)&Bs[row * 64 + (cbo ^ ((row & 7) << 3))];
            }
#pragma unroll
            for (int m = 0; m < 4; ++m)
#pragma unroll
                for (int n = 0; n < 4; ++n)
                    acc[m][n] = __builtin_amdgcn_mfma_f32_16x16x32_bf16(af[m], bfv[n], acc[m][n], 0, 0, 0);
        }
    }

#pragma unroll
    for (int m = 0; m < 4; ++m) {
#pragma unroll
        for (int n = 0; n < 4; ++n) {
            int col = bn * 128 + wc * 64 + n * 16 + (l & 15);
#pragma unroll
            for (int r = 0; r < 4; ++r) {
                int row = bm * 128 + wr * 64 + m * 16 + (l >> 4) * 4 + r;
                float v = acc[m][n][r];
                if (EPI == 3) {
                    outb[(size_t)row * ldo + col] = f2b(v);
                } else {
                    size_t idx = (size_t)row * ldo + col;
                    outf[idx] = xres[idx] + v;
                }
            }
        }
    }
}

// ---------------- phase A: St[t][j] = exp(u_j - a_t)*(q_t.k_j), j<=t ------
__global__ __launch_bounds__(256) void phaseA_kernel(
    const unsigned short* __restrict__ qko,
    const float* __restrict__ u, const float* __restrict__ a,
    unsigned short* __restrict__ st, float* __restrict__ rowsum)
{
    __shared__ unsigned short Qs[64 * 32], Ks[128 * 32];
    int bid = blockIdx.x;
    int b = bid & 7, c = (bid >> 3) & 15, th = bid >> 7;
    int tid = threadIdx.x, l = tid & 63, wv = tid >> 6;
    size_t cb = (size_t)b * T_SEQ + c * CL;
    f32x4 acc[8] = {};
    for (int ks = 0; ks < 512; ks += 32) {
        __syncthreads();
        {
            int p = tid;
            int row = p >> 2, kc = (p & 3) * 8;
            gld_lds16(qko + (cb + th * 64 + row) * 1536 + ks + kc, &Qs[p * 8]);
#pragma unroll
            for (int rI = 0; rI < 2; ++rI) {
                int pp = rI * 256 + tid;
                int rw = pp >> 2, kk = (pp & 3) * 8;
                gld_lds16(qko + (cb + rw) * 1536 + 512 + ks + kk, &Ks[pp * 8]);
            }
        }
        __syncthreads();
        s8v af = *(const s8v*)&Qs[(wv * 16 + (l & 15)) * 32 + (l >> 4) * 8];
#pragma unroll
        for (int n = 0; n < 8; ++n) {
            s8v bf = *(const s8v*)&Ks[(n * 16 + (l & 15)) * 32 + (l >> 4) * 8];
            acc[n] = __builtin_amdgcn_mfma_f32_16x16x32_bf16(af, bf, acc[n], 0, 0, 0);
        }
    }
    float rs[4] = {0.f, 0.f, 0.f, 0.f};
    size_t stb = (size_t)(b * NC + c) * (CL * CL);
#pragma unroll
    for (int e = 0; e < 4; ++e) {
        int tl = th * 64 + wv * 16 + (l >> 4) * 4 + e;
        float a_t = a[cb + tl];
#pragma unroll
        for (int n = 0; n < 8; ++n) {
            int j = n * 16 + (l & 15);
            float val = (j <= tl) ? acc[n][e] * expf(u[cb + j] - a_t) : 0.0f;
            rs[e] += val;
            st[stb + (size_t)tl * CL + j] = f2b(val);
        }
    }
#pragma unroll
    for (int e = 0; e < 4; ++e) {
#pragma unroll
        for (int m = 1; m < 16; m <<= 1) rs[e] += __shfl_xor(rs[e], m, 64);
    }
    if ((l & 15) == 0) {
#pragma unroll
        for (int e = 0; e < 4; ++e)
            rowsum[cb + th * 64 + wv * 16 + (l >> 4) * 4 + e] = rs[e];
    }
}

// ---------------- kwprep2: transpose k from qko + scale; P row-sums ------
// Replaces ktrans + kwprep: reads qko k-cols row-major (coalesced),
// LDS-transposes a 128t x 64s tile, writes kw[s][t] = w_t * k_t[s], and
// P[b,c,s] = sum_t. Eliminates the kvT-k copy (32 MB round trip).
__global__ __launch_bounds__(256) void kwprep2_kernel(
    const unsigned short* __restrict__ qko,
    const float* __restrict__ u, const float* __restrict__ a,
    unsigned short* __restrict__ kw, float* __restrict__ P, float* __restrict__ aE)
{
    __shared__ unsigned short T[64][136];
    __shared__ float w_l[CL];
    int bid = blockIdx.x;
    int b = bid & 7, c = (bid >> 3) & 15, st = bid >> 7;   // st: 0..7
    int s0 = st * 64;
    int tid = threadIdx.x;
    size_t cb = (size_t)b * T_SEQ + c * CL;
    float a_e = a[cb + CL - 1];
    if (tid < CL) w_l[tid] = expf(u[cb + tid] - a_e);
    if (tid == 0 && st == 0) aE[b * NC + c] = a_e;
#pragma unroll
    for (int it = 0; it < 4; ++it) {
        int flat = it * 256 + tid;          // 0..1023
        int t = flat >> 3, g = flat & 7;
        s8v v = *(const s8v*)&qko[(cb + t) * 1536 + 512 + s0 + g * 8];
#pragma unroll
        for (int e = 0; e < 8; ++e) T[g * 8 + e][t] = (unsigned short)v[e];
    }
    __syncthreads();
    int s = tid >> 2, tg = tid & 3;
    float psum = 0.0f;
#pragma unroll
    for (int j = 0; j < 4; ++j) {
        int t0 = tg * 32 + j * 8;
        s8v kv = *(const s8v*)&T[s][t0];
        s8v kwv;
#pragma unroll
        for (int e = 0; e < 8; ++e) {
            float f = b2f((unsigned short)kv[e]) * w_l[t0 + e];
            kwv[e] = (short)f2b(f);
            psum += f;
        }
        *(s8v*)&kw[(size_t)(s0 + s) * MROWS + cb + t0] = kwv;
    }
    psum += __shfl_xor(psum, 1, 64);
    psum += __shfl_xor(psum, 2, 64);
    if (tg == 0) P[(size_t)(b * NC + c) * 512 + s0 + s] = psum;
}

// nhprev[b][c][s] = n-state before chunk c (ref aE[c-1]); scan over c.
__global__ __launch_bounds__(256) void nhscan_kernel(
    const float* __restrict__ P, const float* __restrict__ aE,
    float* __restrict__ nhprev)
{
    int gid = blockIdx.x * 256 + threadIdx.x;   // 0..4095
    int b = gid >> 9, s = gid & 511;
    float nh = 0.0f, aprev = 0.0f;
    for (int c = 0; c < NC; ++c) {
        nhprev[(size_t)(b * NC + c) * 512 + s] = nh;
        float ae = aE[b * NC + c];
        float gam = (c == 0) ? 0.0f : expf(aprev - ae);
        nh = gam * nh + P[(size_t)(b * NC + c) * 512 + s];
        aprev = ae;
    }
}

// rdnm[t] = 1 / max(|beta_t*(q_t.nhprev) + rowsum[t]|, 1)
__global__ __launch_bounds__(256) void denom_kernel(
    const unsigned short* __restrict__ qko, const float* __restrict__ nhprev,
    const float* __restrict__ aE, const float* __restrict__ a,
    const float* __restrict__ rowsum, float* __restrict__ rdnm)
{
    int wv = threadIdx.x >> 6, l = threadIdx.x & 63;
    int t = blockIdx.x * 4 + wv;      // 0..16383
    int b = t >> 11, c = (t & 2047) >> 7;
    const unsigned short* qrow = qko + (size_t)t * 1536 + l * 8;
    const float* nh = nhprev + (size_t)(b * NC + c) * 512 + l * 8;
    s8v qv = *(const s8v*)qrow;
    float4 n0 = *(const float4*)nh;
    float4 n1 = *(const float4*)(nh + 4);
    float nq = b2f((unsigned short)qv[0]) * n0.x + b2f((unsigned short)qv[1]) * n0.y
             + b2f((unsigned short)qv[2]) * n0.z + b2f((unsigned short)qv[3]) * n0.w
             + b2f((unsigned short)qv[4]) * n1.x + b2f((unsigned short)qv[5]) * n1.y
             + b2f((unsigned short)qv[6]) * n1.z + b2f((unsigned short)qv[7]) * n1.w;
#pragma unroll
    for (int m = 1; m < 64; m <<= 1) nq += __shfl_xor(nq, m, 64);
    if (l == 0) {
        float beta = (c == 0) ? 0.0f : expf(aE[b * NC + c - 1] - a[t]);
        rdnm[t] = 1.0f / fmaxf(fabsf(beta * nq + rowsum[t]), 1.0f);
    }
}

// ---------------- cscan: C checkpoints, 1 wave per (b, r-tile32, s-tile32) ----
__global__ __launch_bounds__(64) void cscan_kernel(
    const unsigned short* __restrict__ kvT, const unsigned short* __restrict__ kw,
    const float* __restrict__ aE, unsigned short* __restrict__ chk)
{
    int bid = blockIdx.x;
    int b = bid & 7, rt = (bid >> 3) & 15, stt = bid >> 7;
    int r0 = rt * 32, s0 = stt * 32;
    int l = threadIdx.x;
    size_t tb = (size_t)b * T_SEQ;
    f32x4 acc[2][2] = {};
    float a_prev = 0.0f;

    for (int c = 0; c < NC; ++c) {
        size_t cb = tb + c * CL;
        float a_e = aE[b * NC + c];
        if (c > 0) {
            unsigned short* slot = chk + (size_t)(b * (NC - 1) + (c - 1)) * (512 * 512);
#pragma unroll
            for (int m = 0; m < 2; ++m)
#pragma unroll
                for (int n = 0; n < 2; ++n)
#pragma unroll
                    for (int e = 0; e < 4; ++e) {
                        int r = r0 + m * 16 + (l >> 4) * 4 + e;
                        int s = s0 + n * 16 + (l & 15);
                        slot[r * 512 + s] = f2b(acc[m][n][e]);
                    }
            float gam = expf(a_prev - a_e);
#pragma unroll
            for (int m = 0; m < 2; ++m)
#pragma unroll
                for (int n = 0; n < 2; ++n)
#pragma unroll
                    for (int e = 0; e < 4; ++e) acc[m][n][e] *= gam;
        }
#pragma unroll
        for (int ks = 0; ks < 4; ++ks) {
            int jb = ks * 32 + (l >> 4) * 8;
            s8v vf[2], kf[2];
#pragma unroll
            for (int m = 0; m < 2; ++m)
                vf[m] = *(const s8v*)&kvT[(size_t)(512 + r0 + m * 16 + (l & 15)) * MROWS + cb + jb];
#pragma unroll
            for (int n = 0; n < 2; ++n)
                kf[n] = *(const s8v*)&kw[(size_t)(s0 + n * 16 + (l & 15)) * MROWS + cb + jb];
#pragma unroll
            for (int m = 0; m < 2; ++m)
#pragma unroll
                for (int n = 0; n < 2; ++n)
                    acc[m][n] = __builtin_amdgcn_mfma_f32_16x16x32_bf16(vf[m], kf[n], acc[m][n], 0, 0, 0);
        }
        a_prev = a_e;
    }
}

// ---------------- hout: G = beta*(Q.Cchk^T) + St.V ; h = o*G*rdnm ----------
__global__ __launch_bounds__(512) void hout_kernel(
    const unsigned short* __restrict__ qko, const unsigned short* __restrict__ kvT,
    const unsigned short* __restrict__ st, const unsigned short* __restrict__ chk,
    const float* __restrict__ a, const float* __restrict__ aE,
    const float* __restrict__ rdnm, unsigned short* __restrict__ g)
{
    int bid = blockIdx.x;
    int b = bid & 7, cc = bid >> 3;
    int c = cc >> 1, rh = cc & 1;
    int tid = threadIdx.x, l = tid & 63, wv = tid >> 6;
    int mq = wv & 3;
    int rr = (wv >> 2) * 128 + rh * 256;
    size_t cb = (size_t)b * T_SEQ + c * CL;
    f32x4 acc[2][8] = {};

    if (c > 0) {
        const unsigned short* slot = chk + (size_t)(b * (NC - 1) + (c - 1)) * (512 * 512);
#pragma unroll
        for (int ks = 0; ks < 16; ++ks) {
            s8v aq[2];
#pragma unroll
            for (int mf = 0; mf < 2; ++mf)
                aq[mf] = *(const s8v*)&qko[(cb + mq * 32 + mf * 16 + (l & 15)) * 1536 + ks * 32 + (l >> 4) * 8];
#pragma unroll
            for (int n = 0; n < 8; ++n) {
                s8v bc = *(const s8v*)&slot[(size_t)(rr + n * 16 + (l & 15)) * 512 + ks * 32 + (l >> 4) * 8];
                acc[0][n] = __builtin_amdgcn_mfma_f32_16x16x32_bf16(aq[0], bc, acc[0][n], 0, 0, 0);
                acc[1][n] = __builtin_amdgcn_mfma_f32_16x16x32_bf16(aq[1], bc, acc[1][n], 0, 0, 0);
            }
        }
        float aprev = aE[b * NC + c - 1];
#pragma unroll
        for (int mf = 0; mf < 2; ++mf)
#pragma unroll
            for (int e = 0; e < 4; ++e) {
                int t = mq * 32 + mf * 16 + (l >> 4) * 4 + e;
                float bta = expf(aprev - a[cb + t]);
#pragma unroll
                for (int n = 0; n < 8; ++n) acc[mf][n][e] *= bta;
            }
    }
    const unsigned short* stp = st + (size_t)(b * NC + c) * (CL * CL);
#pragma unroll
    for (int ks = 0; ks < 4; ++ks) {
        s8v aq[2];
#pragma unroll
        for (int mf = 0; mf < 2; ++mf)
            aq[mf] = *(const s8v*)&stp[(size_t)(mq * 32 + mf * 16 + (l & 15)) * CL + ks * 32 + (l >> 4) * 8];
#pragma unroll
        for (int n = 0; n < 8; ++n) {
            s8v bv = *(const s8v*)&kvT[(size_t)(512 + rr + n * 16 + (l & 15)) * MROWS + cb + ks * 32 + (l >> 4) * 8];
            acc[0][n] = __builtin_amdgcn_mfma_f32_16x16x32_bf16(aq[0], bv, acc[0][n], 0, 0, 0);
            acc[1][n] = __builtin_amdgcn_mfma_f32_16x16x32_bf16(aq[1], bv, acc[1][n], 0, 0, 0);
        }
    }
#pragma unroll
    for (int mf = 0; mf < 2; ++mf)
#pragma unroll
        for (int e = 0; e < 4; ++e) {
            int t = mq * 32 + mf * 16 + (l >> 4) * 4 + e;
            float rd = rdnm[cb + t];
#pragma unroll
            for (int n = 0; n < 8; ++n) {
                int r = rr + n * 16 + (l & 15);
                float ov = b2f(qko[(cb + t) * 1536 + 1024 + r]);
                g[(cb + t) * DH + r] = f2b(ov * acc[mf][n][e] * rd);
            }
        }
}

extern "C" void kernel_launch(void* const* d_in, const int* in_sizes, int n_in,
                              void* d_out, int out_size, void* d_ws, size_t ws_size,
                              hipStream_t stream)
{
    (void)in_sizes; (void)n_in; (void)out_size; (void)ws_size;
    const float* x    = (const float*)d_in[0];
    const float* nw   = (const float*)d_in[1];
    const float* Wq   = (const float*)d_in[2];
    const float* Wk   = (const float*)d_in[3];
    const float* Wv   = (const float*)d_in[4];
    const float* wi   = (const float*)d_in[5];
    const float* wib  = (const float*)d_in[6];
    const float* wf   = (const float*)d_in[7];
    const float* wfb  = (const float*)d_in[8];
    const float* Wo   = (const float*)d_in[9];
    const float* bo   = (const float*)d_in[10];
    const float* Wout = (const float*)d_in[11];
    float* out = (float*)d_out;

    char* ws = (char*)d_ws;
    unsigned short* qko    = (unsigned short*)ws;                        // 0 .. 50,331,648
    unsigned short* kvT    = (unsigned short*)(ws + 50331648);           // .. 83,886,080 (v in rows 512+)
    unsigned short* normed = (unsigned short*)(ws + 83886080);           // .. 117,440,512
    unsigned short* g      = normed;                                     // first 16 MB (normed dead)
    unsigned short* kw     = (unsigned short*)(ws + 100663296);          // 16 MB (normed dead)
    float* Pbuf   = (float*)(ws + 117440512);                            // 262,144 (Wcat1 dead)
    float* nhprev = (float*)(ws + 117702656);                            // 262,144
    float* aE     = (float*)(ws + 117964800);                            // 512
    unsigned short* Wcat1  = (unsigned short*)(ws + 117440512);          // 3 MB (dead after gemm_qkv)
    unsigned short* WvB    = (unsigned short*)(ws + 120586240);          // 1 MB
    unsigned short* Woutb  = (unsigned short*)(ws + 122683392);          // 1 MB
    float* zi     = (float*)(ws + 123731968);
    float* zf     = zi + MROWS;
    float* uarr   = zf + MROWS;
    float* aarr   = uarr + MROWS;
    float* rowsum = aarr + MROWS;
    float* rdnm   = rowsum + MROWS;                                      // ends ~124.1 MB

    // d_out as scratch until final gemm: Cchk (60 MiB) + stbuf (4 MiB)
    unsigned short* chk   = (unsigned short*)d_out;                      // 8*15*512*512*2
    unsigned short* stbuf = (unsigned short*)((char*)d_out + 62914560);  // 8*16*128*128*2

    norm_kernel    <<<MROWS, 256, 0, stream>>>(x, nw, wi, wf, wib, wfb, normed, zi, zf,
                                               Wq, Wk, Wo, Wv, Wout, Wcat1, WvB, Woutb);
    mscan2_kernel  <<<NBATCH, 256, 0, stream>>>(zi, zf, uarr, aarr);
    // merged QKO (1536 tiles) + V-proj (512 tiles): 2048 blocks = 2 exact rounds
    gemm_qkv       <<<2048, 256, 0, stream>>>(normed, Wcat1, WvB, DM, qko, bo, kvT + (size_t)512 * MROWS);
    phaseA_kernel  <<<256, 256, 0, stream>>>(qko, uarr, aarr, stbuf, rowsum);
    // k transpose + weight + P, straight from qko (replaces ktrans+kwprep)
    kwprep2_kernel <<<1024, 256, 0, stream>>>(qko, uarr, aarr, kw, Pbuf, aE);
    nhscan_kernel  <<<16, 256, 0, stream>>>(Pbuf, aE, nhprev);
    denom_kernel   <<<4096, 256, 0, stream>>>(qko, nhprev, aE, aarr, rowsum, rdnm);
    cscan_kernel   <<<2048, 64, 0, stream>>>(kvT, kw, aE, chk);
    hout_kernel    <<<256, 512, 0, stream>>>(qko, kvT, stbuf, chk, aarr, aE, rdnm, g);
    // A=g (16MB) >> B=Woutb (1MB): ORD=1 (R0 measured config, 1024 = exact round)
    gemm_bt<1, 1>  <<<128 * 8, 256, 0, stream>>>(g, Woutb, MROWS, DM, DH, DM, nullptr, nullptr, out, x);
}

// Round 4
// 274.157 us; speedup vs baseline: 1.3158x; 1.1529x over previous
//
#include <hip/hip_runtime.h>
#include <cstdint>
#include <cmath>

#define T_SEQ 2048
#define NBATCH 8
#define DM 1024
#define DH 512
#define MROWS (NBATCH * T_SEQ)   // 16384
#define NC 16                    // chunks per batch
#define CL 128                   // chunk length

typedef short s8v __attribute__((ext_vector_type(8)));
typedef float f32x4 __attribute__((ext_vector_type(4)));

typedef unsigned int __attribute__((address_space(1))) uint_g;
typedef unsigned int __attribute__((address_space(3))) uint_l;

#define QKSCALE 0.044194173824159216f   // 1/sqrt(512)

__device__ __forceinline__ float b2f(unsigned short s) {
    union { unsigned u; float f; } c; c.u = ((unsigned)s) << 16; return c.f;
}
__device__ __forceinline__ unsigned short f2b(float f) {
    union { float f; unsigned u; } c; c.f = f;
    unsigned r = c.u + 0x7fffu + ((c.u >> 16) & 1u);
    return (unsigned short)(r >> 16);
}
__device__ __forceinline__ void gld_lds16(const void* g, void* l) {
    __builtin_amdgcn_global_load_lds((const uint_g*)g, (uint_l*)l, 16, 0, 0);
}

#define WAITV(N) asm volatile("s_waitcnt vmcnt(" #N ")" ::: "memory")
#define BARSYNC() do { asm volatile("" ::: "memory"); __builtin_amdgcn_s_barrier(); asm volatile("" ::: "memory"); } while (0)

// ---------------- RMSNorm + zi/zf + fused weight conversion ----------------
__global__ __launch_bounds__(256) void norm_kernel(
    const float* __restrict__ x, const float* __restrict__ nw,
    const float* __restrict__ wi, const float* __restrict__ wf,
    const float* __restrict__ wib, const float* __restrict__ wfb,
    unsigned short* __restrict__ normed, float* __restrict__ zi, float* __restrict__ zf,
    const float* __restrict__ Wq, const float* __restrict__ Wk,
    const float* __restrict__ Wo, const float* __restrict__ Wv,
    const float* __restrict__ Wout,
    unsigned short* __restrict__ Wcat1, unsigned short* __restrict__ WvB,
    unsigned short* __restrict__ Woutb)
{
    int t = blockIdx.x, tid = threadIdx.x;
    float4 xv = ((const float4*)(x + (size_t)t * DM))[tid];
    float ss = xv.x * xv.x + xv.y * xv.y + xv.z * xv.z + xv.w * xv.w;
#pragma unroll
    for (int m = 1; m < 64; m <<= 1) ss += __shfl_xor(ss, m, 64);
    __shared__ float sred[4];
    __shared__ float sred2[8];
    if ((tid & 63) == 0) sred[tid >> 6] = ss;
    __syncthreads();
    ss = sred[0] + sred[1] + sred[2] + sred[3];
    float rstd = rsqrtf(ss * (1.0f / DM) + 1e-6f);
    float4 nwv = ((const float4*)nw)[tid];
    float n0 = xv.x * rstd * nwv.x, n1 = xv.y * rstd * nwv.y;
    float n2 = xv.z * rstd * nwv.z, n3 = xv.w * rstd * nwv.w;
    ushort4 pk;
    pk.x = f2b(n0); pk.y = f2b(n1); pk.z = f2b(n2); pk.w = f2b(n3);
    ((ushort4*)(normed + (size_t)t * DM))[tid] = pk;
    float4 wiv = ((const float4*)wi)[tid];
    float4 wfv = ((const float4*)wf)[tid];
    float pzi = n0 * wiv.x + n1 * wiv.y + n2 * wiv.z + n3 * wiv.w;
    float pzf = n0 * wfv.x + n1 * wfv.y + n2 * wfv.z + n3 * wfv.w;
#pragma unroll
    for (int m = 1; m < 64; m <<= 1) {
        pzi += __shfl_xor(pzi, m, 64);
        pzf += __shfl_xor(pzf, m, 64);
    }
    if ((tid & 63) == 0) { sred2[tid >> 6] = pzi; sred2[4 + (tid >> 6)] = pzf; }
    __syncthreads();
    if (tid == 0) {
        zi[t] = sred2[0] + sred2[1] + sred2[2] + sred2[3] + wib[0];
        zf[t] = sred2[4] + sred2[5] + sred2[6] + sred2[7] + wfb[0];
    }
    // ---- fused weight conversion ----
    if (tid < 160) {
        int idx = blockIdx.x * 160 + tid;
        if (idx < 1572864) {
            int nrow = idx >> 10;
            float v;
            if      (nrow < 512)  v = Wq[idx];
            else if (nrow < 1024) v = Wk[idx - 512 * 1024];
            else                  v = Wo[idx - 1024 * 1024];
            Wcat1[idx] = f2b(v);
        } else if (idx < 2097152) {
            int j = idx - 1572864;
            WvB[j] = f2b(Wv[j]);
        } else {
            int j = idx - 2097152;
            Woutb[j] = f2b(Wout[j]);
        }
    }
}

// ---------------- parallel scans: u = zi - cumsum(zf), a = runmax(u) ------
__global__ __launch_bounds__(256) void mscan2_kernel(
    const float* __restrict__ zi, const float* __restrict__ zf,
    float* __restrict__ u, float* __restrict__ a)
{
    int b = blockIdx.x, tid = threadIdx.x, lane = tid & 63, wid = tid >> 6;
    size_t base = (size_t)b * T_SEQ + tid * 8;
    float z_f[8], z_i[8];
    *(float4*)&z_f[0] = *(const float4*)&zf[base];
    *(float4*)&z_f[4] = *(const float4*)&zf[base + 4];
    *(float4*)&z_i[0] = *(const float4*)&zi[base];
    *(float4*)&z_i[4] = *(const float4*)&zi[base + 4];
    __shared__ float wt[4];
    float c8[8]; float run = 0.0f;
#pragma unroll
    for (int i = 0; i < 8; ++i) { run += z_f[i]; c8[i] = run; }
    float v = run;
#pragma unroll
    for (int d = 1; d < 64; d <<= 1) {
        float o = __shfl_up(v, d, 64);
        if (lane >= d) v += o;
    }
    if (lane == 63) wt[wid] = v;
    __syncthreads();
    float woff = 0.0f;
    for (int j = 0; j < wid; ++j) woff += wt[j];
    float excl = __shfl_up(v, 1, 64);
    if (lane == 0) excl = 0.0f;
    float pre = woff + excl;
    float uu[8];
#pragma unroll
    for (int i = 0; i < 8; ++i) uu[i] = z_i[i] - (pre + c8[i]);
    *(float4*)&u[base] = *(float4*)&uu[0];
    *(float4*)&u[base + 4] = *(float4*)&uu[4];
    __syncthreads();
    float m8[8]; float rm = -INFINITY;
#pragma unroll
    for (int i = 0; i < 8; ++i) { rm = fmaxf(rm, uu[i]); m8[i] = rm; }
    float mv = rm;
#pragma unroll
    for (int d = 1; d < 64; d <<= 1) {
        float o = __shfl_up(mv, d, 64);
        if (lane >= d) mv = fmaxf(mv, o);
    }
    if (lane == 63) wt[wid] = mv;
    __syncthreads();
    float moff = -INFINITY;
    for (int j = 0; j < wid; ++j) moff = fmaxf(moff, wt[j]);
    float mexcl = __shfl_up(mv, 1, 64);
    if (lane == 0) mexcl = -INFINITY;
    float mpre = fmaxf(moff, mexcl);
    float aa[8];
#pragma unroll
    for (int i = 0; i < 8; ++i) aa[i] = fmaxf(mpre, m8[i]);
    *(float4*)&a[base] = *(float4*)&aa[0];
    *(float4*)&a[base + 4] = *(float4*)&aa[4];
}

// ---------------- merged QKO + V projection, 128x128 bf16 MFMA ----------
__global__ __launch_bounds__(256, 4) void gemm_qkv(
    const unsigned short* __restrict__ normed, const unsigned short* __restrict__ Wcat1,
    const unsigned short* __restrict__ WvB, int K,
    unsigned short* __restrict__ qko, const float* __restrict__ bo,
    unsigned short* __restrict__ vout)
{
    __shared__ unsigned short As[128 * 64];
    __shared__ unsigned short Bs[128 * 64];
    int tid = threadIdx.x;
    int l = tid & 63, w = tid >> 6;
    int wg = (blockIdx.x & 7) * 256 + (blockIdx.x >> 3);   // bijective, 2048 blocks
    int job = (wg >= 1536) ? 1 : 0;
    const unsigned short* A;
    const unsigned short* Bw;
    int bm, bn;
    if (job == 0) { A = normed; Bw = Wcat1; bn = wg % 12; bm = wg / 12; }
    else          { int w2 = wg - 1536; A = WvB; Bw = normed; bm = w2 & 3; bn = w2 >> 2; }
    int wr = w >> 1, wc = w & 1;
    f32x4 acc[4][4] = {};
    const size_t abase = (size_t)(bm * 128) * K;
    const size_t bbase = (size_t)(bn * 128) * K;

    for (int ks = 0; ks < K; ks += 64) {
        __syncthreads();
#pragma unroll
        for (int i = 0; i < 4; ++i) {
            int off = (i * 256 + tid) * 8;
            int row = off >> 6, kc = off & 63;
            int kcs = kc ^ ((row & 7) << 3);
            gld_lds16(A + abase + (size_t)row * K + ks + kcs, &As[off]);
            gld_lds16(Bw + bbase + (size_t)row * K + ks + kcs, &Bs[off]);
        }
        __syncthreads();
#pragma unroll
        for (int kk = 0; kk < 2; ++kk) {
            int cbo = kk * 32 + (l >> 4) * 8;
            s8v af[4], bfv[4];
#pragma unroll
            for (int m = 0; m < 4; ++m) {
                int row = wr * 64 + m * 16 + (l & 15);
                af[m] = *(const s8v*)&As[row * 64 + (cbo ^ ((row & 7) << 3))];
            }
#pragma unroll
            for (int n = 0; n < 4; ++n) {
                int row = wc * 64 + n * 16 + (l & 15);
                bfv[n] = *(const s8v*)&Bs[row * 64 + (cbo ^ ((row & 7) << 3))];
            }
#pragma unroll
            for (int m = 0; m < 4; ++m)
#pragma unroll
                for (int n = 0; n < 4; ++n)
                    acc[m][n] = __builtin_amdgcn_mfma_f32_16x16x32_bf16(af[m], bfv[n], acc[m][n], 0, 0, 0);
        }
    }

    if (job == 0) {
#pragma unroll
        for (int m = 0; m < 4; ++m) {
#pragma unroll
            for (int n = 0; n < 4; ++n) {
                int col = bn * 128 + wc * 64 + n * 16 + (l & 15);
#pragma unroll
                for (int r = 0; r < 4; ++r) {
                    int row = bm * 128 + wr * 64 + m * 16 + (l >> 4) * 4 + r;
                    float v = acc[m][n][r];
                    if (col < 1024) v *= QKSCALE;
                    else {
                        float s = v + bo[col - 1024];
                        v = 1.0f / (1.0f + expf(-s));
                    }
                    qko[(size_t)row * 1536 + col] = f2b(v);
                }
            }
        }
    } else {
#pragma unroll
        for (int m = 0; m < 4; ++m) {
#pragma unroll
            for (int n = 0; n < 4; ++n) {
                int col = bn * 128 + wc * 64 + n * 16 + (l & 15);
#pragma unroll
                for (int r = 0; r < 4; ++r) {
                    int row = bm * 128 + wr * 64 + m * 16 + (l >> 4) * 4 + r;
                    vout[(size_t)row * MROWS + col] = f2b(acc[m][n][r]);
                }
            }
        }
    }
}

// ---------------- 128x128 bf16 MFMA GEMM (output projection) -------------
template <int EPI, int ORD>
__global__ __launch_bounds__(256, 4) void gemm_bt(
    const unsigned short* __restrict__ A, const unsigned short* __restrict__ Bw,
    int M, int N, int K, int ldo,
    unsigned short* __restrict__ outb, const float* __restrict__ bo,
    float* __restrict__ outf, const float* __restrict__ xres)
{
    __shared__ unsigned short As[128 * 64];
    __shared__ unsigned short Bs[128 * 64];
    int tid = threadIdx.x;
    int l = tid & 63, w = tid >> 6;
    int cpx = gridDim.x >> 3;
    int wg = (blockIdx.x & 7) * cpx + (blockIdx.x >> 3);
    int mb = M >> 7;
    int nb = N >> 7;
    int bm, bn;
    if (ORD == 0) { bm = wg % mb; bn = wg / mb; }
    else          { bn = wg % nb; bm = wg / nb; }
    int wr = w >> 1, wc = w & 1;
    f32x4 acc[4][4] = {};
    const size_t abase = (size_t)(bm * 128) * K;
    const size_t bbase = (size_t)(bn * 128) * K;

    for (int ks = 0; ks < K; ks += 64) {
        __syncthreads();
#pragma unroll
        for (int i = 0; i < 4; ++i) {
            int off = (i * 256 + tid) * 8;
            int row = off >> 6, kc = off & 63;
            int kcs = kc ^ ((row & 7) << 3);
            gld_lds16(A + abase + (size_t)row * K + ks + kcs, &As[off]);
            gld_lds16(Bw + bbase + (size_t)row * K + ks + kcs, &Bs[off]);
        }
        __syncthreads();
#pragma unroll
        for (int kk = 0; kk < 2; ++kk) {
            int cbo = kk * 32 + (l >> 4) * 8;
            s8v af[4], bfv[4];
#pragma unroll
            for (int m = 0; m < 4; ++m) {
                int row = wr * 64 + m * 16 + (l & 15);
                af[m] = *(const s8v*)&As[row * 64 + (cbo ^ ((row & 7) << 3))];
            }
#pragma unroll
            for (int n = 0; n < 4; ++n) {
                int row = wc * 64 + n * 16 + (l & 15);
                bfv[n] = *(const s8v*)&Bs[row * 64 + (cbo ^ ((row & 7) << 3))];
            }
#pragma unroll
            for (int m = 0; m < 4; ++m)
#pragma unroll
                for (int n = 0; n < 4; ++n)
                    acc[m][n] = __builtin_amdgcn_mfma_f32_16x16x32_bf16(af[m], bfv[n], acc[m][n], 0, 0, 0);
        }
    }

#pragma unroll
    for (int m = 0; m < 4; ++m) {
#pragma unroll
        for (int n = 0; n < 4; ++n) {
            int col = bn * 128 + wc * 64 + n * 16 + (l & 15);
#pragma unroll
            for (int r = 0; r < 4; ++r) {
                int row = bm * 128 + wr * 64 + m * 16 + (l >> 4) * 4 + r;
                float v = acc[m][n][r];
                if (EPI == 3) {
                    outb[(size_t)row * ldo + col] = f2b(v);
                } else {
                    size_t idx = (size_t)row * ldo + col;
                    outf[idx] = xres[idx] + v;
                }
            }
        }
    }
}

// ---------------- phase A: St[t][j] = exp(u_j - a_t)*(q_t.k_j), j<=t ------
__global__ __launch_bounds__(256) void phaseA_kernel(
    const unsigned short* __restrict__ qko,
    const float* __restrict__ u, const float* __restrict__ a,
    unsigned short* __restrict__ st, float* __restrict__ rowsum)
{
    __shared__ unsigned short Qs[64 * 32], Ks[128 * 32];
    int bid = blockIdx.x;
    int b = bid & 7, c = (bid >> 3) & 15, th = bid >> 7;
    int tid = threadIdx.x, l = tid & 63, wv = tid >> 6;
    size_t cb = (size_t)b * T_SEQ + c * CL;
    f32x4 acc[8] = {};
    for (int ks = 0; ks < 512; ks += 32) {
        __syncthreads();
        {
            int p = tid;
            int row = p >> 2, kc = (p & 3) * 8;
            gld_lds16(qko + (cb + th * 64 + row) * 1536 + ks + kc, &Qs[p * 8]);
#pragma unroll
            for (int rI = 0; rI < 2; ++rI) {
                int pp = rI * 256 + tid;
                int rw = pp >> 2, kk = (pp & 3) * 8;
                gld_lds16(qko + (cb + rw) * 1536 + 512 + ks + kk, &Ks[pp * 8]);
            }
        }
        __syncthreads();
        s8v af = *(const s8v*)&Qs[(wv * 16 + (l & 15)) * 32 + (l >> 4) * 8];
#pragma unroll
        for (int n = 0; n < 8; ++n) {
            s8v bf = *(const s8v*)&Ks[(n * 16 + (l & 15)) * 32 + (l >> 4) * 8];
            acc[n] = __builtin_amdgcn_mfma_f32_16x16x32_bf16(af, bf, acc[n], 0, 0, 0);
        }
    }
    float rs[4] = {0.f, 0.f, 0.f, 0.f};
    size_t stb = (size_t)(b * NC + c) * (CL * CL);
#pragma unroll
    for (int e = 0; e < 4; ++e) {
        int tl = th * 64 + wv * 16 + (l >> 4) * 4 + e;
        float a_t = a[cb + tl];
#pragma unroll
        for (int n = 0; n < 8; ++n) {
            int j = n * 16 + (l & 15);
            float val = (j <= tl) ? acc[n][e] * expf(u[cb + j] - a_t) : 0.0f;
            rs[e] += val;
            st[stb + (size_t)tl * CL + j] = f2b(val);
        }
    }
#pragma unroll
    for (int e = 0; e < 4; ++e) {
#pragma unroll
        for (int m = 1; m < 16; m <<= 1) rs[e] += __shfl_xor(rs[e], m, 64);
    }
    if ((l & 15) == 0) {
#pragma unroll
        for (int e = 0; e < 4; ++e)
            rowsum[cb + th * 64 + wv * 16 + (l >> 4) * 4 + e] = rs[e];
    }
}

// ---------------- kwprep2: transpose k from qko + scale; P row-sums ------
__global__ __launch_bounds__(256) void kwprep2_kernel(
    const unsigned short* __restrict__ qko,
    const float* __restrict__ u, const float* __restrict__ a,
    unsigned short* __restrict__ kw, float* __restrict__ P, float* __restrict__ aE)
{
    __shared__ unsigned short T[64][136];
    __shared__ float w_l[CL];
    int bid = blockIdx.x;
    int b = bid & 7, c = (bid >> 3) & 15, st = bid >> 7;   // st: 0..7
    int s0 = st * 64;
    int tid = threadIdx.x;
    size_t cb = (size_t)b * T_SEQ + c * CL;
    float a_e = a[cb + CL - 1];
    if (tid < CL) w_l[tid] = expf(u[cb + tid] - a_e);
    if (tid == 0 && st == 0) aE[b * NC + c] = a_e;
#pragma unroll
    for (int it = 0; it < 4; ++it) {
        int flat = it * 256 + tid;          // 0..1023
        int t = flat >> 3, g = flat & 7;
        s8v v = *(const s8v*)&qko[(cb + t) * 1536 + 512 + s0 + g * 8];
#pragma unroll
        for (int e = 0; e < 8; ++e) T[g * 8 + e][t] = (unsigned short)v[e];
    }
    __syncthreads();
    int s = tid >> 2, tg = tid & 3;
    float psum = 0.0f;
#pragma unroll
    for (int j = 0; j < 4; ++j) {
        int t0 = tg * 32 + j * 8;
        s8v kv = *(const s8v*)&T[s][t0];
        s8v kwv;
#pragma unroll
        for (int e = 0; e < 8; ++e) {
            float f = b2f((unsigned short)kv[e]) * w_l[t0 + e];
            kwv[e] = (short)f2b(f);
            psum += f;
        }
        *(s8v*)&kw[(size_t)(s0 + s) * MROWS + cb + t0] = kwv;
    }
    psum += __shfl_xor(psum, 1, 64);
    psum += __shfl_xor(psum, 2, 64);
    if (tg == 0) P[(size_t)(b * NC + c) * 512 + s0 + s] = psum;
}

// nhprev[b][c][s] = n-state before chunk c (ref aE[c-1]); scan over c.
__global__ __launch_bounds__(256) void nhscan_kernel(
    const float* __restrict__ P, const float* __restrict__ aE,
    float* __restrict__ nhprev)
{
    int gid = blockIdx.x * 256 + threadIdx.x;   // 0..4095
    int b = gid >> 9, s = gid & 511;
    float nh = 0.0f, aprev = 0.0f;
    for (int c = 0; c < NC; ++c) {
        nhprev[(size_t)(b * NC + c) * 512 + s] = nh;
        float ae = aE[b * NC + c];
        float gam = (c == 0) ? 0.0f : expf(aprev - ae);
        nh = gam * nh + P[(size_t)(b * NC + c) * 512 + s];
        aprev = ae;
    }
}

// rdnm[t] = 1 / max(|beta_t*(q_t.nhprev) + rowsum[t]|, 1)
__global__ __launch_bounds__(256) void denom_kernel(
    const unsigned short* __restrict__ qko, const float* __restrict__ nhprev,
    const float* __restrict__ aE, const float* __restrict__ a,
    const float* __restrict__ rowsum, float* __restrict__ rdnm)
{
    int wv = threadIdx.x >> 6, l = threadIdx.x & 63;
    int t = blockIdx.x * 4 + wv;      // 0..16383
    int b = t >> 11, c = (t & 2047) >> 7;
    const unsigned short* qrow = qko + (size_t)t * 1536 + l * 8;
    const float* nh = nhprev + (size_t)(b * NC + c) * 512 + l * 8;
    s8v qv = *(const s8v*)qrow;
    float4 n0 = *(const float4*)nh;
    float4 n1 = *(const float4*)(nh + 4);
    float nq = b2f((unsigned short)qv[0]) * n0.x + b2f((unsigned short)qv[1]) * n0.y
             + b2f((unsigned short)qv[2]) * n0.z + b2f((unsigned short)qv[3]) * n0.w
             + b2f((unsigned short)qv[4]) * n1.x + b2f((unsigned short)qv[5]) * n1.y
             + b2f((unsigned short)qv[6]) * n1.z + b2f((unsigned short)qv[7]) * n1.w;
#pragma unroll
    for (int m = 1; m < 64; m <<= 1) nq += __shfl_xor(nq, m, 64);
    if (l == 0) {
        float beta = (c == 0) ? 0.0f : expf(aE[b * NC + c - 1] - a[t]);
        rdnm[t] = 1.0f / fmaxf(fabsf(beta * nq + rowsum[t]), 1.0f);
    }
}

// ---------------- cscan2: C checkpoints, LDS-staged 64x64 tiles ----------
// Block = 256 thr (4 waves, 2x2 quadrants of 32x32), tile 64 v-rows x 64
// kw-rows. Grid 8b x 8rt x 8st = 512 blocks (2 blocks/CU). Per chunk the
// block stages v[64][128] + kw[64][128] into LDS (gld_lds16, granule XOR
// swizzle g^=row&7, source pre-swizzled per rule 21), double-buffered with
// counted vmcnt(8) so next chunk's loads stay in flight across barriers.
// Cuts global fetch 2x vs per-wave direct loads and adds 4x block reuse.
__global__ __launch_bounds__(256, 2) void cscan2_kernel(
    const unsigned short* __restrict__ kvT, const unsigned short* __restrict__ kw,
    const float* __restrict__ aE, unsigned short* __restrict__ chk)
{
    __shared__ unsigned short Vs[2][64 * 128];
    __shared__ unsigned short Ks[2][64 * 128];
    int bid = blockIdx.x;
    int b = bid & 7, rt = (bid >> 3) & 7, st = bid >> 6;   // 8 x 8 x 8
    int r0 = rt * 64, s0 = st * 64;
    int tid = threadIdx.x, l = tid & 63;
    int w = tid >> 6, wr = w >> 1, wc = w & 1;
    size_t tb = (size_t)b * T_SEQ;
    int srow = tid >> 4, sg = tid & 15;      // stage: 16 granules/row
    f32x4 acc[2][2] = {};
    float a_prev = 0.0f;

#define CSTAGE(c, buf) do { \
        size_t cb_ = tb + (size_t)(c) * CL; \
        _Pragma("unroll") \
        for (int i = 0; i < 4; ++i) { \
            int row_ = i * 16 + srow; \
            int gs_ = sg ^ (row_ & 7); \
            gld_lds16(kvT + (size_t)(512 + r0 + row_) * MROWS + cb_ + gs_ * 8, \
                      &Vs[buf][(i * 256 + tid) * 8]); \
        } \
        _Pragma("unroll") \
        for (int i = 0; i < 4; ++i) { \
            int row_ = i * 16 + srow; \
            int gs_ = sg ^ (row_ & 7); \
            gld_lds16(kw + (size_t)(s0 + row_) * MROWS + cb_ + gs_ * 8, \
                      &Ks[buf][(i * 256 + tid) * 8]); \
        } } while (0)

    CSTAGE(0, 0);
    for (int c = 0; c < NC; ++c) {
        int cur = c & 1;
        if (c + 1 < NC) { CSTAGE(c + 1, cur ^ 1); WAITV(8); }
        else            { WAITV(0); }
        BARSYNC();
        float a_e = aE[b * NC + c];
        if (c > 0) {
            unsigned short* slot = chk + (size_t)(b * (NC - 1) + (c - 1)) * (512 * 512);
#pragma unroll
            for (int m = 0; m < 2; ++m)
#pragma unroll
                for (int n = 0; n < 2; ++n)
#pragma unroll
                    for (int e = 0; e < 4; ++e) {
                        int r = r0 + wr * 32 + m * 16 + (l >> 4) * 4 + e;
                        int s = s0 + wc * 32 + n * 16 + (l & 15);
                        slot[r * 512 + s] = f2b(acc[m][n][e]);
                    }
            float gam = expf(a_prev - a_e);
#pragma unroll
            for (int m = 0; m < 2; ++m)
#pragma unroll
                for (int n = 0; n < 2; ++n)
#pragma unroll
                    for (int e = 0; e < 4; ++e) acc[m][n][e] *= gam;
        }
#pragma unroll
        for (int ks = 0; ks < 4; ++ks) {
            s8v vf[2], kf[2];
#pragma unroll
            for (int m = 0; m < 2; ++m) {
                int row = wr * 32 + m * 16 + (l & 15);
                int gf = ks * 4 + (l >> 4);
                vf[m] = *(const s8v*)&Vs[cur][row * 128 + ((gf ^ (row & 7)) << 3)];
            }
#pragma unroll
            for (int n = 0; n < 2; ++n) {
                int row = wc * 32 + n * 16 + (l & 15);
                int gf = ks * 4 + (l >> 4);
                kf[n] = *(const s8v*)&Ks[cur][row * 128 + ((gf ^ (row & 7)) << 3)];
            }
#pragma unroll
            for (int m = 0; m < 2; ++m)
#pragma unroll
                for (int n = 0; n < 2; ++n)
                    acc[m][n] = __builtin_amdgcn_mfma_f32_16x16x32_bf16(vf[m], kf[n], acc[m][n], 0, 0, 0);
        }
        a_prev = a_e;
        BARSYNC();
    }
#undef CSTAGE
}

// ---------------- hout: G = beta*(Q.Cchk^T) + St.V ; h = o*G*rdnm ----------
__global__ __launch_bounds__(512) void hout_kernel(
    const unsigned short* __restrict__ qko, const unsigned short* __restrict__ kvT,
    const unsigned short* __restrict__ st, const unsigned short* __restrict__ chk,
    const float* __restrict__ a, const float* __restrict__ aE,
    const float* __restrict__ rdnm, unsigned short* __restrict__ g)
{
    int bid = blockIdx.x;
    int b = bid & 7, cc = bid >> 3;
    int c = cc >> 1, rh = cc & 1;
    int tid = threadIdx.x, l = tid & 63, wv = tid >> 6;
    int mq = wv & 3;
    int rr = (wv >> 2) * 128 + rh * 256;
    size_t cb = (size_t)b * T_SEQ + c * CL;
    f32x4 acc[2][8] = {};

    if (c > 0) {
        const unsigned short* slot = chk + (size_t)(b * (NC - 1) + (c - 1)) * (512 * 512);
#pragma unroll
        for (int ks = 0; ks < 16; ++ks) {
            s8v aq[2];
#pragma unroll
            for (int mf = 0; mf < 2; ++mf)
                aq[mf] = *(const s8v*)&qko[(cb + mq * 32 + mf * 16 + (l & 15)) * 1536 + ks * 32 + (l >> 4) * 8];
#pragma unroll
            for (int n = 0; n < 8; ++n) {
                s8v bc = *(const s8v*)&slot[(size_t)(rr + n * 16 + (l & 15)) * 512 + ks * 32 + (l >> 4) * 8];
                acc[0][n] = __builtin_amdgcn_mfma_f32_16x16x32_bf16(aq[0], bc, acc[0][n], 0, 0, 0);
                acc[1][n] = __builtin_amdgcn_mfma_f32_16x16x32_bf16(aq[1], bc, acc[1][n], 0, 0, 0);
            }
        }
        float aprev = aE[b * NC + c - 1];
#pragma unroll
        for (int mf = 0; mf < 2; ++mf)
#pragma unroll
            for (int e = 0; e < 4; ++e) {
                int t = mq * 32 + mf * 16 + (l >> 4) * 4 + e;
                float bta = expf(aprev - a[cb + t]);
#pragma unroll
                for (int n = 0; n < 8; ++n) acc[mf][n][e] *= bta;
            }
    }
    const unsigned short* stp = st + (size_t)(b * NC + c) * (CL * CL);
#pragma unroll
    for (int ks = 0; ks < 4; ++ks) {
        s8v aq[2];
#pragma unroll
        for (int mf = 0; mf < 2; ++mf)
            aq[mf] = *(const s8v*)&stp[(size_t)(mq * 32 + mf * 16 + (l & 15)) * CL + ks * 32 + (l >> 4) * 8];
#pragma unroll
        for (int n = 0; n < 8; ++n) {
            s8v bv = *(const s8v*)&kvT[(size_t)(512 + rr + n * 16 + (l & 15)) * MROWS + cb + ks * 32 + (l >> 4) * 8];
            acc[0][n] = __builtin_amdgcn_mfma_f32_16x16x32_bf16(aq[0], bv, acc[0][n], 0, 0, 0);
            acc[1][n] = __builtin_amdgcn_mfma_f32_16x16x32_bf16(aq[1], bv, acc[1][n], 0, 0, 0);
        }
    }
#pragma unroll
    for (int mf = 0; mf < 2; ++mf)
#pragma unroll
        for (int e = 0; e < 4; ++e) {
            int t = mq * 32 + mf * 16 + (l >> 4) * 4 + e;
            float rd = rdnm[cb + t];
#pragma unroll
            for (int n = 0; n < 8; ++n) {
                int r = rr + n * 16 + (l & 15);
                float ov = b2f(qko[(cb + t) * 1536 + 1024 + r]);
                g[(cb + t) * DH + r] = f2b(ov * acc[mf][n][e] * rd);
            }
        }
}

extern "C" void kernel_launch(void* const* d_in, const int* in_sizes, int n_in,
                              void* d_out, int out_size, void* d_ws, size_t ws_size,
                              hipStream_t stream)
{
    (void)in_sizes; (void)n_in; (void)out_size; (void)ws_size;
    const float* x    = (const float*)d_in[0];
    const float* nw   = (const float*)d_in[1];
    const float* Wq   = (const float*)d_in[2];
    const float* Wk   = (const float*)d_in[3];
    const float* Wv   = (const float*)d_in[4];
    const float* wi   = (const float*)d_in[5];
    const float* wib  = (const float*)d_in[6];
    const float* wf   = (const float*)d_in[7];
    const float* wfb  = (const float*)d_in[8];
    const float* Wo   = (const float*)d_in[9];
    const float* bo   = (const float*)d_in[10];
    const float* Wout = (const float*)d_in[11];
    float* out = (float*)d_out;

    char* ws = (char*)d_ws;
    unsigned short* qko    = (unsigned short*)ws;                        // 0 .. 50,331,648
    unsigned short* kvT    = (unsigned short*)(ws + 50331648);           // .. 83,886,080 (v in rows 512+)
    unsigned short* normed = (unsigned short*)(ws + 83886080);           // .. 117,440,512
    unsigned short* g      = normed;                                     // first 16 MB (normed dead)
    unsigned short* kw     = (unsigned short*)(ws + 100663296);          // 16 MB (normed dead)
    float* Pbuf   = (float*)(ws + 117440512);                            // 262,144 (Wcat1 dead)
    float* nhprev = (float*)(ws + 117702656);                            // 262,144
    float* aE     = (float*)(ws + 117964800);                            // 512
    unsigned short* Wcat1  = (unsigned short*)(ws + 117440512);          // 3 MB (dead after gemm_qkv)
    unsigned short* WvB    = (unsigned short*)(ws + 120586240);          // 1 MB
    unsigned short* Woutb  = (unsigned short*)(ws + 122683392);          // 1 MB
    float* zi     = (float*)(ws + 123731968);
    float* zf     = zi + MROWS;
    float* uarr   = zf + MROWS;
    float* aarr   = uarr + MROWS;
    float* rowsum = aarr + MROWS;
    float* rdnm   = rowsum + MROWS;                                      // ends ~124.1 MB

    // d_out as scratch until final gemm: Cchk (60 MiB) + stbuf (4 MiB)
    unsigned short* chk   = (unsigned short*)d_out;                      // 8*15*512*512*2
    unsigned short* stbuf = (unsigned short*)((char*)d_out + 62914560);  // 8*16*128*128*2

    norm_kernel    <<<MROWS, 256, 0, stream>>>(x, nw, wi, wf, wib, wfb, normed, zi, zf,
                                               Wq, Wk, Wo, Wv, Wout, Wcat1, WvB, Woutb);
    mscan2_kernel  <<<NBATCH, 256, 0, stream>>>(zi, zf, uarr, aarr);
    // merged QKO (1536 tiles) + V-proj (512 tiles): 2048 blocks = 2 exact rounds
    gemm_qkv       <<<2048, 256, 0, stream>>>(normed, Wcat1, WvB, DM, qko, bo, kvT + (size_t)512 * MROWS);
    phaseA_kernel  <<<256, 256, 0, stream>>>(qko, uarr, aarr, stbuf, rowsum);
    // k transpose + weight + P, straight from qko (replaces ktrans+kwprep)
    kwprep2_kernel <<<1024, 256, 0, stream>>>(qko, uarr, aarr, kw, Pbuf, aE);
    nhscan_kernel  <<<16, 256, 0, stream>>>(Pbuf, aE, nhprev);
    denom_kernel   <<<4096, 256, 0, stream>>>(qko, nhprev, aE, aarr, rowsum, rdnm);
    cscan2_kernel  <<<512, 256, 0, stream>>>(kvT, kw, aE, chk);
    hout_kernel    <<<256, 512, 0, stream>>>(qko, kvT, stbuf, chk, aarr, aE, rdnm, g);
    // A=g (16MB) >> B=Woutb (1MB): ORD=1 (R0 measured config, 1024 = exact round)
    gemm_bt<1, 1>  <<<128 * 8, 256, 0, stream>>>(g, Woutb, MROWS, DM, DH, DM, nullptr, nullptr, out, x);
}

// Round 5
// 273.323 us; speedup vs baseline: 1.3198x; 1.0030x over previous
//
#include <hip/hip_runtime.h>
#include <cstdint>
#include <cmath>

#define T_SEQ 2048
#define NBATCH 8
#define DM 1024
#define DH 512
#define MROWS (NBATCH * T_SEQ)   // 16384
#define NC 16                    // chunks per batch
#define CL 128                   // chunk length

typedef short s8v __attribute__((ext_vector_type(8)));
typedef float f32x4 __attribute__((ext_vector_type(4)));

typedef unsigned int __attribute__((address_space(1))) uint_g;
typedef unsigned int __attribute__((address_space(3))) uint_l;

#define QKSCALE 0.044194173824159216f   // 1/sqrt(512)

__device__ __forceinline__ float b2f(unsigned short s) {
    union { unsigned u; float f; } c; c.u = ((unsigned)s) << 16; return c.f;
}
__device__ __forceinline__ unsigned short f2b(float f) {
    union { float f; unsigned u; } c; c.f = f;
    unsigned r = c.u + 0x7fffu + ((c.u >> 16) & 1u);
    return (unsigned short)(r >> 16);
}
__device__ __forceinline__ void gld_lds16(const void* g, void* l) {
    __builtin_amdgcn_global_load_lds((const uint_g*)g, (uint_l*)l, 16, 0, 0);
}

#define WAITV(N) asm volatile("s_waitcnt vmcnt(" #N ")" ::: "memory")
#define BARSYNC() do { asm volatile("" ::: "memory"); __builtin_amdgcn_s_barrier(); asm volatile("" ::: "memory"); } while (0)

// ---------------- RMSNorm + zi/zf + fused weight conversion ----------------
__global__ __launch_bounds__(256) void norm_kernel(
    const float* __restrict__ x, const float* __restrict__ nw,
    const float* __restrict__ wi, const float* __restrict__ wf,
    const float* __restrict__ wib, const float* __restrict__ wfb,
    unsigned short* __restrict__ normed, float* __restrict__ zi, float* __restrict__ zf,
    const float* __restrict__ Wq, const float* __restrict__ Wk,
    const float* __restrict__ Wo, const float* __restrict__ Wv,
    const float* __restrict__ Wout,
    unsigned short* __restrict__ Wcat1, unsigned short* __restrict__ WvB,
    unsigned short* __restrict__ Woutb)
{
    int t = blockIdx.x, tid = threadIdx.x;
    float4 xv = ((const float4*)(x + (size_t)t * DM))[tid];
    float ss = xv.x * xv.x + xv.y * xv.y + xv.z * xv.z + xv.w * xv.w;
#pragma unroll
    for (int m = 1; m < 64; m <<= 1) ss += __shfl_xor(ss, m, 64);
    __shared__ float sred[4];
    __shared__ float sred2[8];
    if ((tid & 63) == 0) sred[tid >> 6] = ss;
    __syncthreads();
    ss = sred[0] + sred[1] + sred[2] + sred[3];
    float rstd = rsqrtf(ss * (1.0f / DM) + 1e-6f);
    float4 nwv = ((const float4*)nw)[tid];
    float n0 = xv.x * rstd * nwv.x, n1 = xv.y * rstd * nwv.y;
    float n2 = xv.z * rstd * nwv.z, n3 = xv.w * rstd * nwv.w;
    ushort4 pk;
    pk.x = f2b(n0); pk.y = f2b(n1); pk.z = f2b(n2); pk.w = f2b(n3);
    ((ushort4*)(normed + (size_t)t * DM))[tid] = pk;
    float4 wiv = ((const float4*)wi)[tid];
    float4 wfv = ((const float4*)wf)[tid];
    float pzi = n0 * wiv.x + n1 * wiv.y + n2 * wiv.z + n3 * wiv.w;
    float pzf = n0 * wfv.x + n1 * wfv.y + n2 * wfv.z + n3 * wfv.w;
#pragma unroll
    for (int m = 1; m < 64; m <<= 1) {
        pzi += __shfl_xor(pzi, m, 64);
        pzf += __shfl_xor(pzf, m, 64);
    }
    if ((tid & 63) == 0) { sred2[tid >> 6] = pzi; sred2[4 + (tid >> 6)] = pzf; }
    __syncthreads();
    if (tid == 0) {
        zi[t] = sred2[0] + sred2[1] + sred2[2] + sred2[3] + wib[0];
        zf[t] = sred2[4] + sred2[5] + sred2[6] + sred2[7] + wfb[0];
    }
    // ---- fused weight conversion ----
    if (tid < 160) {
        int idx = blockIdx.x * 160 + tid;
        if (idx < 1572864) {
            int nrow = idx >> 10;
            float v;
            if      (nrow < 512)  v = Wq[idx];
            else if (nrow < 1024) v = Wk[idx - 512 * 1024];
            else                  v = Wo[idx - 1024 * 1024];
            Wcat1[idx] = f2b(v);
        } else if (idx < 2097152) {
            int j = idx - 1572864;
            WvB[j] = f2b(Wv[j]);
        } else {
            int j = idx - 2097152;
            Woutb[j] = f2b(Wout[j]);
        }
    }
}

// ---------------- merged QKO + V projection + mscan2 (blocks 2048+) ------
// Blocks 0..2047: GEMM (2 exact rounds at 4/CU). Blocks 2048..2055: the
// u/a scan (independent of GEMM; hides under round 2).
__global__ __launch_bounds__(256, 4) void gemm_qkv_ms(
    const unsigned short* __restrict__ normed, const unsigned short* __restrict__ Wcat1,
    const unsigned short* __restrict__ WvB, int K,
    unsigned short* __restrict__ qko, const float* __restrict__ bo,
    unsigned short* __restrict__ vout,
    const float* __restrict__ zi, const float* __restrict__ zf,
    float* __restrict__ u, float* __restrict__ a)
{
    __shared__ unsigned short As[128 * 64];
    __shared__ unsigned short Bs[128 * 64];
    __shared__ float wt[4];
    int tid = threadIdx.x;

    if (blockIdx.x >= 2048) {
        // ---- mscan2 body ----
        int b = blockIdx.x - 2048, lane = tid & 63, wid = tid >> 6;
        size_t base = (size_t)b * T_SEQ + tid * 8;
        float z_f[8], z_i[8];
        *(float4*)&z_f[0] = *(const float4*)&zf[base];
        *(float4*)&z_f[4] = *(const float4*)&zf[base + 4];
        *(float4*)&z_i[0] = *(const float4*)&zi[base];
        *(float4*)&z_i[4] = *(const float4*)&zi[base + 4];
        float c8[8]; float run = 0.0f;
#pragma unroll
        for (int i = 0; i < 8; ++i) { run += z_f[i]; c8[i] = run; }
        float v = run;
#pragma unroll
        for (int d = 1; d < 64; d <<= 1) {
            float o = __shfl_up(v, d, 64);
            if (lane >= d) v += o;
        }
        if (lane == 63) wt[wid] = v;
        __syncthreads();
        float woff = 0.0f;
        for (int j = 0; j < wid; ++j) woff += wt[j];
        float excl = __shfl_up(v, 1, 64);
        if (lane == 0) excl = 0.0f;
        float pre = woff + excl;
        float uu[8];
#pragma unroll
        for (int i = 0; i < 8; ++i) uu[i] = z_i[i] - (pre + c8[i]);
        *(float4*)&u[base] = *(float4*)&uu[0];
        *(float4*)&u[base + 4] = *(float4*)&uu[4];
        __syncthreads();
        float m8[8]; float rm = -INFINITY;
#pragma unroll
        for (int i = 0; i < 8; ++i) { rm = fmaxf(rm, uu[i]); m8[i] = rm; }
        float mv = rm;
#pragma unroll
        for (int d = 1; d < 64; d <<= 1) {
            float o = __shfl_up(mv, d, 64);
            if (lane >= d) mv = fmaxf(mv, o);
        }
        if (lane == 63) wt[wid] = mv;
        __syncthreads();
        float moff = -INFINITY;
        for (int j = 0; j < wid; ++j) moff = fmaxf(moff, wt[j]);
        float mexcl = __shfl_up(mv, 1, 64);
        if (lane == 0) mexcl = -INFINITY;
        float mpre = fmaxf(moff, mexcl);
        float aa[8];
#pragma unroll
        for (int i = 0; i < 8; ++i) aa[i] = fmaxf(mpre, m8[i]);
        *(float4*)&a[base] = *(float4*)&aa[0];
        *(float4*)&a[base + 4] = *(float4*)&aa[4];
        return;
    }

    // ---- GEMM body ----
    int l = tid & 63, w = tid >> 6;
    int wg = (blockIdx.x & 7) * 256 + (blockIdx.x >> 3);   // bijective, 2048 blocks
    int job = (wg >= 1536) ? 1 : 0;
    const unsigned short* A;
    const unsigned short* Bw;
    int bm, bn;
    if (job == 0) { A = normed; Bw = Wcat1; bn = wg % 12; bm = wg / 12; }
    else          { int w2 = wg - 1536; A = WvB; Bw = normed; bm = w2 & 3; bn = w2 >> 2; }
    int wr = w >> 1, wc = w & 1;
    f32x4 acc[4][4] = {};
    const size_t abase = (size_t)(bm * 128) * K;
    const size_t bbase = (size_t)(bn * 128) * K;

    for (int ks = 0; ks < K; ks += 64) {
        __syncthreads();
#pragma unroll
        for (int i = 0; i < 4; ++i) {
            int off = (i * 256 + tid) * 8;
            int row = off >> 6, kc = off & 63;
            int kcs = kc ^ ((row & 7) << 3);
            gld_lds16(A + abase + (size_t)row * K + ks + kcs, &As[off]);
            gld_lds16(Bw + bbase + (size_t)row * K + ks + kcs, &Bs[off]);
        }
        __syncthreads();
#pragma unroll
        for (int kk = 0; kk < 2; ++kk) {
            int cbo = kk * 32 + (l >> 4) * 8;
            s8v af[4], bfv[4];
#pragma unroll
            for (int m = 0; m < 4; ++m) {
                int row = wr * 64 + m * 16 + (l & 15);
                af[m] = *(const s8v*)&As[row * 64 + (cbo ^ ((row & 7) << 3))];
            }
#pragma unroll
            for (int n = 0; n < 4; ++n) {
                int row = wc * 64 + n * 16 + (l & 15);
                bfv[n] = *(const s8v*)&Bs[row * 64 + (cbo ^ ((row & 7) << 3))];
            }
#pragma unroll
            for (int m = 0; m < 4; ++m)
#pragma unroll
                for (int n = 0; n < 4; ++n)
                    acc[m][n] = __builtin_amdgcn_mfma_f32_16x16x32_bf16(af[m], bfv[n], acc[m][n], 0, 0, 0);
        }
    }

    if (job == 0) {
#pragma unroll
        for (int m = 0; m < 4; ++m) {
#pragma unroll
            for (int n = 0; n < 4; ++n) {
                int col = bn * 128 + wc * 64 + n * 16 + (l & 15);
#pragma unroll
                for (int r = 0; r < 4; ++r) {
                    int row = bm * 128 + wr * 64 + m * 16 + (l >> 4) * 4 + r;
                    float v = acc[m][n][r];
                    if (col < 1024) v *= QKSCALE;
                    else {
                        float s = v + bo[col - 1024];
                        v = 1.0f / (1.0f + expf(-s));
                    }
                    qko[(size_t)row * 1536 + col] = f2b(v);
                }
            }
        }
    } else {
#pragma unroll
        for (int m = 0; m < 4; ++m) {
#pragma unroll
            for (int n = 0; n < 4; ++n) {
                int col = bn * 128 + wc * 64 + n * 16 + (l & 15);
#pragma unroll
                for (int r = 0; r < 4; ++r) {
                    int row = bm * 128 + wr * 64 + m * 16 + (l >> 4) * 4 + r;
                    vout[(size_t)row * MROWS + col] = f2b(acc[m][n][r]);
                }
            }
        }
    }
}

// ---------------- 128x128 bf16 MFMA GEMM (output projection) -------------
template <int EPI, int ORD>
__global__ __launch_bounds__(256, 4) void gemm_bt(
    const unsigned short* __restrict__ A, const unsigned short* __restrict__ Bw,
    int M, int N, int K, int ldo,
    unsigned short* __restrict__ outb, const float* __restrict__ bo,
    float* __restrict__ outf, const float* __restrict__ xres)
{
    __shared__ unsigned short As[128 * 64];
    __shared__ unsigned short Bs[128 * 64];
    int tid = threadIdx.x;
    int l = tid & 63, w = tid >> 6;
    int cpx = gridDim.x >> 3;
    int wg = (blockIdx.x & 7) * cpx + (blockIdx.x >> 3);
    int mb = M >> 7;
    int nb = N >> 7;
    int bm, bn;
    if (ORD == 0) { bm = wg % mb; bn = wg / mb; }
    else          { bn = wg % nb; bm = wg / nb; }
    int wr = w >> 1, wc = w & 1;
    f32x4 acc[4][4] = {};
    const size_t abase = (size_t)(bm * 128) * K;
    const size_t bbase = (size_t)(bn * 128) * K;

    for (int ks = 0; ks < K; ks += 64) {
        __syncthreads();
#pragma unroll
        for (int i = 0; i < 4; ++i) {
            int off = (i * 256 + tid) * 8;
            int row = off >> 6, kc = off & 63;
            int kcs = kc ^ ((row & 7) << 3);
            gld_lds16(A + abase + (size_t)row * K + ks + kcs, &As[off]);
            gld_lds16(Bw + bbase + (size_t)row * K + ks + kcs, &Bs[off]);
        }
        __syncthreads();
#pragma unroll
        for (int kk = 0; kk < 2; ++kk) {
            int cbo = kk * 32 + (l >> 4) * 8;
            s8v af[4], bfv[4];
#pragma unroll
            for (int m = 0; m < 4; ++m) {
                int row = wr * 64 + m * 16 + (l & 15);
                af[m] = *(const s8v*)&As[row * 64 + (cbo ^ ((row & 7) << 3))];
            }
#pragma unroll
            for (int n = 0; n < 4; ++n) {
                int row = wc * 64 + n * 16 + (l & 15);
                bfv[n] = *(const s8v*)&Bs[row * 64 + (cbo ^ ((row & 7) << 3))];
            }
#pragma unroll
            for (int m = 0; m < 4; ++m)
#pragma unroll
                for (int n = 0; n < 4; ++n)
                    acc[m][n] = __builtin_amdgcn_mfma_f32_16x16x32_bf16(af[m], bfv[n], acc[m][n], 0, 0, 0);
        }
    }

#pragma unroll
    for (int m = 0; m < 4; ++m) {
#pragma unroll
        for (int n = 0; n < 4; ++n) {
            int col = bn * 128 + wc * 64 + n * 16 + (l & 15);
#pragma unroll
            for (int r = 0; r < 4; ++r) {
                int row = bm * 128 + wr * 64 + m * 16 + (l >> 4) * 4 + r;
                float v = acc[m][n][r];
                if (EPI == 3) {
                    outb[(size_t)row * ldo + col] = f2b(v);
                } else {
                    size_t idx = (size_t)row * ldo + col;
                    outf[idx] = xres[idx] + v;
                }
            }
        }
    }
}

// ---------------- fusedA: phaseA (blocks 0..255) + kwprep2 (256..1279) ----
// Both depend only on {qko, u, a}; disjoint outputs; co-resident blocks
// fill each other's idle wave slots. Shared-LDS union (17.9 KB).
__global__ __launch_bounds__(256) void fusedA_kernel(
    const unsigned short* __restrict__ qko,
    const float* __restrict__ u, const float* __restrict__ a,
    unsigned short* __restrict__ stb, float* __restrict__ rowsum,
    unsigned short* __restrict__ kw, float* __restrict__ P, float* __restrict__ aE)
{
    __shared__ char smem[17920];
    int bid = blockIdx.x, tid = threadIdx.x;

    if (bid < 256) {
        // ---- phaseA: St[t][j] = exp(u_j - a_t)*(q_t.k_j), j<=t ----
        unsigned short* Qs = (unsigned short*)smem;            // 64*32
        unsigned short* Ks = (unsigned short*)(smem + 4096);   // 128*32
        int b = bid & 7, c = (bid >> 3) & 15, th = bid >> 7;
        int l = tid & 63, wv = tid >> 6;
        size_t cb = (size_t)b * T_SEQ + c * CL;
        f32x4 acc[8] = {};
        for (int ks = 0; ks < 512; ks += 32) {
            __syncthreads();
            {
                int p = tid;
                int row = p >> 2, kc = (p & 3) * 8;
                gld_lds16(qko + (cb + th * 64 + row) * 1536 + ks + kc, &Qs[p * 8]);
#pragma unroll
                for (int rI = 0; rI < 2; ++rI) {
                    int pp = rI * 256 + tid;
                    int rw = pp >> 2, kk = (pp & 3) * 8;
                    gld_lds16(qko + (cb + rw) * 1536 + 512 + ks + kk, &Ks[pp * 8]);
                }
            }
            __syncthreads();
            s8v af = *(const s8v*)&Qs[(wv * 16 + (l & 15)) * 32 + (l >> 4) * 8];
#pragma unroll
            for (int n = 0; n < 8; ++n) {
                s8v bf = *(const s8v*)&Ks[(n * 16 + (l & 15)) * 32 + (l >> 4) * 8];
                acc[n] = __builtin_amdgcn_mfma_f32_16x16x32_bf16(af, bf, acc[n], 0, 0, 0);
            }
        }
        float rs[4] = {0.f, 0.f, 0.f, 0.f};
        size_t stbase = (size_t)(b * NC + c) * (CL * CL);
#pragma unroll
        for (int e = 0; e < 4; ++e) {
            int tl = th * 64 + wv * 16 + (l >> 4) * 4 + e;
            float a_t = a[cb + tl];
#pragma unroll
            for (int n = 0; n < 8; ++n) {
                int j = n * 16 + (l & 15);
                float val = (j <= tl) ? acc[n][e] * expf(u[cb + j] - a_t) : 0.0f;
                rs[e] += val;
                stb[stbase + (size_t)tl * CL + j] = f2b(val);
            }
        }
#pragma unroll
        for (int e = 0; e < 4; ++e) {
#pragma unroll
            for (int m = 1; m < 16; m <<= 1) rs[e] += __shfl_xor(rs[e], m, 64);
        }
        if ((l & 15) == 0) {
#pragma unroll
            for (int e = 0; e < 4; ++e)
                rowsum[cb + th * 64 + wv * 16 + (l >> 4) * 4 + e] = rs[e];
        }
    } else {
        // ---- kwprep2: transpose k + scale; P row-sums ----
        unsigned short (*T)[136] = (unsigned short(*)[136])smem;   // 64*136
        float* w_l = (float*)(smem + 17408);                       // CL floats
        int kb = bid - 256;
        int b = kb & 7, c = (kb >> 3) & 15, stt = kb >> 7;   // stt: 0..7
        int s0 = stt * 64;
        size_t cb = (size_t)b * T_SEQ + c * CL;
        float a_e = a[cb + CL - 1];
        if (tid < CL) w_l[tid] = expf(u[cb + tid] - a_e);
        if (tid == 0 && stt == 0) aE[b * NC + c] = a_e;
#pragma unroll
        for (int it = 0; it < 4; ++it) {
            int flat = it * 256 + tid;          // 0..1023
            int t = flat >> 3, g = flat & 7;
            s8v v = *(const s8v*)&qko[(cb + t) * 1536 + 512 + s0 + g * 8];
#pragma unroll
            for (int e = 0; e < 8; ++e) T[g * 8 + e][t] = (unsigned short)v[e];
        }
        __syncthreads();
        int s = tid >> 2, tg = tid & 3;
        float psum = 0.0f;
#pragma unroll
        for (int j = 0; j < 4; ++j) {
            int t0 = tg * 32 + j * 8;
            s8v kv = *(const s8v*)&T[s][t0];
            s8v kwv;
#pragma unroll
            for (int e = 0; e < 8; ++e) {
                float f = b2f((unsigned short)kv[e]) * w_l[t0 + e];
                kwv[e] = (short)f2b(f);
                psum += f;
            }
            *(s8v*)&kw[(size_t)(s0 + s) * MROWS + cb + t0] = kwv;
        }
        psum += __shfl_xor(psum, 1, 64);
        psum += __shfl_xor(psum, 2, 64);
        if (tg == 0) P[(size_t)(b * NC + c) * 512 + s0 + s] = psum;
    }
}

// ---------------- cscan3: C checkpoints + fused denom/nhscan epilogue ----
// Main scan: as cscan2 (LDS-staged 64x64 tiles, dbuf, counted vmcnt).
// Epilogue: each block's 4 waves handle 32 t's (bid*32..+31, one (b,c));
// nhprev recomputed inline per wave (<=15 scan steps over L2-hot P).
__global__ __launch_bounds__(256, 2) void cscan3_kernel(
    const unsigned short* __restrict__ kvT, const unsigned short* __restrict__ kw,
    const float* __restrict__ aE, unsigned short* __restrict__ chk,
    const unsigned short* __restrict__ qko, const float* __restrict__ P,
    const float* __restrict__ a, const float* __restrict__ rowsum,
    float* __restrict__ rdnm)
{
    __shared__ unsigned short Vs[2][64 * 128];
    __shared__ unsigned short Ks[2][64 * 128];
    int bid = blockIdx.x;
    int b = bid & 7, rt = (bid >> 3) & 7, st = bid >> 6;   // 8 x 8 x 8
    int r0 = rt * 64, s0 = st * 64;
    int tid = threadIdx.x, l = tid & 63;
    int w = tid >> 6, wr = w >> 1, wc = w & 1;
    size_t tb = (size_t)b * T_SEQ;
    int srow = tid >> 4, sg = tid & 15;
    f32x4 acc[2][2] = {};
    float a_prev = 0.0f;

#define CSTAGE(c, buf) do { \
        size_t cb_ = tb + (size_t)(c) * CL; \
        _Pragma("unroll") \
        for (int i = 0; i < 4; ++i) { \
            int row_ = i * 16 + srow; \
            int gs_ = sg ^ (row_ & 7); \
            gld_lds16(kvT + (size_t)(512 + r0 + row_) * MROWS + cb_ + gs_ * 8, \
                      &Vs[buf][(i * 256 + tid) * 8]); \
        } \
        _Pragma("unroll") \
        for (int i = 0; i < 4; ++i) { \
            int row_ = i * 16 + srow; \
            int gs_ = sg ^ (row_ & 7); \
            gld_lds16(kw + (size_t)(s0 + row_) * MROWS + cb_ + gs_ * 8, \
                      &Ks[buf][(i * 256 + tid) * 8]); \
        } } while (0)

    CSTAGE(0, 0);
    for (int c = 0; c < NC; ++c) {
        int cur = c & 1;
        if (c + 1 < NC) { CSTAGE(c + 1, cur ^ 1); WAITV(8); }
        else            { WAITV(0); }
        BARSYNC();
        float a_e = aE[b * NC + c];
        if (c > 0) {
            unsigned short* slot = chk + (size_t)(b * (NC - 1) + (c - 1)) * (512 * 512);
#pragma unroll
            for (int m = 0; m < 2; ++m)
#pragma unroll
                for (int n = 0; n < 2; ++n)
#pragma unroll
                    for (int e = 0; e < 4; ++e) {
                        int r = r0 + wr * 32 + m * 16 + (l >> 4) * 4 + e;
                        int s = s0 + wc * 32 + n * 16 + (l & 15);
                        slot[r * 512 + s] = f2b(acc[m][n][e]);
                    }
            float gam = expf(a_prev - a_e);
#pragma unroll
            for (int m = 0; m < 2; ++m)
#pragma unroll
                for (int n = 0; n < 2; ++n)
#pragma unroll
                    for (int e = 0; e < 4; ++e) acc[m][n][e] *= gam;
        }
#pragma unroll
        for (int ks = 0; ks < 4; ++ks) {
            s8v vf[2], kf[2];
#pragma unroll
            for (int m = 0; m < 2; ++m) {
                int row = wr * 32 + m * 16 + (l & 15);
                int gf = ks * 4 + (l >> 4);
                vf[m] = *(const s8v*)&Vs[cur][row * 128 + ((gf ^ (row & 7)) << 3)];
            }
#pragma unroll
            for (int n = 0; n < 2; ++n) {
                int row = wc * 32 + n * 16 + (l & 15);
                int gf = ks * 4 + (l >> 4);
                kf[n] = *(const s8v*)&Ks[cur][row * 128 + ((gf ^ (row & 7)) << 3)];
            }
#pragma unroll
            for (int m = 0; m < 2; ++m)
#pragma unroll
                for (int n = 0; n < 2; ++n)
                    acc[m][n] = __builtin_amdgcn_mfma_f32_16x16x32_bf16(vf[m], kf[n], acc[m][n], 0, 0, 0);
        }
        a_prev = a_e;
        BARSYNC();
    }
#undef CSTAGE

    // ---- fused denom (nhscan inline): 32 t's per block, 8 per wave ----
    {
        int wv = tid >> 6;
        int t0 = bid * 32 + wv * 8;
        int bt = t0 >> 11, ct = (t0 & 2047) >> 7;
        float nh[8] = {0, 0, 0, 0, 0, 0, 0, 0};
        float aprev = 0.0f;
        for (int cp = 0; cp < ct; ++cp) {
            float ae = aE[bt * NC + cp];
            float gam = (cp == 0) ? 0.0f : expf(aprev - ae);
            const float* Pp = P + (size_t)(bt * NC + cp) * 512 + l * 8;
            float4 p0 = *(const float4*)Pp;
            float4 p1 = *(const float4*)(Pp + 4);
#pragma unroll
            for (int e = 0; e < 8; ++e) nh[e] *= gam;
            nh[0] += p0.x; nh[1] += p0.y; nh[2] += p0.z; nh[3] += p0.w;
            nh[4] += p1.x; nh[5] += p1.y; nh[6] += p1.z; nh[7] += p1.w;
            aprev = ae;
        }
        float aeprev = (ct > 0) ? aE[bt * NC + ct - 1] : 0.0f;
        for (int tt = 0; tt < 8; ++tt) {
            int tc = t0 + tt;
            s8v qv = *(const s8v*)(qko + (size_t)tc * 1536 + l * 8);
            float nq = 0.0f;
#pragma unroll
            for (int e = 0; e < 8; ++e) nq += b2f((unsigned short)qv[e]) * nh[e];
#pragma unroll
            for (int m = 1; m < 64; m <<= 1) nq += __shfl_xor(nq, m, 64);
            if (l == 0) {
                float beta = (ct == 0) ? 0.0f : expf(aeprev - a[tc]);
                rdnm[tc] = 1.0f / fmaxf(fabsf(beta * nq + rowsum[tc]), 1.0f);
            }
        }
    }
}

// ---------------- hout: G = beta*(Q.Cchk^T) + St.V ; h = o*G*rdnm ----------
__global__ __launch_bounds__(512) void hout_kernel(
    const unsigned short* __restrict__ qko, const unsigned short* __restrict__ kvT,
    const unsigned short* __restrict__ st, const unsigned short* __restrict__ chk,
    const float* __restrict__ a, const float* __restrict__ aE,
    const float* __restrict__ rdnm, unsigned short* __restrict__ g)
{
    int bid = blockIdx.x;
    int b = bid & 7, cc = bid >> 3;
    int c = cc >> 1, rh = cc & 1;
    int tid = threadIdx.x, l = tid & 63, wv = tid >> 6;
    int mq = wv & 3;
    int rr = (wv >> 2) * 128 + rh * 256;
    size_t cb = (size_t)b * T_SEQ + c * CL;
    f32x4 acc[2][8] = {};

    if (c > 0) {
        const unsigned short* slot = chk + (size_t)(b * (NC - 1) + (c - 1)) * (512 * 512);
#pragma unroll
        for (int ks = 0; ks < 16; ++ks) {
            s8v aq[2];
#pragma unroll
            for (int mf = 0; mf < 2; ++mf)
                aq[mf] = *(const s8v*)&qko[(cb + mq * 32 + mf * 16 + (l & 15)) * 1536 + ks * 32 + (l >> 4) * 8];
#pragma unroll
            for (int n = 0; n < 8; ++n) {
                s8v bc = *(const s8v*)&slot[(size_t)(rr + n * 16 + (l & 15)) * 512 + ks * 32 + (l >> 4) * 8];
                acc[0][n] = __builtin_amdgcn_mfma_f32_16x16x32_bf16(aq[0], bc, acc[0][n], 0, 0, 0);
                acc[1][n] = __builtin_amdgcn_mfma_f32_16x16x32_bf16(aq[1], bc, acc[1][n], 0, 0, 0);
            }
        }
        float aprev = aE[b * NC + c - 1];
#pragma unroll
        for (int mf = 0; mf < 2; ++mf)
#pragma unroll
            for (int e = 0; e < 4; ++e) {
                int t = mq * 32 + mf * 16 + (l >> 4) * 4 + e;
                float bta = expf(aprev - a[cb + t]);
#pragma unroll
                for (int n = 0; n < 8; ++n) acc[mf][n][e] *= bta;
            }
    }
    const unsigned short* stp = st + (size_t)(b * NC + c) * (CL * CL);
#pragma unroll
    for (int ks = 0; ks < 4; ++ks) {
        s8v aq[2];
#pragma unroll
        for (int mf = 0; mf < 2; ++mf)
            aq[mf] = *(const s8v*)&stp[(size_t)(mq * 32 + mf * 16 + (l & 15)) * CL + ks * 32 + (l >> 4) * 8];
#pragma unroll
        for (int n = 0; n < 8; ++n) {
            s8v bv = *(const s8v*)&kvT[(size_t)(512 + rr + n * 16 + (l & 15)) * MROWS + cb + ks * 32 + (l >> 4) * 8];
            acc[0][n] = __builtin_amdgcn_mfma_f32_16x16x32_bf16(aq[0], bv, acc[0][n], 0, 0, 0);
            acc[1][n] = __builtin_amdgcn_mfma_f32_16x16x32_bf16(aq[1], bv, acc[1][n], 0, 0, 0);
        }
    }
#pragma unroll
    for (int mf = 0; mf < 2; ++mf)
#pragma unroll
        for (int e = 0; e < 4; ++e) {
            int t = mq * 32 + mf * 16 + (l >> 4) * 4 + e;
            float rd = rdnm[cb + t];
#pragma unroll
            for (int n = 0; n < 8; ++n) {
                int r = rr + n * 16 + (l & 15);
                float ov = b2f(qko[(cb + t) * 1536 + 1024 + r]);
                g[(cb + t) * DH + r] = f2b(ov * acc[mf][n][e] * rd);
            }
        }
}

extern "C" void kernel_launch(void* const* d_in, const int* in_sizes, int n_in,
                              void* d_out, int out_size, void* d_ws, size_t ws_size,
                              hipStream_t stream)
{
    (void)in_sizes; (void)n_in; (void)out_size; (void)ws_size;
    const float* x    = (const float*)d_in[0];
    const float* nw   = (const float*)d_in[1];
    const float* Wq   = (const float*)d_in[2];
    const float* Wk   = (const float*)d_in[3];
    const float* Wv   = (const float*)d_in[4];
    const float* wi   = (const float*)d_in[5];
    const float* wib  = (const float*)d_in[6];
    const float* wf   = (const float*)d_in[7];
    const float* wfb  = (const float*)d_in[8];
    const float* Wo   = (const float*)d_in[9];
    const float* bo   = (const float*)d_in[10];
    const float* Wout = (const float*)d_in[11];
    float* out = (float*)d_out;

    char* ws = (char*)d_ws;
    unsigned short* qko    = (unsigned short*)ws;                        // 0 .. 50,331,648
    unsigned short* kvT    = (unsigned short*)(ws + 50331648);           // v in rows 512+
    unsigned short* normed = (unsigned short*)(ws + 83886080);
    unsigned short* g      = normed;                                     // first 16 MB (normed dead)
    unsigned short* kw     = (unsigned short*)(ws + 100663296);
    float* Pbuf   = (float*)(ws + 117440512);
    float* aE     = (float*)(ws + 117964800);
    unsigned short* Wcat1  = (unsigned short*)(ws + 117440512);          // dead after gemm_qkv
    unsigned short* WvB    = (unsigned short*)(ws + 120586240);
    unsigned short* Woutb  = (unsigned short*)(ws + 122683392);
    float* zi     = (float*)(ws + 123731968);
    float* zf     = zi + MROWS;
    float* uarr   = zf + MROWS;
    float* aarr   = uarr + MROWS;
    float* rowsum = aarr + MROWS;
    float* rdnm   = rowsum + MROWS;

    // d_out as scratch until final gemm: Cchk (60 MiB) + stbuf (4 MiB)
    unsigned short* chk   = (unsigned short*)d_out;                      // 8*15*512*512*2
    unsigned short* stbuf = (unsigned short*)((char*)d_out + 62914560);  // 8*16*128*128*2

    norm_kernel    <<<MROWS, 256, 0, stream>>>(x, nw, wi, wf, wib, wfb, normed, zi, zf,
                                               Wq, Wk, Wo, Wv, Wout, Wcat1, WvB, Woutb);
    // QKO+V GEMM (blocks 0..2047) + mscan2 (blocks 2048..2055)
    gemm_qkv_ms    <<<2056, 256, 0, stream>>>(normed, Wcat1, WvB, DM, qko, bo,
                                              kvT + (size_t)512 * MROWS, zi, zf, uarr, aarr);
    // phaseA (256) + kwprep2 (1024) co-resident
    fusedA_kernel  <<<1280, 256, 0, stream>>>(qko, uarr, aarr, stbuf, rowsum, kw, Pbuf, aE);
    // C-scan + inline nhscan/denom epilogue
    cscan3_kernel  <<<512, 256, 0, stream>>>(kvT, kw, aE, chk, qko, Pbuf, aarr, rowsum, rdnm);
    hout_kernel    <<<256, 512, 0, stream>>>(qko, kvT, stbuf, chk, aarr, aE, rdnm, g);
    // A=g (16MB) >> B=Woutb (1MB): ORD=1, 1024 = exact round
    gemm_bt<1, 1>  <<<128 * 8, 256, 0, stream>>>(g, Woutb, MROWS, DM, DH, DM, nullptr, nullptr, out, x);
}

// Round 6
// 243.626 us; speedup vs baseline: 1.4807x; 1.1219x over previous
//
#include <hip/hip_runtime.h>
#include <cstdint>
#include <cmath>

#define T_SEQ 2048
#define NBATCH 8
#define DM 1024
#define DH 512
#define MROWS (NBATCH * T_SEQ)   // 16384
#define NC 16                    // chunks per batch
#define CL 128                   // chunk length

typedef short s8v __attribute__((ext_vector_type(8)));
typedef float f32x4 __attribute__((ext_vector_type(4)));

typedef unsigned int __attribute__((address_space(1))) uint_g;
typedef unsigned int __attribute__((address_space(3))) uint_l;

#define QKSCALE 0.044194173824159216f   // 1/sqrt(512)

__device__ __forceinline__ float b2f(unsigned short s) {
    union { unsigned u; float f; } c; c.u = ((unsigned)s) << 16; return c.f;
}
__device__ __forceinline__ unsigned short f2b(float f) {
    union { float f; unsigned u; } c; c.f = f;
    unsigned r = c.u + 0x7fffu + ((c.u >> 16) & 1u);
    return (unsigned short)(r >> 16);
}
__device__ __forceinline__ void gld_lds16(const void* g, void* l) {
    __builtin_amdgcn_global_load_lds((const uint_g*)g, (uint_l*)l, 16, 0, 0);
}

#define WAITV(N) asm volatile("s_waitcnt vmcnt(" #N ")" ::: "memory")
#define BARSYNC() do { asm volatile("" ::: "memory"); __builtin_amdgcn_s_barrier(); asm volatile("" ::: "memory"); } while (0)

// ---------------- RMSNorm + zi/zf + fused weight conversion ----------------
__global__ __launch_bounds__(256) void norm_kernel(
    const float* __restrict__ x, const float* __restrict__ nw,
    const float* __restrict__ wi, const float* __restrict__ wf,
    const float* __restrict__ wib, const float* __restrict__ wfb,
    unsigned short* __restrict__ normed, float* __restrict__ zi, float* __restrict__ zf,
    const float* __restrict__ Wq, const float* __restrict__ Wk,
    const float* __restrict__ Wo, const float* __restrict__ Wv,
    const float* __restrict__ Wout,
    unsigned short* __restrict__ Wcat1, unsigned short* __restrict__ WvB,
    unsigned short* __restrict__ Woutb)
{
    int t = blockIdx.x, tid = threadIdx.x;
    float4 xv = ((const float4*)(x + (size_t)t * DM))[tid];
    float ss = xv.x * xv.x + xv.y * xv.y + xv.z * xv.z + xv.w * xv.w;
#pragma unroll
    for (int m = 1; m < 64; m <<= 1) ss += __shfl_xor(ss, m, 64);
    __shared__ float sred[4];
    __shared__ float sred2[8];
    if ((tid & 63) == 0) sred[tid >> 6] = ss;
    __syncthreads();
    ss = sred[0] + sred[1] + sred[2] + sred[3];
    float rstd = rsqrtf(ss * (1.0f / DM) + 1e-6f);
    float4 nwv = ((const float4*)nw)[tid];
    float n0 = xv.x * rstd * nwv.x, n1 = xv.y * rstd * nwv.y;
    float n2 = xv.z * rstd * nwv.z, n3 = xv.w * rstd * nwv.w;
    ushort4 pk;
    pk.x = f2b(n0); pk.y = f2b(n1); pk.z = f2b(n2); pk.w = f2b(n3);
    ((ushort4*)(normed + (size_t)t * DM))[tid] = pk;
    float4 wiv = ((const float4*)wi)[tid];
    float4 wfv = ((const float4*)wf)[tid];
    float pzi = n0 * wiv.x + n1 * wiv.y + n2 * wiv.z + n3 * wiv.w;
    float pzf = n0 * wfv.x + n1 * wfv.y + n2 * wfv.z + n3 * wfv.w;
#pragma unroll
    for (int m = 1; m < 64; m <<= 1) {
        pzi += __shfl_xor(pzi, m, 64);
        pzf += __shfl_xor(pzf, m, 64);
    }
    if ((tid & 63) == 0) { sred2[tid >> 6] = pzi; sred2[4 + (tid >> 6)] = pzf; }
    __syncthreads();
    if (tid == 0) {
        zi[t] = sred2[0] + sred2[1] + sred2[2] + sred2[3] + wib[0];
        zf[t] = sred2[4] + sred2[5] + sred2[6] + sred2[7] + wfb[0];
    }
    // ---- fused weight conversion ----
    if (tid < 160) {
        int idx = blockIdx.x * 160 + tid;
        if (idx < 1572864) {
            int nrow = idx >> 10;
            float v;
            if      (nrow < 512)  v = Wq[idx];
            else if (nrow < 1024) v = Wk[idx - 512 * 1024];
            else                  v = Wo[idx - 1024 * 1024];
            Wcat1[idx] = f2b(v);
        } else if (idx < 2097152) {
            int j = idx - 1572864;
            WvB[j] = f2b(Wv[j]);
        } else {
            int j = idx - 2097152;
            Woutb[j] = f2b(Wout[j]);
        }
    }
}

// ---------------- merged QKO + V projection + mscan2 (blocks 2048+) ------
__global__ __launch_bounds__(256, 4) void gemm_qkv_ms(
    const unsigned short* __restrict__ normed, const unsigned short* __restrict__ Wcat1,
    const unsigned short* __restrict__ WvB, int K,
    unsigned short* __restrict__ qko, const float* __restrict__ bo,
    unsigned short* __restrict__ vout,
    const float* __restrict__ zi, const float* __restrict__ zf,
    float* __restrict__ u, float* __restrict__ a)
{
    __shared__ unsigned short As[128 * 64];
    __shared__ unsigned short Bs[128 * 64];
    __shared__ float wt[4];
    int tid = threadIdx.x;

    if (blockIdx.x >= 2048) {
        // ---- mscan2 body ----
        int b = blockIdx.x - 2048, lane = tid & 63, wid = tid >> 6;
        size_t base = (size_t)b * T_SEQ + tid * 8;
        float z_f[8], z_i[8];
        *(float4*)&z_f[0] = *(const float4*)&zf[base];
        *(float4*)&z_f[4] = *(const float4*)&zf[base + 4];
        *(float4*)&z_i[0] = *(const float4*)&zi[base];
        *(float4*)&z_i[4] = *(const float4*)&zi[base + 4];
        float c8[8]; float run = 0.0f;
#pragma unroll
        for (int i = 0; i < 8; ++i) { run += z_f[i]; c8[i] = run; }
        float v = run;
#pragma unroll
        for (int d = 1; d < 64; d <<= 1) {
            float o = __shfl_up(v, d, 64);
            if (lane >= d) v += o;
        }
        if (lane == 63) wt[wid] = v;
        __syncthreads();
        float woff = 0.0f;
        for (int j = 0; j < wid; ++j) woff += wt[j];
        float excl = __shfl_up(v, 1, 64);
        if (lane == 0) excl = 0.0f;
        float pre = woff + excl;
        float uu[8];
#pragma unroll
        for (int i = 0; i < 8; ++i) uu[i] = z_i[i] - (pre + c8[i]);
        *(float4*)&u[base] = *(float4*)&uu[0];
        *(float4*)&u[base + 4] = *(float4*)&uu[4];
        __syncthreads();
        float m8[8]; float rm = -INFINITY;
#pragma unroll
        for (int i = 0; i < 8; ++i) { rm = fmaxf(rm, uu[i]); m8[i] = rm; }
        float mv = rm;
#pragma unroll
        for (int d = 1; d < 64; d <<= 1) {
            float o = __shfl_up(mv, d, 64);
            if (lane >= d) mv = fmaxf(mv, o);
        }
        if (lane == 63) wt[wid] = mv;
        __syncthreads();
        float moff = -INFINITY;
        for (int j = 0; j < wid; ++j) moff = fmaxf(moff, wt[j]);
        float mexcl = __shfl_up(mv, 1, 64);
        if (lane == 0) mexcl = -INFINITY;
        float mpre = fmaxf(moff, mexcl);
        float aa[8];
#pragma unroll
        for (int i = 0; i < 8; ++i) aa[i] = fmaxf(mpre, m8[i]);
        *(float4*)&a[base] = *(float4*)&aa[0];
        *(float4*)&a[base + 4] = *(float4*)&aa[4];
        return;
    }

    // ---- GEMM body ----
    int l = tid & 63, w = tid >> 6;
    int wg = (blockIdx.x & 7) * 256 + (blockIdx.x >> 3);   // bijective, 2048 blocks
    int job = (wg >= 1536) ? 1 : 0;
    const unsigned short* A;
    const unsigned short* Bw;
    int bm, bn;
    if (job == 0) { A = normed; Bw = Wcat1; bn = wg % 12; bm = wg / 12; }
    else          { int w2 = wg - 1536; A = WvB; Bw = normed; bm = w2 & 3; bn = w2 >> 2; }
    int wr = w >> 1, wc = w & 1;
    f32x4 acc[4][4] = {};
    const size_t abase = (size_t)(bm * 128) * K;
    const size_t bbase = (size_t)(bn * 128) * K;

    for (int ks = 0; ks < K; ks += 64) {
        __syncthreads();
#pragma unroll
        for (int i = 0; i < 4; ++i) {
            int off = (i * 256 + tid) * 8;
            int row = off >> 6, kc = off & 63;
            int kcs = kc ^ ((row & 7) << 3);
            gld_lds16(A + abase + (size_t)row * K + ks + kcs, &As[off]);
            gld_lds16(Bw + bbase + (size_t)row * K + ks + kcs, &Bs[off]);
        }
        __syncthreads();
#pragma unroll
        for (int kk = 0; kk < 2; ++kk) {
            int cbo = kk * 32 + (l >> 4) * 8;
            s8v af[4], bfv[4];
#pragma unroll
            for (int m = 0; m < 4; ++m) {
                int row = wr * 64 + m * 16 + (l & 15);
                af[m] = *(const s8v*)&As[row * 64 + (cbo ^ ((row & 7) << 3))];
            }
#pragma unroll
            for (int n = 0; n < 4; ++n) {
                int row = wc * 64 + n * 16 + (l & 15);
                bfv[n] = *(const s8v*)&Bs[row * 64 + (cbo ^ ((row & 7) << 3))];
            }
#pragma unroll
            for (int m = 0; m < 4; ++m)
#pragma unroll
                for (int n = 0; n < 4; ++n)
                    acc[m][n] = __builtin_amdgcn_mfma_f32_16x16x32_bf16(af[m], bfv[n], acc[m][n], 0, 0, 0);
        }
    }

    if (job == 0) {
#pragma unroll
        for (int m = 0; m < 4; ++m) {
#pragma unroll
            for (int n = 0; n < 4; ++n) {
                int col = bn * 128 + wc * 64 + n * 16 + (l & 15);
#pragma unroll
                for (int r = 0; r < 4; ++r) {
                    int row = bm * 128 + wr * 64 + m * 16 + (l >> 4) * 4 + r;
                    float v = acc[m][n][r];
                    if (col < 1024) v *= QKSCALE;
                    else {
                        float s = v + bo[col - 1024];
                        v = 1.0f / (1.0f + expf(-s));
                    }
                    qko[(size_t)row * 1536 + col] = f2b(v);
                }
            }
        }
    } else {
#pragma unroll
        for (int m = 0; m < 4; ++m) {
#pragma unroll
            for (int n = 0; n < 4; ++n) {
                int col = bn * 128 + wc * 64 + n * 16 + (l & 15);
#pragma unroll
                for (int r = 0; r < 4; ++r) {
                    int row = bm * 128 + wr * 64 + m * 16 + (l >> 4) * 4 + r;
                    vout[(size_t)row * MROWS + col] = f2b(acc[m][n][r]);
                }
            }
        }
    }
}

// ---------------- 128x128 bf16 MFMA GEMM (output projection) -------------
template <int EPI, int ORD>
__global__ __launch_bounds__(256, 4) void gemm_bt(
    const unsigned short* __restrict__ A, const unsigned short* __restrict__ Bw,
    int M, int N, int K, int ldo,
    unsigned short* __restrict__ outb, const float* __restrict__ bo,
    float* __restrict__ outf, const float* __restrict__ xres)
{
    __shared__ unsigned short As[128 * 64];
    __shared__ unsigned short Bs[128 * 64];
    int tid = threadIdx.x;
    int l = tid & 63, w = tid >> 6;
    int cpx = gridDim.x >> 3;
    int wg = (blockIdx.x & 7) * cpx + (blockIdx.x >> 3);
    int mb = M >> 7;
    int nb = N >> 7;
    int bm, bn;
    if (ORD == 0) { bm = wg % mb; bn = wg / mb; }
    else          { bn = wg % nb; bm = wg / nb; }
    int wr = w >> 1, wc = w & 1;
    f32x4 acc[4][4] = {};
    const size_t abase = (size_t)(bm * 128) * K;
    const size_t bbase = (size_t)(bn * 128) * K;

    for (int ks = 0; ks < K; ks += 64) {
        __syncthreads();
#pragma unroll
        for (int i = 0; i < 4; ++i) {
            int off = (i * 256 + tid) * 8;
            int row = off >> 6, kc = off & 63;
            int kcs = kc ^ ((row & 7) << 3);
            gld_lds16(A + abase + (size_t)row * K + ks + kcs, &As[off]);
            gld_lds16(Bw + bbase + (size_t)row * K + ks + kcs, &Bs[off]);
        }
        __syncthreads();
#pragma unroll
        for (int kk = 0; kk < 2; ++kk) {
            int cbo = kk * 32 + (l >> 4) * 8;
            s8v af[4], bfv[4];
#pragma unroll
            for (int m = 0; m < 4; ++m) {
                int row = wr * 64 + m * 16 + (l & 15);
                af[m] = *(const s8v*)&As[row * 64 + (cbo ^ ((row & 7) << 3))];
            }
#pragma unroll
            for (int n = 0; n < 4; ++n) {
                int row = wc * 64 + n * 16 + (l & 15);
                bfv[n] = *(const s8v*)&Bs[row * 64 + (cbo ^ ((row & 7) << 3))];
            }
#pragma unroll
            for (int m = 0; m < 4; ++m)
#pragma unroll
                for (int n = 0; n < 4; ++n)
                    acc[m][n] = __builtin_amdgcn_mfma_f32_16x16x32_bf16(af[m], bfv[n], acc[m][n], 0, 0, 0);
        }
    }

#pragma unroll
    for (int m = 0; m < 4; ++m) {
#pragma unroll
        for (int n = 0; n < 4; ++n) {
            int col = bn * 128 + wc * 64 + n * 16 + (l & 15);
#pragma unroll
            for (int r = 0; r < 4; ++r) {
                int row = bm * 128 + wr * 64 + m * 16 + (l >> 4) * 4 + r;
                float v = acc[m][n][r];
                if (EPI == 3) {
                    outb[(size_t)row * ldo + col] = f2b(v);
                } else {
                    size_t idx = (size_t)row * ldo + col;
                    outf[idx] = xres[idx] + v;
                }
            }
        }
    }
}

// ---------------- fusedA: phaseA (blocks 0..255) + kwprep2 (256..1279) ----
__global__ __launch_bounds__(256) void fusedA_kernel(
    const unsigned short* __restrict__ qko,
    const float* __restrict__ u, const float* __restrict__ a,
    unsigned short* __restrict__ stb, float* __restrict__ rowsum,
    unsigned short* __restrict__ kw, float* __restrict__ P, float* __restrict__ aE)
{
    __shared__ char smem[17920];
    int bid = blockIdx.x, tid = threadIdx.x;

    if (bid < 256) {
        // ---- phaseA: St[t][j] = exp(u_j - a_t)*(q_t.k_j), j<=t ----
        unsigned short* Qs = (unsigned short*)smem;            // 64*32
        unsigned short* Ks = (unsigned short*)(smem + 4096);   // 128*32
        int b = bid & 7, c = (bid >> 3) & 15, th = bid >> 7;
        int l = tid & 63, wv = tid >> 6;
        size_t cb = (size_t)b * T_SEQ + c * CL;
        f32x4 acc[8] = {};
        for (int ks = 0; ks < 512; ks += 32) {
            __syncthreads();
            {
                int p = tid;
                int row = p >> 2, kc = (p & 3) * 8;
                gld_lds16(qko + (cb + th * 64 + row) * 1536 + ks + kc, &Qs[p * 8]);
#pragma unroll
                for (int rI = 0; rI < 2; ++rI) {
                    int pp = rI * 256 + tid;
                    int rw = pp >> 2, kk = (pp & 3) * 8;
                    gld_lds16(qko + (cb + rw) * 1536 + 512 + ks + kk, &Ks[pp * 8]);
                }
            }
            __syncthreads();
            s8v af = *(const s8v*)&Qs[(wv * 16 + (l & 15)) * 32 + (l >> 4) * 8];
#pragma unroll
            for (int n = 0; n < 8; ++n) {
                s8v bf = *(const s8v*)&Ks[(n * 16 + (l & 15)) * 32 + (l >> 4) * 8];
                acc[n] = __builtin_amdgcn_mfma_f32_16x16x32_bf16(af, bf, acc[n], 0, 0, 0);
            }
        }
        float rs[4] = {0.f, 0.f, 0.f, 0.f};
        size_t stbase = (size_t)(b * NC + c) * (CL * CL);
#pragma unroll
        for (int e = 0; e < 4; ++e) {
            int tl = th * 64 + wv * 16 + (l >> 4) * 4 + e;
            float a_t = a[cb + tl];
#pragma unroll
            for (int n = 0; n < 8; ++n) {
                int j = n * 16 + (l & 15);
                float val = (j <= tl) ? acc[n][e] * expf(u[cb + j] - a_t) : 0.0f;
                rs[e] += val;
                stb[stbase + (size_t)tl * CL + j] = f2b(val);
            }
        }
#pragma unroll
        for (int e = 0; e < 4; ++e) {
#pragma unroll
            for (int m = 1; m < 16; m <<= 1) rs[e] += __shfl_xor(rs[e], m, 64);
        }
        if ((l & 15) == 0) {
#pragma unroll
            for (int e = 0; e < 4; ++e)
                rowsum[cb + th * 64 + wv * 16 + (l >> 4) * 4 + e] = rs[e];
        }
    } else {
        // ---- kwprep2: transpose k + scale; P row-sums ----
        unsigned short (*T)[136] = (unsigned short(*)[136])smem;   // 64*136
        float* w_l = (float*)(smem + 17408);                       // CL floats
        int kb = bid - 256;
        int b = kb & 7, c = (kb >> 3) & 15, stt = kb >> 7;   // stt: 0..7
        int s0 = stt * 64;
        size_t cb = (size_t)b * T_SEQ + c * CL;
        float a_e = a[cb + CL - 1];
        if (tid < CL) w_l[tid] = expf(u[cb + tid] - a_e);
        if (tid == 0 && stt == 0) aE[b * NC + c] = a_e;
#pragma unroll
        for (int it = 0; it < 4; ++it) {
            int flat = it * 256 + tid;          // 0..1023
            int t = flat >> 3, g = flat & 7;
            s8v v = *(const s8v*)&qko[(cb + t) * 1536 + 512 + s0 + g * 8];
#pragma unroll
            for (int e = 0; e < 8; ++e) T[g * 8 + e][t] = (unsigned short)v[e];
        }
        __syncthreads();
        int s = tid >> 2, tg = tid & 3;
        float psum = 0.0f;
#pragma unroll
        for (int j = 0; j < 4; ++j) {
            int t0 = tg * 32 + j * 8;
            s8v kv = *(const s8v*)&T[s][t0];
            s8v kwv;
#pragma unroll
            for (int e = 0; e < 8; ++e) {
                float f = b2f((unsigned short)kv[e]) * w_l[t0 + e];
                kwv[e] = (short)f2b(f);
                psum += f;
            }
            *(s8v*)&kw[(size_t)(s0 + s) * MROWS + cb + t0] = kwv;
        }
        psum += __shfl_xor(psum, 1, 64);
        psum += __shfl_xor(psum, 2, 64);
        if (tg == 0) P[(size_t)(b * NC + c) * 512 + s0 + s] = psum;
    }
}

// ---------------- cscan3: C checkpoints + fused denom/nhscan epilogue ----
__global__ __launch_bounds__(256, 2) void cscan3_kernel(
    const unsigned short* __restrict__ kvT, const unsigned short* __restrict__ kw,
    const float* __restrict__ aE, unsigned short* __restrict__ chk,
    const unsigned short* __restrict__ qko, const float* __restrict__ P,
    const float* __restrict__ a, const float* __restrict__ rowsum,
    float* __restrict__ rdnm)
{
    __shared__ unsigned short Vs[2][64 * 128];
    __shared__ unsigned short Ks[2][64 * 128];
    int bid = blockIdx.x;
    int b = bid & 7, rt = (bid >> 3) & 7, st = bid >> 6;   // 8 x 8 x 8
    int r0 = rt * 64, s0 = st * 64;
    int tid = threadIdx.x, l = tid & 63;
    int w = tid >> 6, wr = w >> 1, wc = w & 1;
    size_t tb = (size_t)b * T_SEQ;
    int srow = tid >> 4, sg = tid & 15;
    f32x4 acc[2][2] = {};
    float a_prev = 0.0f;

#define CSTAGE(c, buf) do { \
        size_t cb_ = tb + (size_t)(c) * CL; \
        _Pragma("unroll") \
        for (int i = 0; i < 4; ++i) { \
            int row_ = i * 16 + srow; \
            int gs_ = sg ^ (row_ & 7); \
            gld_lds16(kvT + (size_t)(512 + r0 + row_) * MROWS + cb_ + gs_ * 8, \
                      &Vs[buf][(i * 256 + tid) * 8]); \
        } \
        _Pragma("unroll") \
        for (int i = 0; i < 4; ++i) { \
            int row_ = i * 16 + srow; \
            int gs_ = sg ^ (row_ & 7); \
            gld_lds16(kw + (size_t)(s0 + row_) * MROWS + cb_ + gs_ * 8, \
                      &Ks[buf][(i * 256 + tid) * 8]); \
        } } while (0)

    CSTAGE(0, 0);
    for (int c = 0; c < NC; ++c) {
        int cur = c & 1;
        if (c + 1 < NC) { CSTAGE(c + 1, cur ^ 1); WAITV(8); }
        else            { WAITV(0); }
        BARSYNC();
        float a_e = aE[b * NC + c];
        if (c > 0) {
            unsigned short* slot = chk + (size_t)(b * (NC - 1) + (c - 1)) * (512 * 512);
#pragma unroll
            for (int m = 0; m < 2; ++m)
#pragma unroll
                for (int n = 0; n < 2; ++n)
#pragma unroll
                    for (int e = 0; e < 4; ++e) {
                        int r = r0 + wr * 32 + m * 16 + (l >> 4) * 4 + e;
                        int s = s0 + wc * 32 + n * 16 + (l & 15);
                        slot[r * 512 + s] = f2b(acc[m][n][e]);
                    }
            float gam = expf(a_prev - a_e);
#pragma unroll
            for (int m = 0; m < 2; ++m)
#pragma unroll
                for (int n = 0; n < 2; ++n)
#pragma unroll
                    for (int e = 0; e < 4; ++e) acc[m][n][e] *= gam;
        }
#pragma unroll
        for (int ks = 0; ks < 4; ++ks) {
            s8v vf[2], kf[2];
#pragma unroll
            for (int m = 0; m < 2; ++m) {
                int row = wr * 32 + m * 16 + (l & 15);
                int gf = ks * 4 + (l >> 4);
                vf[m] = *(const s8v*)&Vs[cur][row * 128 + ((gf ^ (row & 7)) << 3)];
            }
#pragma unroll
            for (int n = 0; n < 2; ++n) {
                int row = wc * 32 + n * 16 + (l & 15);
                int gf = ks * 4 + (l >> 4);
                kf[n] = *(const s8v*)&Ks[cur][row * 128 + ((gf ^ (row & 7)) << 3)];
            }
#pragma unroll
            for (int m = 0; m < 2; ++m)
#pragma unroll
                for (int n = 0; n < 2; ++n)
                    acc[m][n] = __builtin_amdgcn_mfma_f32_16x16x32_bf16(vf[m], kf[n], acc[m][n], 0, 0, 0);
        }
        a_prev = a_e;
        BARSYNC();
    }
#undef CSTAGE

    // ---- fused denom (nhscan inline): 32 t's per block, 8 per wave ----
    {
        int wv = tid >> 6;
        int t0 = bid * 32 + wv * 8;
        int bt = t0 >> 11, ct = (t0 & 2047) >> 7;
        float nh[8] = {0, 0, 0, 0, 0, 0, 0, 0};
        float aprev = 0.0f;
        for (int cp = 0; cp < ct; ++cp) {
            float ae = aE[bt * NC + cp];
            float gam = (cp == 0) ? 0.0f : expf(aprev - ae);
            const float* Pp = P + (size_t)(bt * NC + cp) * 512 + l * 8;
            float4 p0 = *(const float4*)Pp;
            float4 p1 = *(const float4*)(Pp + 4);
#pragma unroll
            for (int e = 0; e < 8; ++e) nh[e] *= gam;
            nh[0] += p0.x; nh[1] += p0.y; nh[2] += p0.z; nh[3] += p0.w;
            nh[4] += p1.x; nh[5] += p1.y; nh[6] += p1.z; nh[7] += p1.w;
            aprev = ae;
        }
        float aeprev = (ct > 0) ? aE[bt * NC + ct - 1] : 0.0f;
        for (int tt = 0; tt < 8; ++tt) {
            int tc = t0 + tt;
            s8v qv = *(const s8v*)(qko + (size_t)tc * 1536 + l * 8);
            float nq = 0.0f;
#pragma unroll
            for (int e = 0; e < 8; ++e) nq += b2f((unsigned short)qv[e]) * nh[e];
#pragma unroll
            for (int m = 1; m < 64; m <<= 1) nq += __shfl_xor(nq, m, 64);
            if (l == 0) {
                float beta = (ct == 0) ? 0.0f : expf(aeprev - a[tc]);
                rdnm[tc] = 1.0f / fmaxf(fabsf(beta * nq + rowsum[tc]), 1.0f);
            }
        }
    }
}

// ---------------- hout2: G = beta*(Q.Cchk^T) + St.V ; h = o*G*rdnm --------
// LDS-staged B-operands (chk / V rows shared by the 4 mq-waves of each
// rg-group: removes 4x redundant global reads), double-buffered with
// counted vmcnt(4). Tile [256 r][64 k] = 32 KB/buf; granule swizzle
// g^=(row&7) applied to SOURCE, same XOR on read (rule 21). Bank check:
// fragment read = 16 rows x XOR'd granule -> all 32 banks, 2 lanes/bank.
__global__ __launch_bounds__(512) void hout2_kernel(
    const unsigned short* __restrict__ qko, const unsigned short* __restrict__ kvT,
    const unsigned short* __restrict__ st, const unsigned short* __restrict__ chk,
    const float* __restrict__ a, const float* __restrict__ aE,
    const float* __restrict__ rdnm, unsigned short* __restrict__ g)
{
    __shared__ unsigned short Bsh[2][256 * 64];
    int bid = blockIdx.x;
    int b = bid & 7, cc = bid >> 3;
    int c = cc >> 1, rh = cc & 1;
    int tid = threadIdx.x, l = tid & 63, wv = tid >> 6;
    int mq = wv & 3, rg = wv >> 2;
    int rr = rg * 128 + rh * 256;
    int R0 = rh * 256;
    size_t cb = (size_t)b * T_SEQ + c * CL;
    f32x4 acc[2][8] = {};

    // staging geometry: granule gidx = i*512+tid; row = i*64+(tid>>3); gc = tid&7
    int srow7 = tid >> 3;        // 0..63 (row within 64-row group)
    int sgc = tid & 7;

    if (c > 0) {
        const unsigned short* slot = chk + (size_t)(b * (NC - 1) + (c - 1)) * (512 * 512);
#define HSTG_C(ksb, buf) do { \
        _Pragma("unroll") \
        for (int i = 0; i < 4; ++i) { \
            int row_ = i * 64 + srow7; \
            int gs_ = sgc ^ (row_ & 7); \
            gld_lds16(slot + (size_t)(R0 + row_) * 512 + (ksb) * 64 + gs_ * 8, \
                      &Bsh[buf][(i * 512 + tid) * 8]); \
        } } while (0)
        HSTG_C(0, 0);
        for (int s = 0; s < 8; ++s) {
            int cur = s & 1;
            if (s + 1 < 8) { HSTG_C(s + 1, cur ^ 1); WAITV(4); }
            else           { WAITV(0); }
            BARSYNC();
#pragma unroll
            for (int kk = 0; kk < 2; ++kk) {
                s8v aq[2];
#pragma unroll
                for (int mf = 0; mf < 2; ++mf)
                    aq[mf] = *(const s8v*)&qko[(cb + mq * 32 + mf * 16 + (l & 15)) * 1536 + s * 64 + kk * 32 + (l >> 4) * 8];
#pragma unroll
                for (int n = 0; n < 8; ++n) {
                    int row = rg * 128 + n * 16 + (l & 15);
                    int gr = (kk * 4 + (l >> 4)) ^ (row & 7);
                    s8v bc = *(const s8v*)&Bsh[cur][row * 64 + gr * 8];
                    acc[0][n] = __builtin_amdgcn_mfma_f32_16x16x32_bf16(aq[0], bc, acc[0][n], 0, 0, 0);
                    acc[1][n] = __builtin_amdgcn_mfma_f32_16x16x32_bf16(aq[1], bc, acc[1][n], 0, 0, 0);
                }
            }
            BARSYNC();
        }
#undef HSTG_C
        float aprev = aE[b * NC + c - 1];
#pragma unroll
        for (int mf = 0; mf < 2; ++mf)
#pragma unroll
            for (int e = 0; e < 4; ++e) {
                int t = mq * 32 + mf * 16 + (l >> 4) * 4 + e;
                float bta = expf(aprev - a[cb + t]);
#pragma unroll
                for (int n = 0; n < 8; ++n) acc[mf][n][e] *= bta;
            }
    }

    // ---- St.V phase: V tile [256 r][64 t-cols], 2 steps ----
    const unsigned short* stp = st + (size_t)(b * NC + c) * (CL * CL);
#define HSTG_V(vsb, buf) do { \
        _Pragma("unroll") \
        for (int i = 0; i < 4; ++i) { \
            int row_ = i * 64 + srow7; \
            int gs_ = sgc ^ (row_ & 7); \
            gld_lds16(kvT + (size_t)(512 + R0 + row_) * MROWS + cb + (vsb) * 64 + gs_ * 8, \
                      &Bsh[buf][(i * 512 + tid) * 8]); \
        } } while (0)
    HSTG_V(0, 0);
    for (int s = 0; s < 2; ++s) {
        if (s + 1 < 2) { HSTG_V(1, 1); WAITV(4); }
        else           { WAITV(0); }
        BARSYNC();
#pragma unroll
        for (int kk = 0; kk < 2; ++kk) {
            s8v aq[2];
#pragma unroll
            for (int mf = 0; mf < 2; ++mf)
                aq[mf] = *(const s8v*)&stp[(size_t)(mq * 32 + mf * 16 + (l & 15)) * CL + s * 64 + kk * 32 + (l >> 4) * 8];
#pragma unroll
            for (int n = 0; n < 8; ++n) {
                int row = rg * 128 + n * 16 + (l & 15);
                int gr = (kk * 4 + (l >> 4)) ^ (row & 7);
                s8v bv = *(const s8v*)&Bsh[s][row * 64 + gr * 8];
                acc[0][n] = __builtin_amdgcn_mfma_f32_16x16x32_bf16(aq[0], bv, acc[0][n], 0, 0, 0);
                acc[1][n] = __builtin_amdgcn_mfma_f32_16x16x32_bf16(aq[1], bv, acc[1][n], 0, 0, 0);
            }
        }
        BARSYNC();
    }
#undef HSTG_V

#pragma unroll
    for (int mf = 0; mf < 2; ++mf)
#pragma unroll
        for (int e = 0; e < 4; ++e) {
            int t = mq * 32 + mf * 16 + (l >> 4) * 4 + e;
            float rd = rdnm[cb + t];
#pragma unroll
            for (int n = 0; n < 8; ++n) {
                int r = rr + n * 16 + (l & 15);
                float ov = b2f(qko[(cb + t) * 1536 + 1024 + r]);
                g[(cb + t) * DH + r] = f2b(ov * acc[mf][n][e] * rd);
            }
        }
}

extern "C" void kernel_launch(void* const* d_in, const int* in_sizes, int n_in,
                              void* d_out, int out_size, void* d_ws, size_t ws_size,
                              hipStream_t stream)
{
    (void)in_sizes; (void)n_in; (void)out_size; (void)ws_size;
    const float* x    = (const float*)d_in[0];
    const float* nw   = (const float*)d_in[1];
    const float* Wq   = (const float*)d_in[2];
    const float* Wk   = (const float*)d_in[3];
    const float* Wv   = (const float*)d_in[4];
    const float* wi   = (const float*)d_in[5];
    const float* wib  = (const float*)d_in[6];
    const float* wf   = (const float*)d_in[7];
    const float* wfb  = (const float*)d_in[8];
    const float* Wo   = (const float*)d_in[9];
    const float* bo   = (const float*)d_in[10];
    const float* Wout = (const float*)d_in[11];
    float* out = (float*)d_out;

    char* ws = (char*)d_ws;
    unsigned short* qko    = (unsigned short*)ws;                        // 0 .. 50,331,648
    unsigned short* kvT    = (unsigned short*)(ws + 50331648);           // v in rows 512+
    unsigned short* normed = (unsigned short*)(ws + 83886080);
    unsigned short* g      = normed;                                     // first 16 MB (normed dead)
    unsigned short* kw     = (unsigned short*)(ws + 100663296);
    float* Pbuf   = (float*)(ws + 117440512);
    float* aE     = (float*)(ws + 117964800);
    unsigned short* Wcat1  = (unsigned short*)(ws + 117440512);          // dead after gemm_qkv
    unsigned short* WvB    = (unsigned short*)(ws + 120586240);
    unsigned short* Woutb  = (unsigned short*)(ws + 122683392);
    float* zi     = (float*)(ws + 123731968);
    float* zf     = zi + MROWS;
    float* uarr   = zf + MROWS;
    float* aarr   = uarr + MROWS;
    float* rowsum = aarr + MROWS;
    float* rdnm   = rowsum + MROWS;

    // d_out as scratch until final gemm: Cchk (60 MiB) + stbuf (4 MiB)
    unsigned short* chk   = (unsigned short*)d_out;                      // 8*15*512*512*2
    unsigned short* stbuf = (unsigned short*)((char*)d_out + 62914560);  // 8*16*128*128*2

    norm_kernel    <<<MROWS, 256, 0, stream>>>(x, nw, wi, wf, wib, wfb, normed, zi, zf,
                                               Wq, Wk, Wo, Wv, Wout, Wcat1, WvB, Woutb);
    // QKO+V GEMM (blocks 0..2047) + mscan2 (blocks 2048..2055)
    gemm_qkv_ms    <<<2056, 256, 0, stream>>>(normed, Wcat1, WvB, DM, qko, bo,
                                              kvT + (size_t)512 * MROWS, zi, zf, uarr, aarr);
    // phaseA (256) + kwprep2 (1024) co-resident
    fusedA_kernel  <<<1280, 256, 0, stream>>>(qko, uarr, aarr, stbuf, rowsum, kw, Pbuf, aE);
    // C-scan + inline nhscan/denom epilogue
    cscan3_kernel  <<<512, 256, 0, stream>>>(kvT, kw, aE, chk, qko, Pbuf, aarr, rowsum, rdnm);
    hout2_kernel   <<<256, 512, 0, stream>>>(qko, kvT, stbuf, chk, aarr, aE, rdnm, g);
    // A=g (16MB) >> B=Woutb (1MB): ORD=1, 1024 = exact round
    gemm_bt<1, 1>  <<<128 * 8, 256, 0, stream>>>(g, Woutb, MROWS, DM, DH, DM, nullptr, nullptr, out, x);
}